// Round 2
// baseline (4143.510 us; speedup 1.0000x reference)
//
#include <hip/hip_runtime.h>
#include <hip/hip_bf16.h>
#include <math.h>

typedef unsigned short u16;
typedef unsigned int   u32;

#define NUU 50000
#define NTT 100000
#define EE  100000
#define DD  128
#define HH  4
#define HCC 512

// ---------- helpers ----------
__device__ __forceinline__ float bf2f(u16 u) { return __uint_as_float((u32)u << 16); }
__device__ __forceinline__ float bflo(u32 u) { return __uint_as_float(u << 16); }
__device__ __forceinline__ float bfhi(u32 u) { return __uint_as_float(u & 0xFFFF0000u); }
__device__ __forceinline__ u16 f2bf(float f) {
  u32 u = __float_as_uint(f);
  u32 r = (u + 0x7FFFu + ((u >> 16) & 1u)) >> 16;
  return (u16)r;
}
// order-preserving f32 <-> u32 map for atomicMax-based segment max
__device__ __forceinline__ u32 f2ord(float f) {
  u32 u = __float_as_uint(f);
  return (u & 0x80000000u) ? ~u : (u | 0x80000000u);
}
__device__ __forceinline__ float ord2f(u32 u) {
  u32 b = (u & 0x80000000u) ? (u & 0x7FFFFFFFu) : ~u;
  return __uint_as_float(b);
}

// ---------- init: x_user = emb_user ; x_tweet[i,:] = tv_tweet ----------
__global__ __launch_bounds__(256) void init_x(const float* __restrict__ emb,
                                              const float* __restrict__ tv,
                                              float* __restrict__ xu,
                                              float* __restrict__ xt) {
  size_t idx = (size_t)blockIdx.x * 256 + threadIdx.x;
  size_t nu = (size_t)NUU * DD;
  size_t nt = (size_t)NTT * DD;
  if (idx < nu) {
    xu[idx] = emb[idx];
  } else {
    size_t j = idx - nu;
    if (j < nt) xt[j] = tv[j & (DD - 1)];
  }
}

// ---------- QKV GEMM: Y[n, ldy](bf16) = X[n,128] @ W[128, col0:col0+ldy] + bias ----------
// W row stride is HCC (512). ldy = HB*128, col0 = h0*128.
__global__ __launch_bounds__(256) void gemm_qkv(const float* __restrict__ X,
                                                const float* __restrict__ W,
                                                const float* __restrict__ bias,
                                                u16* __restrict__ Y,
                                                int n, int ldy, int col0) {
  __shared__ float Xs[64][68];
  __shared__ float Ws[64][68];
  const int bm = blockIdx.x * 64;
  const int bn = blockIdx.y * 64;
  const int tid = threadIdx.x;
  const int ty = tid >> 4, tx = tid & 15;
  float acc[4][4] = {};

  for (int kt = 0; kt < 128; kt += 64) {
    {
      int r = tid >> 2, qq = tid & 3;
      int grow = bm + r;
      const float* xp = X + (size_t)grow * DD + kt;
      #pragma unroll
      for (int i = 0; i < 4; ++i) {
        int c = (qq + 4 * i) * 4;
        float4 val = make_float4(0.f, 0.f, 0.f, 0.f);
        if (grow < n) val = *(const float4*)(xp + c);
        *(float4*)&Xs[r][c] = val;
      }
    }
    {
      int kr = tid >> 2, qq = tid & 3;
      const float* wp = W + (size_t)(kt + kr) * HCC + col0 + bn;
      #pragma unroll
      for (int i = 0; i < 4; ++i) {
        int c = (qq + 4 * i) * 4;
        *(float4*)&Ws[kr][c] = *(const float4*)(wp + c);
      }
    }
    __syncthreads();
    #pragma unroll 8
    for (int k = 0; k < 64; ++k) {
      float a0 = Xs[ty * 4 + 0][k];
      float a1 = Xs[ty * 4 + 1][k];
      float a2 = Xs[ty * 4 + 2][k];
      float a3 = Xs[ty * 4 + 3][k];
      float4 b4 = *(float4*)&Ws[k][tx * 4];
      acc[0][0] = fmaf(a0, b4.x, acc[0][0]);
      acc[0][1] = fmaf(a0, b4.y, acc[0][1]);
      acc[0][2] = fmaf(a0, b4.z, acc[0][2]);
      acc[0][3] = fmaf(a0, b4.w, acc[0][3]);
      acc[1][0] = fmaf(a1, b4.x, acc[1][0]);
      acc[1][1] = fmaf(a1, b4.y, acc[1][1]);
      acc[1][2] = fmaf(a1, b4.z, acc[1][2]);
      acc[1][3] = fmaf(a1, b4.w, acc[1][3]);
      acc[2][0] = fmaf(a2, b4.x, acc[2][0]);
      acc[2][1] = fmaf(a2, b4.y, acc[2][1]);
      acc[2][2] = fmaf(a2, b4.z, acc[2][2]);
      acc[2][3] = fmaf(a2, b4.w, acc[2][3]);
      acc[3][0] = fmaf(a3, b4.x, acc[3][0]);
      acc[3][1] = fmaf(a3, b4.y, acc[3][1]);
      acc[3][2] = fmaf(a3, b4.z, acc[3][2]);
      acc[3][3] = fmaf(a3, b4.w, acc[3][3]);
    }
    __syncthreads();
  }

  const float4 bb = *(const float4*)(bias + col0 + bn + tx * 4);
  #pragma unroll
  for (int i = 0; i < 4; ++i) {
    int grow = bm + ty * 4 + i;
    if (grow >= n) continue;
    u16* yp = Y + (size_t)grow * ldy + bn + tx * 4;
    ushort4 pk;
    pk.x = f2bf(acc[i][0] + bb.x);
    pk.y = f2bf(acc[i][1] + bb.y);
    pk.z = f2bf(acc[i][2] + bb.z);
    pk.w = f2bf(acc[i][3] + bb.w);
    *(ushort4*)yp = pk;
  }
}

// ---------- skip GEMM: Yacc[n,128] += X[n,128] @ W[128,128] + bias ----------
__global__ __launch_bounds__(256) void gemm_skip(const float* __restrict__ X,
                                                 const float* __restrict__ W,
                                                 const float* __restrict__ bias,
                                                 float* __restrict__ Yacc, int n) {
  __shared__ float Xs[64][68];
  __shared__ float Ws[64][68];
  const int bm = blockIdx.x * 64;
  const int bn = blockIdx.y * 64;
  const int tid = threadIdx.x;
  const int ty = tid >> 4, tx = tid & 15;
  float acc[4][4] = {};

  for (int kt = 0; kt < 128; kt += 64) {
    {
      int r = tid >> 2, qq = tid & 3;
      int grow = bm + r;
      const float* xp = X + (size_t)grow * DD + kt;
      #pragma unroll
      for (int i = 0; i < 4; ++i) {
        int c = (qq + 4 * i) * 4;
        float4 val = make_float4(0.f, 0.f, 0.f, 0.f);
        if (grow < n) val = *(const float4*)(xp + c);
        *(float4*)&Xs[r][c] = val;
      }
    }
    {
      int kr = tid >> 2, qq = tid & 3;
      const float* wp = W + (size_t)(kt + kr) * DD + bn;
      #pragma unroll
      for (int i = 0; i < 4; ++i) {
        int c = (qq + 4 * i) * 4;
        *(float4*)&Ws[kr][c] = *(const float4*)(wp + c);
      }
    }
    __syncthreads();
    #pragma unroll 8
    for (int k = 0; k < 64; ++k) {
      float a0 = Xs[ty * 4 + 0][k];
      float a1 = Xs[ty * 4 + 1][k];
      float a2 = Xs[ty * 4 + 2][k];
      float a3 = Xs[ty * 4 + 3][k];
      float4 b4 = *(float4*)&Ws[k][tx * 4];
      acc[0][0] = fmaf(a0, b4.x, acc[0][0]);
      acc[0][1] = fmaf(a0, b4.y, acc[0][1]);
      acc[0][2] = fmaf(a0, b4.z, acc[0][2]);
      acc[0][3] = fmaf(a0, b4.w, acc[0][3]);
      acc[1][0] = fmaf(a1, b4.x, acc[1][0]);
      acc[1][1] = fmaf(a1, b4.y, acc[1][1]);
      acc[1][2] = fmaf(a1, b4.z, acc[1][2]);
      acc[1][3] = fmaf(a1, b4.w, acc[1][3]);
      acc[2][0] = fmaf(a2, b4.x, acc[2][0]);
      acc[2][1] = fmaf(a2, b4.y, acc[2][1]);
      acc[2][2] = fmaf(a2, b4.z, acc[2][2]);
      acc[2][3] = fmaf(a2, b4.w, acc[2][3]);
      acc[3][0] = fmaf(a3, b4.x, acc[3][0]);
      acc[3][1] = fmaf(a3, b4.y, acc[3][1]);
      acc[3][2] = fmaf(a3, b4.z, acc[3][2]);
      acc[3][3] = fmaf(a3, b4.w, acc[3][3]);
    }
    __syncthreads();
  }

  const float4 bb = *(const float4*)(bias + bn + tx * 4);
  #pragma unroll
  for (int i = 0; i < 4; ++i) {
    int grow = bm + ty * 4 + i;
    if (grow >= n) continue;
    float* yp = Yacc + (size_t)grow * DD + bn + tx * 4;
    float4 old = *(float4*)yp;
    old.x += acc[i][0] + bb.x;
    old.y += acc[i][1] + bb.y;
    old.z += acc[i][2] + bb.z;
    old.w += acc[i][3] + bb.w;
    *(float4*)yp = old;
  }
}

// ---------- logits: one wave per edge, HB heads; q/k layout [n, HB, 128] ----------
__global__ __launch_bounds__(256) void logits_kernel(const u16* __restrict__ q,
                                                     const u16* __restrict__ k,
                                                     const int* __restrict__ esrc,
                                                     const int* __restrict__ edst,
                                                     float* __restrict__ logits,
                                                     u32* __restrict__ mmax, int HB) {
  int wid = (int)(((size_t)blockIdx.x * 256 + threadIdx.x) >> 6);
  int lane = threadIdx.x & 63;
  if (wid >= EE) return;
  int s = esrc[wid], dv = edst[wid];
  const u32* qp = (const u32*)(q + (size_t)dv * HB * DD);
  const u32* kp = (const u32*)(k + (size_t)s * HB * DD);
  for (int h = 0; h < HB; ++h) {
    u32 qu = qp[h * 64 + lane];
    u32 ku = kp[h * 64 + lane];
    float dot = bflo(qu) * bflo(ku) + bfhi(qu) * bfhi(ku);
    #pragma unroll
    for (int o = 1; o < 64; o <<= 1) dot += __shfl_xor(dot, o);
    if (lane == 0) {
      float lgv = dot * 0.08838834764831845f;  // 1/sqrt(128)
      logits[(size_t)wid * HB + h] = lgv;
      atomicMax(mmax + (size_t)dv * HB + h, f2ord(lgv));
    }
  }
}

// ---------- z: e = exp(logit - m[dst]); z[dst] += e; store e over logits ----------
__global__ __launch_bounds__(256) void z_kernel(const int* __restrict__ edst,
                                                float* __restrict__ logits,
                                                const u32* __restrict__ mmax,
                                                float* __restrict__ z, int HB, int HSH) {
  int i = blockIdx.x * 256 + threadIdx.x;
  if (i >= EE * HB) return;
  int e = i >> HSH, h = i & (HB - 1);
  int dv = edst[e];
  float m = ord2f(mmax[(size_t)dv * HB + h]);
  float ev = __expf(logits[i] - m);
  logits[i] = ev;
  unsafeAtomicAdd(z + (size_t)dv * HB + h, ev);
}

// ---------- scatter: agg[dst] += (1/4) * sum_h a_h * v[src, h, :] ----------
__global__ __launch_bounds__(256) void scatter_kernel(const u16* __restrict__ v,
                                                      const int* __restrict__ esrc,
                                                      const int* __restrict__ edst,
                                                      const float* __restrict__ evals,
                                                      const float* __restrict__ z,
                                                      float* __restrict__ agg, int HB) {
  int wid = (int)(((size_t)blockIdx.x * 256 + threadIdx.x) >> 6);
  int lane = threadIdx.x & 63;
  if (wid >= EE) return;
  int s = esrc[wid], dv = edst[wid];
  const u32* vp = (const u32*)(v + (size_t)s * HB * DD);
  float acc0 = 0.f, acc1 = 0.f;
  for (int h = 0; h < HB; ++h) {
    float wgt = evals[(size_t)wid * HB + h] / z[(size_t)dv * HB + h] * 0.25f;
    u32 vu = vp[h * 64 + lane];
    acc0 += wgt * bflo(vu);
    acc1 += wgt * bfhi(vu);
  }
  unsafeAtomicAdd(agg + (size_t)dv * DD + 2 * lane, acc0);
  unsafeAtomicAdd(agg + (size_t)dv * DD + 2 * lane + 1, acc1);
}

// ---------- LayerNorm + residual, one wave per node ----------
__global__ __launch_bounds__(256) void ln_kernel(const float* __restrict__ agg,
                                                 const float* __restrict__ g,
                                                 const float* __restrict__ b,
                                                 float* __restrict__ x,
                                                 int n) {
  int wid = (int)(((size_t)blockIdx.x * 256 + threadIdx.x) >> 6);
  int lane = threadIdx.x & 63;
  if (wid >= n) return;
  const float* ap = agg + (size_t)wid * DD;
  float v0 = ap[lane], v1 = ap[lane + 64];
  float s = v0 + v1;
  #pragma unroll
  for (int o = 1; o < 64; o <<= 1) s += __shfl_xor(s, o);
  float mean = s * (1.0f / DD);
  float d0 = v0 - mean, d1 = v1 - mean;
  float sq = d0 * d0 + d1 * d1;
  #pragma unroll
  for (int o = 1; o < 64; o <<= 1) sq += __shfl_xor(sq, o);
  float rstd = rsqrtf(sq * (1.0f / DD) + 1e-5f);
  float* xp = x + (size_t)wid * DD;
  xp[lane]      = g[lane]      * d0 * rstd + b[lane]      + xp[lane];
  xp[lane + 64] = g[lane + 64] * d1 * rstd + b[lane + 64] + xp[lane + 64];
}

extern "C" void kernel_launch(void* const* d_in, const int* in_sizes, int n_in,
                              void* d_out, int out_size, void* d_ws, size_t ws_size,
                              hipStream_t stream) {
  const float* emb_user = (const float*)d_in[0];
  const float* tv_tweet = (const float*)d_in[1];
  const float* W_qkv  = (const float*)d_in[2];
  const float* b_qkv  = (const float*)d_in[3];
  const float* W_skip = (const float*)d_in[4];
  const float* b_skip = (const float*)d_in[5];
  const float* ln_g   = (const float*)d_in[6];
  const float* ln_b   = (const float*)d_in[7];
  const int* edges[3] = { (const int*)d_in[8], (const int*)d_in[9], (const int*)d_in[10] };

  float* x_user  = (float*)d_out;
  float* x_tweet = x_user + (size_t)NUU * DD;

  // ---- workspace layout, head-chunked to fit ws_size ----
  // need(HB) = 3*25.6e6*HB (q,k,v bf16) + 76.8e6 (agg f32) + 3*0.4e6*HB (lgb,mm,zb)
  auto need = [](int hb) -> size_t {
    return (size_t)3 * 25600000 * hb + 76800000 + (size_t)3 * 400000 * hb + 4096;
  };
  int HB = (ws_size >= need(4)) ? 4 : (ws_size >= need(2)) ? 2 : 1;
  int HSH = (HB == 4) ? 2 : (HB == 2) ? 1 : 0;

  char* w = (char*)d_ws;
  size_t qkvBytes = (size_t)100000 * HB * DD * 2;
  u16* qb = (u16*)w;        w += qkvBytes;
  u16* kb = (u16*)w;        w += qkvBytes;
  u16* vb = (u16*)w;        w += qkvBytes;
  float* agg_u = (float*)w; w += (size_t)NUU * DD * 4;
  float* agg_t = (float*)w; w += (size_t)NTT * DD * 4;
  float* lgb = (float*)w;   w += (size_t)EE * HB * 4;
  u32* mm = (u32*)w;        w += (size_t)100000 * HB * 4;
  float* zb = (float*)w;

  init_x<<<(19200000 + 255) / 256, 256, 0, stream>>>(emb_user, tv_tweet, x_user, x_tweet);

  const int stt[3] = {0, 0, 1}, dtt[3] = {0, 1, 0};
  const int cnt[2] = {NUU, NTT};
  float* xs[2]   = {x_user, x_tweet};
  float* aggs[2] = {agg_u, agg_t};

  for (int l = 0; l < 2; ++l) {
    hipMemsetAsync(agg_u, 0, (size_t)NUU * DD * 4, stream);
    hipMemsetAsync(agg_t, 0, (size_t)NTT * DD * 4, stream);
    for (int r = 0; r < 3; ++r) {
      const int st = stt[r], dt = dtt[r];
      const int ns = cnt[st], nd = cnt[dt];
      const float* Wq = W_qkv + (size_t)((l * 3 + r) * 3 + 0) * DD * HCC;
      const float* Wk = W_qkv + (size_t)((l * 3 + r) * 3 + 1) * DD * HCC;
      const float* Wv = W_qkv + (size_t)((l * 3 + r) * 3 + 2) * DD * HCC;
      const float* bq = b_qkv + (size_t)((l * 3 + r) * 3 + 0) * HCC;
      const float* bk = b_qkv + (size_t)((l * 3 + r) * 3 + 1) * HCC;
      const float* bv = b_qkv + (size_t)((l * 3 + r) * 3 + 2) * HCC;
      const float* Wsk = W_skip + (size_t)(l * 3 + r) * DD * DD;
      const float* bsk = b_skip + (size_t)(l * 3 + r) * DD;

      for (int h0 = 0; h0 < HH; h0 += HB) {
        hipMemsetAsync(mm, 0, (size_t)nd * HB * 4, stream);
        hipMemsetAsync(zb, 0, (size_t)nd * HB * 4, stream);

        const int ldy = HB * DD, col0 = h0 * DD;
        gemm_qkv<<<dim3((nd + 63) / 64, ldy / 64), 256, 0, stream>>>(xs[dt], Wq, bq, qb, nd, ldy, col0);
        gemm_qkv<<<dim3((ns + 63) / 64, ldy / 64), 256, 0, stream>>>(xs[st], Wk, bk, kb, ns, ldy, col0);
        gemm_qkv<<<dim3((ns + 63) / 64, ldy / 64), 256, 0, stream>>>(xs[st], Wv, bv, vb, ns, ldy, col0);

        logits_kernel<<<EE / 4, 256, 0, stream>>>(qb, kb, edges[r], edges[r] + EE, lgb, mm, HB);
        z_kernel<<<(EE * HB + 255) / 256, 256, 0, stream>>>(edges[r] + EE, lgb, mm, zb, HB, HSH);
        scatter_kernel<<<EE / 4, 256, 0, stream>>>(vb, edges[r], edges[r] + EE, lgb, zb, aggs[dt], HB);
      }

      gemm_skip<<<dim3((nd + 63) / 64, 2), 256, 0, stream>>>(xs[dt], Wsk, bsk, aggs[dt], nd);
    }
    ln_kernel<<<(NUU + 3) / 4, 256, 0, stream>>>(agg_u, ln_g + (size_t)(l * 2 + 0) * DD,
                                                 ln_b + (size_t)(l * 2 + 0) * DD, x_user, NUU);
    ln_kernel<<<(NTT + 3) / 4, 256, 0, stream>>>(agg_t, ln_g + (size_t)(l * 2 + 1) * DD,
                                                 ln_b + (size_t)(l * 2 + 1) * DD, x_tweet, NTT);
  }
}

// Round 3
// 3211.420 us; speedup vs baseline: 1.2902x; 1.2902x over previous
//
#include <hip/hip_runtime.h>
#include <hip/hip_bf16.h>
#include <math.h>

typedef unsigned short u16;
typedef unsigned int   u32;
typedef __attribute__((ext_vector_type(8))) short s8v;   // 8 x bf16 (4 VGPR)
typedef __attribute__((ext_vector_type(4))) float f4v;   // MFMA accumulator

#define NUU 50000
#define NTT 100000
#define EE  100000
#define DD  128
#define HH  4
#define HCC 512

// ---------- helpers ----------
__device__ __forceinline__ float bf2f(u16 u) { return __uint_as_float((u32)u << 16); }
__device__ __forceinline__ float bflo(u32 u) { return __uint_as_float(u << 16); }
__device__ __forceinline__ float bfhi(u32 u) { return __uint_as_float(u & 0xFFFF0000u); }
__device__ __forceinline__ u16 f2bf(float f) {
  u32 u = __float_as_uint(f);
  u32 r = (u + 0x7FFFu + ((u >> 16) & 1u)) >> 16;
  return (u16)r;
}
__device__ __forceinline__ u32 f2ord(float f) {
  u32 u = __float_as_uint(f);
  return (u & 0x80000000u) ? ~u : (u | 0x80000000u);
}
__device__ __forceinline__ float ord2f(u32 u) {
  u32 b = (u & 0x80000000u) ? (u & 0x7FFFFFFFu) : ~u;
  return __uint_as_float(b);
}
__device__ __forceinline__ s8v cvt_row8(const float* __restrict__ p) {
  s8v r;
  #pragma unroll
  for (int i = 0; i < 8; ++i) r[i] = (short)f2bf(p[i]);
  return r;
}

// ---------- init: x_user = emb_user ; x_tweet[i,:] = tv_tweet ----------
__global__ __launch_bounds__(256) void init_x(const float* __restrict__ emb,
                                              const float* __restrict__ tv,
                                              float* __restrict__ xu,
                                              float* __restrict__ xt) {
  size_t idx = (size_t)blockIdx.x * 256 + threadIdx.x;
  size_t nu = (size_t)NUU * DD;
  size_t nt = (size_t)NTT * DD;
  if (idx < nu) {
    xu[idx] = emb[idx];
  } else {
    size_t j = idx - nu;
    if (j < nt) xt[j] = tv[j & (DD - 1)];
  }
}

// ---------- convert weights to bf16, transposed: Wt[mat][col][k] ----------
__global__ __launch_bounds__(256) void conv_w(const float* __restrict__ Wq,
                                              const float* __restrict__ Wsk,
                                              u16* __restrict__ Wtq,
                                              u16* __restrict__ Wts) {
  int idx = blockIdx.x * 256 + threadIdx.x;
  if (idx < 18 * 512 * 128) {
    int k = idx & 127, col = (idx >> 7) & 511, mat = idx >> 16;
    Wtq[idx] = f2bf(Wq[((size_t)mat * 128 + k) * 512 + col]);
  }
  if (idx < 6 * 128 * 128) {
    int k = idx & 127, col = (idx >> 7) & 127, mat = idx >> 14;
    Wts[idx] = f2bf(Wsk[((size_t)mat * 128 + k) * 128 + col]);
  }
}

// ---------- MFMA QKV GEMM: Y[n,ldy](bf16) = bf16(X[n,128]) @ Wt^T + bias ----------
// Wt layout [512][128] (col-major-by-k). col0 selects head chunk; ldy = chunk width.
__global__ __launch_bounds__(256) void gemm_qkv_mfma(const float* __restrict__ X,
                                                     const u16* __restrict__ Wt,
                                                     const float* __restrict__ bias,
                                                     u16* __restrict__ Y,
                                                     int n, int ldy, int col0) {
  const int bm = blockIdx.x * 128;
  const int bn = blockIdx.y * 128;
  const int wid = threadIdx.x >> 6, lane = threadIdx.x & 63;
  const int l15 = lane & 15, l4 = lane >> 4;
  const int rbase = bm + wid * 32;
  f4v acc[2][8] = {};
  int r0 = rbase + l15;      if (r0 >= n) r0 = n - 1;
  int r1 = rbase + 16 + l15; if (r1 >= n) r1 = n - 1;
  const float* xp0 = X + (size_t)r0 * DD + l4 * 8;
  const float* xp1 = X + (size_t)r1 * DD + l4 * 8;
  const u16* wp = Wt + (size_t)(col0 + bn + l15) * DD + l4 * 8;

  #pragma unroll
  for (int kk = 0; kk < 4; ++kk) {
    s8v a0 = cvt_row8(xp0 + kk * 32);
    s8v a1 = cvt_row8(xp1 + kk * 32);
    #pragma unroll
    for (int nn = 0; nn < 8; ++nn) {
      s8v b = *(const s8v*)(wp + (size_t)nn * 16 * DD + kk * 32);
      acc[0][nn] = __builtin_amdgcn_mfma_f32_16x16x32_bf16(a0, b, acc[0][nn], 0, 0, 0);
      acc[1][nn] = __builtin_amdgcn_mfma_f32_16x16x32_bf16(a1, b, acc[1][nn], 0, 0, 0);
    }
  }

  float bv[8];
  #pragma unroll
  for (int nn = 0; nn < 8; ++nn) bv[nn] = bias[col0 + bn + nn * 16 + l15];
  // D layout: col = lane&15, row = (lane>>4)*4 + j   [m89]
  #pragma unroll
  for (int m = 0; m < 2; ++m) {
    #pragma unroll
    for (int j = 0; j < 4; ++j) {
      int r = rbase + m * 16 + l4 * 4 + j;
      if (r >= n) continue;
      u16* yp = Y + (size_t)r * ldy + bn + l15;
      #pragma unroll
      for (int nn = 0; nn < 8; ++nn) yp[nn * 16] = f2bf(acc[m][nn][j] + bv[nn]);
    }
  }
}

// ---------- MFMA skip GEMM: agg[n,128] += bf16(X) @ Wt^T + bias ----------
__global__ __launch_bounds__(256) void gemm_skip_mfma(const float* __restrict__ X,
                                                      const u16* __restrict__ Wt,
                                                      const float* __restrict__ bias,
                                                      float* __restrict__ agg, int n) {
  const int bm = blockIdx.x * 128;
  const int wid = threadIdx.x >> 6, lane = threadIdx.x & 63;
  const int l15 = lane & 15, l4 = lane >> 4;
  const int rbase = bm + wid * 32;
  f4v acc[2][8] = {};
  int r0 = rbase + l15;      if (r0 >= n) r0 = n - 1;
  int r1 = rbase + 16 + l15; if (r1 >= n) r1 = n - 1;
  const float* xp0 = X + (size_t)r0 * DD + l4 * 8;
  const float* xp1 = X + (size_t)r1 * DD + l4 * 8;
  const u16* wp = Wt + (size_t)l15 * DD + l4 * 8;

  #pragma unroll
  for (int kk = 0; kk < 4; ++kk) {
    s8v a0 = cvt_row8(xp0 + kk * 32);
    s8v a1 = cvt_row8(xp1 + kk * 32);
    #pragma unroll
    for (int nn = 0; nn < 8; ++nn) {
      s8v b = *(const s8v*)(wp + (size_t)nn * 16 * DD + kk * 32);
      acc[0][nn] = __builtin_amdgcn_mfma_f32_16x16x32_bf16(a0, b, acc[0][nn], 0, 0, 0);
      acc[1][nn] = __builtin_amdgcn_mfma_f32_16x16x32_bf16(a1, b, acc[1][nn], 0, 0, 0);
    }
  }

  float bv[8];
  #pragma unroll
  for (int nn = 0; nn < 8; ++nn) bv[nn] = bias[nn * 16 + l15];
  #pragma unroll
  for (int m = 0; m < 2; ++m) {
    #pragma unroll
    for (int j = 0; j < 4; ++j) {
      int r = rbase + m * 16 + l4 * 4 + j;
      if (r >= n) continue;
      float* yp = agg + (size_t)r * DD + l15;
      #pragma unroll
      for (int nn = 0; nn < 8; ++nn) yp[nn * 16] += acc[m][nn][j] + bv[nn];
    }
  }
}

// ---------- logits: one wave per edge, HB heads; q/k layout [n, HB, 128] ----------
__global__ __launch_bounds__(256) void logits_kernel(const u16* __restrict__ q,
                                                     const u16* __restrict__ k,
                                                     const int* __restrict__ esrc,
                                                     const int* __restrict__ edst,
                                                     float* __restrict__ logits,
                                                     u32* __restrict__ mmax, int HB) {
  int wid = (int)(((size_t)blockIdx.x * 256 + threadIdx.x) >> 6);
  int lane = threadIdx.x & 63;
  if (wid >= EE) return;
  int s = esrc[wid], dv = edst[wid];
  const u32* qp = (const u32*)(q + (size_t)dv * HB * DD);
  const u32* kp = (const u32*)(k + (size_t)s * HB * DD);
  for (int h = 0; h < HB; ++h) {
    u32 qu = qp[h * 64 + lane];
    u32 ku = kp[h * 64 + lane];
    float dot = bflo(qu) * bflo(ku) + bfhi(qu) * bfhi(ku);
    #pragma unroll
    for (int o = 1; o < 64; o <<= 1) dot += __shfl_xor(dot, o);
    if (lane == 0) {
      float lgv = dot * 0.08838834764831845f;  // 1/sqrt(128)
      logits[(size_t)wid * HB + h] = lgv;
      atomicMax(mmax + (size_t)dv * HB + h, f2ord(lgv));
    }
  }
}

// ---------- z: e = exp(logit - m[dst]); z[dst] += e; store e over logits ----------
__global__ __launch_bounds__(256) void z_kernel(const int* __restrict__ edst,
                                                float* __restrict__ logits,
                                                const u32* __restrict__ mmax,
                                                float* __restrict__ z, int HB, int HSH) {
  int i = blockIdx.x * 256 + threadIdx.x;
  if (i >= EE * HB) return;
  int e = i >> HSH, h = i & (HB - 1);
  int dv = edst[e];
  float m = ord2f(mmax[(size_t)dv * HB + h]);
  float ev = __expf(logits[i] - m);
  logits[i] = ev;
  unsafeAtomicAdd(z + (size_t)dv * HB + h, ev);
}

// ---------- scatter: agg[dst] += (1/4) * sum_h a_h * v[src, h, :] ----------
__global__ __launch_bounds__(256) void scatter_kernel(const u16* __restrict__ v,
                                                      const int* __restrict__ esrc,
                                                      const int* __restrict__ edst,
                                                      const float* __restrict__ evals,
                                                      const float* __restrict__ z,
                                                      float* __restrict__ agg, int HB) {
  int wid = (int)(((size_t)blockIdx.x * 256 + threadIdx.x) >> 6);
  int lane = threadIdx.x & 63;
  if (wid >= EE) return;
  int s = esrc[wid], dv = edst[wid];
  const u32* vp = (const u32*)(v + (size_t)s * HB * DD);
  float acc0 = 0.f, acc1 = 0.f;
  for (int h = 0; h < HB; ++h) {
    float wgt = evals[(size_t)wid * HB + h] / z[(size_t)dv * HB + h] * 0.25f;
    u32 vu = vp[h * 64 + lane];
    acc0 += wgt * bflo(vu);
    acc1 += wgt * bfhi(vu);
  }
  unsafeAtomicAdd(agg + (size_t)dv * DD + 2 * lane, acc0);
  unsafeAtomicAdd(agg + (size_t)dv * DD + 2 * lane + 1, acc1);
}

// ---------- LayerNorm + residual, one wave per node ----------
__global__ __launch_bounds__(256) void ln_kernel(const float* __restrict__ agg,
                                                 const float* __restrict__ g,
                                                 const float* __restrict__ b,
                                                 float* __restrict__ x,
                                                 int n) {
  int wid = (int)(((size_t)blockIdx.x * 256 + threadIdx.x) >> 6);
  int lane = threadIdx.x & 63;
  if (wid >= n) return;
  const float* ap = agg + (size_t)wid * DD;
  float v0 = ap[lane], v1 = ap[lane + 64];
  float s = v0 + v1;
  #pragma unroll
  for (int o = 1; o < 64; o <<= 1) s += __shfl_xor(s, o);
  float mean = s * (1.0f / DD);
  float d0 = v0 - mean, d1 = v1 - mean;
  float sq = d0 * d0 + d1 * d1;
  #pragma unroll
  for (int o = 1; o < 64; o <<= 1) sq += __shfl_xor(sq, o);
  float rstd = rsqrtf(sq * (1.0f / DD) + 1e-5f);
  float* xp = x + (size_t)wid * DD;
  xp[lane]      = g[lane]      * d0 * rstd + b[lane]      + xp[lane];
  xp[lane + 64] = g[lane + 64] * d1 * rstd + b[lane + 64] + xp[lane + 64];
}

extern "C" void kernel_launch(void* const* d_in, const int* in_sizes, int n_in,
                              void* d_out, int out_size, void* d_ws, size_t ws_size,
                              hipStream_t stream) {
  const float* emb_user = (const float*)d_in[0];
  const float* tv_tweet = (const float*)d_in[1];
  const float* W_qkv  = (const float*)d_in[2];
  const float* b_qkv  = (const float*)d_in[3];
  const float* W_skip = (const float*)d_in[4];
  const float* b_skip = (const float*)d_in[5];
  const float* ln_g   = (const float*)d_in[6];
  const float* ln_b   = (const float*)d_in[7];
  const int* edges[3] = { (const int*)d_in[8], (const int*)d_in[9], (const int*)d_in[10] };

  float* x_user  = (float*)d_out;
  float* x_tweet = x_user + (size_t)NUU * DD;

  // ---- workspace layout ----
  const size_t wtqB = (size_t)18 * 512 * 128 * 2;   // 2,359,296
  const size_t wtsB = (size_t)6 * 128 * 128 * 2;    //   196,608
  auto need = [&](int hb) -> size_t {
    return wtqB + wtsB + (size_t)3 * 25600000 * hb + 76800000 + (size_t)3 * 400000 * hb + 4096;
  };
  int HB = (ws_size >= need(4)) ? 4 : (ws_size >= need(2)) ? 2 : 1;
  int HSH = (HB == 4) ? 2 : (HB == 2) ? 1 : 0;

  char* w = (char*)d_ws;
  u16* Wtq = (u16*)w;       w += wtqB;
  u16* Wts = (u16*)w;       w += wtsB;
  size_t qkvBytes = (size_t)100000 * HB * DD * 2;
  u16* qb = (u16*)w;        w += qkvBytes;
  u16* kb = (u16*)w;        w += qkvBytes;
  u16* vb = (u16*)w;        w += qkvBytes;
  float* agg_u = (float*)w; w += (size_t)NUU * DD * 4;
  float* agg_t = (float*)w; w += (size_t)NTT * DD * 4;
  float* lgb = (float*)w;   w += (size_t)EE * HB * 4;
  u32* mm = (u32*)w;        w += (size_t)100000 * HB * 4;
  float* zb = (float*)w;

  init_x<<<(19200000 + 255) / 256, 256, 0, stream>>>(emb_user, tv_tweet, x_user, x_tweet);
  conv_w<<<(18 * 512 * 128 + 255) / 256, 256, 0, stream>>>(W_qkv, W_skip, Wtq, Wts);

  const int stt[3] = {0, 0, 1}, dtt[3] = {0, 1, 0};
  const int cnt[2] = {NUU, NTT};
  float* xs[2]   = {x_user, x_tweet};
  float* aggs[2] = {agg_u, agg_t};

  for (int l = 0; l < 2; ++l) {
    hipMemsetAsync(agg_u, 0, (size_t)NUU * DD * 4, stream);
    hipMemsetAsync(agg_t, 0, (size_t)NTT * DD * 4, stream);
    for (int r = 0; r < 3; ++r) {
      const int st = stt[r], dt = dtt[r];
      const int ns = cnt[st], nd = cnt[dt];
      const int mat = l * 3 + r;
      const u16* WtQ = Wtq + (size_t)(mat * 3 + 0) * 512 * 128;
      const u16* WtK = Wtq + (size_t)(mat * 3 + 1) * 512 * 128;
      const u16* WtV = Wtq + (size_t)(mat * 3 + 2) * 512 * 128;
      const float* bq = b_qkv + (size_t)(mat * 3 + 0) * HCC;
      const float* bk = b_qkv + (size_t)(mat * 3 + 1) * HCC;
      const float* bv = b_qkv + (size_t)(mat * 3 + 2) * HCC;
      const u16* WtS = Wts + (size_t)mat * 128 * 128;
      const float* bsk = b_skip + (size_t)mat * DD;

      for (int h0 = 0; h0 < HH; h0 += HB) {
        hipMemsetAsync(mm, 0, (size_t)nd * HB * 4, stream);
        hipMemsetAsync(zb, 0, (size_t)nd * HB * 4, stream);

        const int ldy = HB * DD, col0 = h0 * DD;
        dim3 gq((nd + 127) / 128, ldy / 128), gs((ns + 127) / 128, ldy / 128);
        gemm_qkv_mfma<<<gq, 256, 0, stream>>>(xs[dt], WtQ, bq, qb, nd, ldy, col0);
        gemm_qkv_mfma<<<gs, 256, 0, stream>>>(xs[st], WtK, bk, kb, ns, ldy, col0);
        gemm_qkv_mfma<<<gs, 256, 0, stream>>>(xs[st], WtV, bv, vb, ns, ldy, col0);

        logits_kernel<<<EE / 4, 256, 0, stream>>>(qb, kb, edges[r], edges[r] + EE, lgb, mm, HB);
        z_kernel<<<(EE * HB + 255) / 256, 256, 0, stream>>>(edges[r] + EE, lgb, mm, zb, HB, HSH);
        scatter_kernel<<<EE / 4, 256, 0, stream>>>(vb, edges[r], edges[r] + EE, lgb, zb, aggs[dt], HB);
      }

      gemm_skip_mfma<<<(nd + 127) / 128, 256, 0, stream>>>(xs[dt], WtS, bsk, aggs[dt], nd);
    }
    ln_kernel<<<(NUU + 3) / 4, 256, 0, stream>>>(agg_u, ln_g + (size_t)(l * 2 + 0) * DD,
                                                 ln_b + (size_t)(l * 2 + 0) * DD, x_user, NUU);
    ln_kernel<<<(NTT + 3) / 4, 256, 0, stream>>>(agg_t, ln_g + (size_t)(l * 2 + 1) * DD,
                                                 ln_b + (size_t)(l * 2 + 1) * DD, x_tweet, NTT);
  }
}

// Round 4
// 1914.292 us; speedup vs baseline: 2.1645x; 1.6776x over previous
//
#include <hip/hip_runtime.h>
#include <hip/hip_bf16.h>
#include <math.h>

typedef unsigned short u16;
typedef unsigned int   u32;
typedef __attribute__((ext_vector_type(8))) short s8v;   // 8 x bf16 (4 VGPR)
typedef __attribute__((ext_vector_type(4))) float f4v;   // MFMA accumulator

#define NUU 50000
#define NTT 100000
#define EE  100000
#define DD  128
#define HH  4
#define HCC 512

// ---------- helpers ----------
__device__ __forceinline__ float bflo(u32 u) { return __uint_as_float(u << 16); }
__device__ __forceinline__ float bfhi(u32 u) { return __uint_as_float(u & 0xFFFF0000u); }
__device__ __forceinline__ u16 f2bf(float f) {
  u32 u = __float_as_uint(f);
  u32 r = (u + 0x7FFFu + ((u >> 16) & 1u)) >> 16;
  return (u16)r;
}
__device__ __forceinline__ s8v cvt_row8(const float* __restrict__ p) {
  s8v r;
  #pragma unroll
  for (int i = 0; i < 8; ++i) r[i] = (short)f2bf(p[i]);
  return r;
}

// ---------- init: x_user = emb_user ; x_tweet[i,:] = tv_tweet ----------
__global__ __launch_bounds__(256) void init_x(const float* __restrict__ emb,
                                              const float* __restrict__ tv,
                                              float* __restrict__ xu,
                                              float* __restrict__ xt) {
  size_t idx = (size_t)blockIdx.x * 256 + threadIdx.x;
  size_t nu = (size_t)NUU * DD;
  size_t nt = (size_t)NTT * DD;
  if (idx < nu) {
    xu[idx] = emb[idx];
  } else {
    size_t j = idx - nu;
    if (j < nt) xt[j] = tv[j & (DD - 1)];
  }
}

// ---------- convert weights to bf16, transposed: Wt[mat][col][k] ----------
__global__ __launch_bounds__(256) void conv_w(const float* __restrict__ Wq,
                                              const float* __restrict__ Wsk,
                                              u16* __restrict__ Wtq,
                                              u16* __restrict__ Wts) {
  int idx = blockIdx.x * 256 + threadIdx.x;
  if (idx < 18 * 512 * 128) {
    int k = idx & 127, col = (idx >> 7) & 511, mat = idx >> 16;
    Wtq[idx] = f2bf(Wq[((size_t)mat * 128 + k) * 512 + col]);
  }
  if (idx < 6 * 128 * 128) {
    int k = idx & 127, col = (idx >> 7) & 127, mat = idx >> 14;
    Wts[idx] = f2bf(Wsk[((size_t)mat * 128 + k) * 128 + col]);
  }
}

// ---------- CSR build ----------
__global__ __launch_bounds__(256) void hist_kernel(const int* __restrict__ edst,
                                                   int* __restrict__ cnt) {
  int e = blockIdx.x * 256 + threadIdx.x;
  if (e < EE) atomicAdd(&cnt[edst[e]], 1);
}

__global__ __launch_bounds__(256) void bsum_kernel(const int* __restrict__ cnt, int n,
                                                   int* __restrict__ bsum) {
  int i = blockIdx.x * 256 + threadIdx.x;
  int v = (i < n) ? cnt[i] : 0;
  #pragma unroll
  for (int o = 1; o < 64; o <<= 1) v += __shfl_xor(v, o);
  __shared__ int ws4[4];
  if ((threadIdx.x & 63) == 0) ws4[threadIdx.x >> 6] = v;
  __syncthreads();
  if (threadIdx.x == 0) bsum[blockIdx.x] = ws4[0] + ws4[1] + ws4[2] + ws4[3];
}

// exclusive scan of bsum[0..nb), single block of 256
__global__ __launch_bounds__(256) void bscan_kernel(int* __restrict__ bsum, int nb) {
  __shared__ int sh[256];
  __shared__ int runs;
  if (threadIdx.x == 0) runs = 0;
  __syncthreads();
  for (int base = 0; base < nb; base += 256) {
    int i = base + threadIdx.x;
    int v = (i < nb) ? bsum[i] : 0;
    sh[threadIdx.x] = v;
    __syncthreads();
    for (int o = 1; o < 256; o <<= 1) {
      int t = (threadIdx.x >= o) ? sh[threadIdx.x - o] : 0;
      __syncthreads();
      sh[threadIdx.x] += t;
      __syncthreads();
    }
    int incl = sh[threadIdx.x];
    int r0 = runs;
    if (i < nb) bsum[i] = r0 + incl - v;
    __syncthreads();
    if (threadIdx.x == 0) runs = r0 + sh[255];
    __syncthreads();
  }
}

__global__ __launch_bounds__(256) void rptr_kernel(const int* __restrict__ cnt,
                                                   const int* __restrict__ bsum,
                                                   int* __restrict__ rptr,
                                                   int* __restrict__ cursor, int n) {
  __shared__ int sh[256];
  int i = blockIdx.x * 256 + threadIdx.x;
  int v = (i < n) ? cnt[i] : 0;
  sh[threadIdx.x] = v;
  __syncthreads();
  for (int o = 1; o < 256; o <<= 1) {
    int t = (threadIdx.x >= o) ? sh[threadIdx.x - o] : 0;
    __syncthreads();
    sh[threadIdx.x] += t;
    __syncthreads();
  }
  int excl = sh[threadIdx.x] - v + bsum[blockIdx.x];
  if (i < n) { rptr[i] = excl; cursor[i] = excl; }
  if (i == 0) rptr[n] = EE;
}

__global__ __launch_bounds__(256) void fill_kernel(const int* __restrict__ esrc,
                                                   const int* __restrict__ edst,
                                                   int* __restrict__ cursor,
                                                   int* __restrict__ csrc) {
  int e = blockIdx.x * 256 + threadIdx.x;
  if (e < EE) {
    int pos = atomicAdd(&cursor[edst[e]], 1);
    csrc[pos] = esrc[e];
  }
}

// ---------- MFMA QKV GEMM: Y[n,ldy](bf16) = bf16(X[n,128]) @ Wt^T + bias ----------
__global__ __launch_bounds__(256) void gemm_qkv_mfma(const float* __restrict__ X,
                                                     const u16* __restrict__ Wt,
                                                     const float* __restrict__ bias,
                                                     u16* __restrict__ Y,
                                                     int n, int ldy, int col0) {
  const int bm = blockIdx.x * 128;
  const int bn = blockIdx.y * 128;
  const int wid = threadIdx.x >> 6, lane = threadIdx.x & 63;
  const int l15 = lane & 15, l4 = lane >> 4;
  const int rbase = bm + wid * 32;
  f4v acc[2][8] = {};
  int r0 = rbase + l15;      if (r0 >= n) r0 = n - 1;
  int r1 = rbase + 16 + l15; if (r1 >= n) r1 = n - 1;
  const float* xp0 = X + (size_t)r0 * DD + l4 * 8;
  const float* xp1 = X + (size_t)r1 * DD + l4 * 8;
  const u16* wp = Wt + (size_t)(col0 + bn + l15) * DD + l4 * 8;

  #pragma unroll
  for (int kk = 0; kk < 4; ++kk) {
    s8v a0 = cvt_row8(xp0 + kk * 32);
    s8v a1 = cvt_row8(xp1 + kk * 32);
    #pragma unroll
    for (int nn = 0; nn < 8; ++nn) {
      s8v b = *(const s8v*)(wp + (size_t)nn * 16 * DD + kk * 32);
      acc[0][nn] = __builtin_amdgcn_mfma_f32_16x16x32_bf16(a0, b, acc[0][nn], 0, 0, 0);
      acc[1][nn] = __builtin_amdgcn_mfma_f32_16x16x32_bf16(a1, b, acc[1][nn], 0, 0, 0);
    }
  }

  float bv[8];
  #pragma unroll
  for (int nn = 0; nn < 8; ++nn) bv[nn] = bias[col0 + bn + nn * 16 + l15];
  #pragma unroll
  for (int m = 0; m < 2; ++m) {
    #pragma unroll
    for (int j = 0; j < 4; ++j) {
      int r = rbase + m * 16 + l4 * 4 + j;
      if (r >= n) continue;
      u16* yp = Y + (size_t)r * ldy + bn + l15;
      #pragma unroll
      for (int nn = 0; nn < 8; ++nn) yp[nn * 16] = f2bf(acc[m][nn][j] + bv[nn]);
    }
  }
}

// ---------- MFMA skip GEMM: agg[n,128] += bf16(X) @ Wt^T + bias ----------
__global__ __launch_bounds__(256) void gemm_skip_mfma(const float* __restrict__ X,
                                                      const u16* __restrict__ Wt,
                                                      const float* __restrict__ bias,
                                                      float* __restrict__ agg, int n) {
  const int bm = blockIdx.x * 128;
  const int wid = threadIdx.x >> 6, lane = threadIdx.x & 63;
  const int l15 = lane & 15, l4 = lane >> 4;
  const int rbase = bm + wid * 32;
  f4v acc[2][8] = {};
  int r0 = rbase + l15;      if (r0 >= n) r0 = n - 1;
  int r1 = rbase + 16 + l15; if (r1 >= n) r1 = n - 1;
  const float* xp0 = X + (size_t)r0 * DD + l4 * 8;
  const float* xp1 = X + (size_t)r1 * DD + l4 * 8;
  const u16* wp = Wt + (size_t)l15 * DD + l4 * 8;

  #pragma unroll
  for (int kk = 0; kk < 4; ++kk) {
    s8v a0 = cvt_row8(xp0 + kk * 32);
    s8v a1 = cvt_row8(xp1 + kk * 32);
    #pragma unroll
    for (int nn = 0; nn < 8; ++nn) {
      s8v b = *(const s8v*)(wp + (size_t)nn * 16 * DD + kk * 32);
      acc[0][nn] = __builtin_amdgcn_mfma_f32_16x16x32_bf16(a0, b, acc[0][nn], 0, 0, 0);
      acc[1][nn] = __builtin_amdgcn_mfma_f32_16x16x32_bf16(a1, b, acc[1][nn], 0, 0, 0);
    }
  }

  float bv[8];
  #pragma unroll
  for (int nn = 0; nn < 8; ++nn) bv[nn] = bias[nn * 16 + l15];
  #pragma unroll
  for (int m = 0; m < 2; ++m) {
    #pragma unroll
    for (int j = 0; j < 4; ++j) {
      int r = rbase + m * 16 + l4 * 4 + j;
      if (r >= n) continue;
      float* yp = agg + (size_t)r * DD + l15;
      #pragma unroll
      for (int nn = 0; nn < 8; ++nn) yp[nn * 16] += acc[m][nn][j] + bv[nn];
    }
  }
}

// ---------- fused edge kernel: one wave per dst node ----------
// q/k/v layout [n][HB*128] bf16; qs32/ks32 = row stride in u32 (0 => broadcast row 0)
template<int HB>
__global__ __launch_bounds__(256) void edge_fused(const u16* __restrict__ q,
                                                  const u16* __restrict__ k,
                                                  const u16* __restrict__ v,
                                                  const int* __restrict__ rptr,
                                                  const int* __restrict__ csrc,
                                                  float* __restrict__ agg,
                                                  int nd, int qs32, int ks32) {
  constexpr int LPH = 64 / HB;          // lanes per head
  int node = (int)(((size_t)blockIdx.x * 256 + threadIdx.x) >> 6);
  int lane = threadIdx.x & 63;
  if (node >= nd) return;
  int e0 = rptr[node], e1 = rptr[node + 1];
  if (e0 == e1) return;

  const u32* qp = (const u32*)q + (size_t)node * qs32 + lane * HB;
  u32 qv[HB];
  #pragma unroll
  for (int j = 0; j < HB; ++j) qv[j] = qp[j];

  float m = -1e30f, z = 0.f;
  float acc[2 * HB] = {};
  for (int e = e0; e < e1; ++e) {
    int s = csrc[e];
    const u32* kp = (const u32*)k + (size_t)s * ks32 + lane * HB;
    float dot = 0.f;
    #pragma unroll
    for (int j = 0; j < HB; ++j) {
      u32 ku = kp[j];
      dot += bflo(qv[j]) * bflo(ku) + bfhi(qv[j]) * bfhi(ku);
    }
    #pragma unroll
    for (int o = 1; o < LPH; o <<= 1) dot += __shfl_xor(dot, o);
    dot *= 0.08838834764831845f;   // 1/sqrt(128)
    float w;
    if (dot > m) {
      float sc = __expf(m - dot);
      z *= sc;
      #pragma unroll
      for (int j = 0; j < 2 * HB; ++j) acc[j] *= sc;
      m = dot; w = 1.f;
    } else {
      w = __expf(dot - m);
    }
    z += w;
    const u32* vp = (const u32*)v + (size_t)s * ks32 + lane * HB;
    #pragma unroll
    for (int j = 0; j < HB; ++j) {
      u32 vu = vp[j];
      acc[2 * j]     += w * bflo(vu);
      acc[2 * j + 1] += w * bfhi(vu);
    }
  }
  float inv = 0.25f / z;   // 1/H head-mean factor (H=4 overall)
  #pragma unroll
  for (int j = 0; j < 2 * HB; ++j) acc[j] *= inv;
  // sum across head groups
  #pragma unroll
  for (int o = LPH; o < 64; o <<= 1) {
    #pragma unroll
    for (int j = 0; j < 2 * HB; ++j) acc[j] += __shfl_xor(acc[j], o);
  }
  if (lane < LPH) {
    float* op = agg + (size_t)node * DD + lane * 2 * HB;
    #pragma unroll
    for (int j = 0; j < 2 * HB; ++j) op[j] += acc[j];
  }
}

// ---------- LayerNorm + residual, one wave per node ----------
__global__ __launch_bounds__(256) void ln_kernel(const float* __restrict__ agg,
                                                 const float* __restrict__ g,
                                                 const float* __restrict__ b,
                                                 float* __restrict__ x,
                                                 int n) {
  int wid = (int)(((size_t)blockIdx.x * 256 + threadIdx.x) >> 6);
  int lane = threadIdx.x & 63;
  if (wid >= n) return;
  const float* ap = agg + (size_t)wid * DD;
  float v0 = ap[lane], v1 = ap[lane + 64];
  float s = v0 + v1;
  #pragma unroll
  for (int o = 1; o < 64; o <<= 1) s += __shfl_xor(s, o);
  float mean = s * (1.0f / DD);
  float d0 = v0 - mean, d1 = v1 - mean;
  float sq = d0 * d0 + d1 * d1;
  #pragma unroll
  for (int o = 1; o < 64; o <<= 1) sq += __shfl_xor(sq, o);
  float rstd = rsqrtf(sq * (1.0f / DD) + 1e-5f);
  float* xp = x + (size_t)wid * DD;
  xp[lane]      = g[lane]      * d0 * rstd + b[lane]      + xp[lane];
  xp[lane + 64] = g[lane + 64] * d1 * rstd + b[lane + 64] + xp[lane + 64];
}

extern "C" void kernel_launch(void* const* d_in, const int* in_sizes, int n_in,
                              void* d_out, int out_size, void* d_ws, size_t ws_size,
                              hipStream_t stream) {
  const float* emb_user = (const float*)d_in[0];
  const float* tv_tweet = (const float*)d_in[1];
  const float* W_qkv  = (const float*)d_in[2];
  const float* b_qkv  = (const float*)d_in[3];
  const float* W_skip = (const float*)d_in[4];
  const float* b_skip = (const float*)d_in[5];
  const float* ln_g   = (const float*)d_in[6];
  const float* ln_b   = (const float*)d_in[7];
  const int* edges[3] = { (const int*)d_in[8], (const int*)d_in[9], (const int*)d_in[10] };

  float* x_user  = (float*)d_out;
  float* x_tweet = x_user + (size_t)NUU * DD;

  // ---- workspace layout ----
  const size_t wtqB = (size_t)18 * 512 * 128 * 2;
  const size_t wtsB = (size_t)6 * 128 * 128 * 2;
  const size_t csrB = (size_t)3 * 100008 * 4 + (size_t)3 * 100000 * 4
                    + (size_t)2 * 100000 * 4 + 1600;
  auto need = [&](int hb) -> size_t {
    return wtqB + wtsB + (size_t)3 * 25600000 * hb + 76800000 + csrB + 4096;
  };
  int HB = (ws_size >= need(4)) ? 4 : (ws_size >= need(2)) ? 2 : 1;

  char* w = (char*)d_ws;
  u16* Wtq = (u16*)w;       w += wtqB;
  u16* Wts = (u16*)w;       w += wtsB;
  size_t qkvBytes = (size_t)100000 * HB * DD * 2;
  u16* qb = (u16*)w;        w += qkvBytes;
  u16* kb = (u16*)w;        w += qkvBytes;
  u16* vb = (u16*)w;        w += qkvBytes;
  float* agg_u = (float*)w; w += (size_t)NUU * DD * 4;
  float* agg_t = (float*)w; w += (size_t)NTT * DD * 4;
  int* rptrA[3]; int* csrcA[3];
  for (int r = 0; r < 3; ++r) { rptrA[r] = (int*)w; w += 100008 * 4; }
  for (int r = 0; r < 3; ++r) { csrcA[r] = (int*)w; w += 100000 * 4; }
  int* cnt = (int*)w;       w += 100000 * 4;
  int* cursor = (int*)w;    w += 100000 * 4;
  int* bsum = (int*)w;      /* 400 ints */

  init_x<<<(19200000 + 255) / 256, 256, 0, stream>>>(emb_user, tv_tweet, x_user, x_tweet);
  conv_w<<<(18 * 512 * 128 + 255) / 256, 256, 0, stream>>>(W_qkv, W_skip, Wtq, Wts);

  const int stt[3] = {0, 0, 1}, dtt[3] = {0, 1, 0};
  const int cnt2[2] = {NUU, NTT};
  float* xs[2]   = {x_user, x_tweet};
  float* aggs[2] = {agg_u, agg_t};

  // ---- build CSR per relation (edge lists are launch-constant) ----
  for (int r = 0; r < 3; ++r) {
    const int nd = cnt2[dtt[r]];
    const int* edst = edges[r] + EE;
    const int nb = (nd + 255) / 256;
    hipMemsetAsync(cnt, 0, (size_t)nd * 4, stream);
    hist_kernel<<<(EE + 255) / 256, 256, 0, stream>>>(edst, cnt);
    bsum_kernel<<<nb, 256, 0, stream>>>(cnt, nd, bsum);
    bscan_kernel<<<1, 256, 0, stream>>>(bsum, nb);
    rptr_kernel<<<nb, 256, 0, stream>>>(cnt, bsum, rptrA[r], cursor, nd);
    fill_kernel<<<(EE + 255) / 256, 256, 0, stream>>>(edges[r], edst, cursor, csrcA[r]);
  }

  for (int l = 0; l < 2; ++l) {
    hipMemsetAsync(agg_u, 0, (size_t)NUU * DD * 4, stream);
    hipMemsetAsync(agg_t, 0, (size_t)NTT * DD * 4, stream);
    for (int r = 0; r < 3; ++r) {
      const int st = stt[r], dt = dtt[r];
      const int ns = cnt2[st], nd = cnt2[dt];
      const int mat = l * 3 + r;
      const u16* WtQ = Wtq + (size_t)(mat * 3 + 0) * 512 * 128;
      const u16* WtK = Wtq + (size_t)(mat * 3 + 1) * 512 * 128;
      const u16* WtV = Wtq + (size_t)(mat * 3 + 2) * 512 * 128;
      const float* bq = b_qkv + (size_t)(mat * 3 + 0) * HCC;
      const float* bk = b_qkv + (size_t)(mat * 3 + 1) * HCC;
      const float* bv = b_qkv + (size_t)(mat * 3 + 2) * HCC;
      const u16* WtS = Wts + (size_t)mat * 128 * 128;
      const float* bsk = b_skip + (size_t)mat * DD;

      // layer-0 degeneracy: all x_tweet rows identical -> single-row GEMM + stride-0
      const bool qDeg = (l == 0 && dt == 1);   // ut: q over tweets
      const bool kDeg = (l == 0 && st == 1);   // tu: k,v over tweets
      for (int h0 = 0; h0 < HH; h0 += HB) {
        const int ldy = HB * DD, col0 = h0 * DD;
        const int nq = qDeg ? 1 : nd;
        const int nk = kDeg ? 1 : ns;
        dim3 gq((nq + 127) / 128, ldy / 128), gs((nk + 127) / 128, ldy / 128);
        gemm_qkv_mfma<<<gq, 256, 0, stream>>>(xs[dt], WtQ, bq, qb, nq, ldy, col0);
        gemm_qkv_mfma<<<gs, 256, 0, stream>>>(xs[st], WtK, bk, kb, nk, ldy, col0);
        gemm_qkv_mfma<<<gs, 256, 0, stream>>>(xs[st], WtV, bv, vb, nk, ldy, col0);

        const int qs32 = qDeg ? 0 : HB * DD / 2;
        const int ks32 = kDeg ? 0 : HB * DD / 2;
        const int eblk = (nd + 3) / 4;
        if (HB == 4)
          edge_fused<4><<<eblk, 256, 0, stream>>>(qb, kb, vb, rptrA[r], csrcA[r], aggs[dt], nd, qs32, ks32);
        else if (HB == 2)
          edge_fused<2><<<eblk, 256, 0, stream>>>(qb, kb, vb, rptrA[r], csrcA[r], aggs[dt], nd, qs32, ks32);
        else
          edge_fused<1><<<eblk, 256, 0, stream>>>(qb, kb, vb, rptrA[r], csrcA[r], aggs[dt], nd, qs32, ks32);
      }

      gemm_skip_mfma<<<(nd + 127) / 128, 256, 0, stream>>>(xs[dt], WtS, bsk, aggs[dt], nd);
    }
    ln_kernel<<<(NUU + 3) / 4, 256, 0, stream>>>(agg_u, ln_g + (size_t)(l * 2 + 0) * DD,
                                                 ln_b + (size_t)(l * 2 + 0) * DD, x_user, NUU);
    ln_kernel<<<(NTT + 3) / 4, 256, 0, stream>>>(agg_t, ln_g + (size_t)(l * 2 + 1) * DD,
                                                 ln_b + (size_t)(l * 2 + 1) * DD, x_tweet, NTT);
  }
}

// Round 5
// 1757.367 us; speedup vs baseline: 2.3578x; 1.0893x over previous
//
#include <hip/hip_runtime.h>
#include <hip/hip_bf16.h>
#include <math.h>

typedef unsigned short u16;
typedef unsigned int   u32;
typedef __attribute__((ext_vector_type(8))) short s8v;   // 8 x bf16 (4 VGPR)
typedef __attribute__((ext_vector_type(4))) float f4v;   // MFMA accumulator

#define NUU 50000
#define NTT 100000
#define EE  100000
#define DD  128
#define HH  4
#define HCC 512

// ---------- helpers ----------
__device__ __forceinline__ float bflo(u32 u) { return __uint_as_float(u << 16); }
__device__ __forceinline__ float bfhi(u32 u) { return __uint_as_float(u & 0xFFFF0000u); }
__device__ __forceinline__ u16 f2bf(float f) {
  u32 u = __float_as_uint(f);
  u32 r = (u + 0x7FFFu + ((u >> 16) & 1u)) >> 16;
  return (u16)r;
}
__device__ __forceinline__ s8v cvt_row8(const float* __restrict__ p) {
  s8v r;
  #pragma unroll
  for (int i = 0; i < 8; ++i) r[i] = (short)f2bf(p[i]);
  return r;
}

// ---------- init: x_user = emb_user ; x_tweet[i,:] = tv_tweet ----------
__global__ __launch_bounds__(256) void init_x(const float* __restrict__ emb,
                                              const float* __restrict__ tv,
                                              float* __restrict__ xu,
                                              float* __restrict__ xt) {
  size_t idx = (size_t)blockIdx.x * 256 + threadIdx.x;
  size_t nu = (size_t)NUU * DD;
  size_t nt = (size_t)NTT * DD;
  if (idx < nu) {
    xu[idx] = emb[idx];
  } else {
    size_t j = idx - nu;
    if (j < nt) xt[j] = tv[j & (DD - 1)];
  }
}

// ---------- convert weights to bf16, transposed: Wt[mat][col][k] ----------
__global__ __launch_bounds__(256) void conv_w(const float* __restrict__ Wq,
                                              const float* __restrict__ Wsk,
                                              u16* __restrict__ Wtq,
                                              u16* __restrict__ Wts) {
  int idx = blockIdx.x * 256 + threadIdx.x;
  if (idx < 18 * 512 * 128) {
    int k = idx & 127, col = (idx >> 7) & 511, mat = idx >> 16;
    Wtq[idx] = f2bf(Wq[((size_t)mat * 128 + k) * 512 + col]);
  }
  if (idx < 6 * 128 * 128) {
    int k = idx & 127, col = (idx >> 7) & 127, mat = idx >> 14;
    Wts[idx] = f2bf(Wsk[((size_t)mat * 128 + k) * 128 + col]);
  }
}

// ---------- CSR build ----------
__global__ __launch_bounds__(256) void hist_kernel(const int* __restrict__ edst,
                                                   int* __restrict__ cnt) {
  int e = blockIdx.x * 256 + threadIdx.x;
  if (e < EE) atomicAdd(&cnt[edst[e]], 1);
}

__global__ __launch_bounds__(256) void bsum_kernel(const int* __restrict__ cnt, int n,
                                                   int* __restrict__ bsum) {
  int i = blockIdx.x * 256 + threadIdx.x;
  int v = (i < n) ? cnt[i] : 0;
  #pragma unroll
  for (int o = 1; o < 64; o <<= 1) v += __shfl_xor(v, o);
  __shared__ int ws4[4];
  if ((threadIdx.x & 63) == 0) ws4[threadIdx.x >> 6] = v;
  __syncthreads();
  if (threadIdx.x == 0) bsum[blockIdx.x] = ws4[0] + ws4[1] + ws4[2] + ws4[3];
}

__global__ __launch_bounds__(256) void bscan_kernel(int* __restrict__ bsum, int nb) {
  __shared__ int sh[256];
  __shared__ int runs;
  if (threadIdx.x == 0) runs = 0;
  __syncthreads();
  for (int base = 0; base < nb; base += 256) {
    int i = base + threadIdx.x;
    int v = (i < nb) ? bsum[i] : 0;
    sh[threadIdx.x] = v;
    __syncthreads();
    for (int o = 1; o < 256; o <<= 1) {
      int t = (threadIdx.x >= o) ? sh[threadIdx.x - o] : 0;
      __syncthreads();
      sh[threadIdx.x] += t;
      __syncthreads();
    }
    int incl = sh[threadIdx.x];
    int r0 = runs;
    if (i < nb) bsum[i] = r0 + incl - v;
    __syncthreads();
    if (threadIdx.x == 0) runs = r0 + sh[255];
    __syncthreads();
  }
}

__global__ __launch_bounds__(256) void rptr_kernel(const int* __restrict__ cnt,
                                                   const int* __restrict__ bsum,
                                                   int* __restrict__ rptr,
                                                   int* __restrict__ cursor, int n) {
  __shared__ int sh[256];
  int i = blockIdx.x * 256 + threadIdx.x;
  int v = (i < n) ? cnt[i] : 0;
  sh[threadIdx.x] = v;
  __syncthreads();
  for (int o = 1; o < 256; o <<= 1) {
    int t = (threadIdx.x >= o) ? sh[threadIdx.x - o] : 0;
    __syncthreads();
    sh[threadIdx.x] += t;
    __syncthreads();
  }
  int excl = sh[threadIdx.x] - v + bsum[blockIdx.x];
  if (i < n) { rptr[i] = excl; cursor[i] = excl; }
  if (i == 0) rptr[n] = EE;
}

__global__ __launch_bounds__(256) void fill_kernel(const int* __restrict__ esrc,
                                                   const int* __restrict__ edst,
                                                   int* __restrict__ cursor,
                                                   int* __restrict__ csrc) {
  int e = blockIdx.x * 256 + threadIdx.x;
  if (e < EE) {
    int pos = atomicAdd(&cursor[edst[e]], 1);
    csrc[pos] = esrc[e];
  }
}

// ---------- fused QKV GEMM (swapped-operand MFMA, ushort4 stores) ----------
// Grid: (ceil(n/128), nm). mat = mat0+blockIdx.y selects W/bias/output.
// Wfam: [3][512][128] bf16 (col-major-by-k). Y row stride = ldy, cols [0,ldy).
__global__ __launch_bounds__(256) void gemm_qkv3(const float* __restrict__ X,
                                                 const u16* __restrict__ Wfam,
                                                 const float* __restrict__ bfam,
                                                 u16* __restrict__ oq,
                                                 u16* __restrict__ ok,
                                                 u16* __restrict__ ov,
                                                 int n, int ldy, int col0, int mat0) {
  const int bm = blockIdx.x * 128;
  const int matA = mat0 + blockIdx.y;
  const u16* Wt = Wfam + (size_t)matA * 512 * 128;
  const float* bias = bfam + (size_t)matA * HCC + col0;
  u16* Y = (matA == 0) ? oq : (matA == 1) ? ok : ov;

  const int wid = threadIdx.x >> 6, lane = threadIdx.x & 63;
  const int l15 = lane & 15, l4 = lane >> 4;
  const int rbase = bm + wid * 32;
  int r0 = rbase + l15;      if (r0 >= n) r0 = n - 1;
  int r1 = rbase + 16 + l15; if (r1 >= n) r1 = n - 1;
  const float* xp0 = X + (size_t)r0 * DD + l4 * 8;
  const float* xp1 = X + (size_t)r1 * DD + l4 * 8;
  s8v a0[4], a1[4];
  #pragma unroll
  for (int kk = 0; kk < 4; ++kk) {
    a0[kk] = cvt_row8(xp0 + kk * 32);
    a1[kk] = cvt_row8(xp1 + kk * 32);
  }

  const u16* wp = Wt + (size_t)(col0 + l15) * DD + l4 * 8;
  const bool ok0 = (rbase + l15 < n), ok1 = (rbase + 16 + l15 < n);
  u16* yp0 = Y + (size_t)(rbase + l15) * ldy + l4 * 4;
  u16* yp1 = Y + (size_t)(rbase + 16 + l15) * ldy + l4 * 4;
  const int nnN = ldy >> 4;

  for (int nn = 0; nn < nnN; ++nn) {
    f4v acc0 = {}, acc1 = {};
    const u16* wpn = wp + (size_t)nn * 16 * DD;
    #pragma unroll
    for (int kk = 0; kk < 4; ++kk) {
      s8v b = *(const s8v*)(wpn + kk * 32);
      acc0 = __builtin_amdgcn_mfma_f32_16x16x32_bf16(b, a0[kk], acc0, 0, 0, 0);
      acc1 = __builtin_amdgcn_mfma_f32_16x16x32_bf16(b, a1[kk], acc1, 0, 0, 0);
    }
    const float4 bb = *(const float4*)(bias + nn * 16 + l4 * 4);
    if (ok0) {
      ushort4 pk;
      pk.x = f2bf(acc0[0] + bb.x);
      pk.y = f2bf(acc0[1] + bb.y);
      pk.z = f2bf(acc0[2] + bb.z);
      pk.w = f2bf(acc0[3] + bb.w);
      *(ushort4*)(yp0 + nn * 16) = pk;
    }
    if (ok1) {
      ushort4 pk;
      pk.x = f2bf(acc1[0] + bb.x);
      pk.y = f2bf(acc1[1] + bb.y);
      pk.z = f2bf(acc1[2] + bb.z);
      pk.w = f2bf(acc1[3] + bb.w);
      *(ushort4*)(yp1 + nn * 16) = pk;
    }
  }
}

// ---------- skip GEMM (swapped-operand, float4 RMW): agg += bf16(X)@Wt^T + bias ----------
__global__ __launch_bounds__(256) void gemm_skip2(const float* __restrict__ X,
                                                  const u16* __restrict__ Wt,
                                                  const float* __restrict__ bias,
                                                  float* __restrict__ agg, int n) {
  const int bm = blockIdx.x * 128;
  const int wid = threadIdx.x >> 6, lane = threadIdx.x & 63;
  const int l15 = lane & 15, l4 = lane >> 4;
  const int rbase = bm + wid * 32;
  int r0 = rbase + l15;      if (r0 >= n) r0 = n - 1;
  int r1 = rbase + 16 + l15; if (r1 >= n) r1 = n - 1;
  const float* xp0 = X + (size_t)r0 * DD + l4 * 8;
  const float* xp1 = X + (size_t)r1 * DD + l4 * 8;
  s8v a0[4], a1[4];
  #pragma unroll
  for (int kk = 0; kk < 4; ++kk) {
    a0[kk] = cvt_row8(xp0 + kk * 32);
    a1[kk] = cvt_row8(xp1 + kk * 32);
  }

  const u16* wp = Wt + (size_t)l15 * DD + l4 * 8;
  const bool ok0 = (rbase + l15 < n), ok1 = (rbase + 16 + l15 < n);
  float* yp0 = agg + (size_t)(rbase + l15) * DD + l4 * 4;
  float* yp1 = agg + (size_t)(rbase + 16 + l15) * DD + l4 * 4;

  #pragma unroll
  for (int nn = 0; nn < 8; ++nn) {
    f4v acc0 = {}, acc1 = {};
    const u16* wpn = wp + (size_t)nn * 16 * DD;
    #pragma unroll
    for (int kk = 0; kk < 4; ++kk) {
      s8v b = *(const s8v*)(wpn + kk * 32);
      acc0 = __builtin_amdgcn_mfma_f32_16x16x32_bf16(b, a0[kk], acc0, 0, 0, 0);
      acc1 = __builtin_amdgcn_mfma_f32_16x16x32_bf16(b, a1[kk], acc1, 0, 0, 0);
    }
    const float4 bb = *(const float4*)(bias + nn * 16 + l4 * 4);
    if (ok0) {
      float4 old = *(float4*)(yp0 + nn * 16);
      old.x += acc0[0] + bb.x; old.y += acc0[1] + bb.y;
      old.z += acc0[2] + bb.z; old.w += acc0[3] + bb.w;
      *(float4*)(yp0 + nn * 16) = old;
    }
    if (ok1) {
      float4 old = *(float4*)(yp1 + nn * 16);
      old.x += acc1[0] + bb.x; old.y += acc1[1] + bb.y;
      old.z += acc1[2] + bb.z; old.w += acc1[3] + bb.w;
      *(float4*)(yp1 + nn * 16) = old;
    }
  }
}

// ---------- fused edge kernel: one wave per dst node ----------
template<int HB>
__global__ __launch_bounds__(256) void edge_fused(const u16* __restrict__ q,
                                                  const u16* __restrict__ k,
                                                  const u16* __restrict__ v,
                                                  const int* __restrict__ rptr,
                                                  const int* __restrict__ csrc,
                                                  float* __restrict__ agg,
                                                  int nd, int qs32, int ks32) {
  constexpr int LPH = 64 / HB;          // lanes per head
  int node = (int)(((size_t)blockIdx.x * 256 + threadIdx.x) >> 6);
  int lane = threadIdx.x & 63;
  if (node >= nd) return;
  int e0 = rptr[node], e1 = rptr[node + 1];
  if (e0 == e1) return;

  const u32* qp = (const u32*)q + (size_t)node * qs32 + lane * HB;
  u32 qv[HB];
  #pragma unroll
  for (int j = 0; j < HB; ++j) qv[j] = qp[j];

  float m = -1e30f, z = 0.f;
  float acc[2 * HB] = {};
  for (int e = e0; e < e1; ++e) {
    int s = csrc[e];
    const u32* kp = (const u32*)k + (size_t)s * ks32 + lane * HB;
    float dot = 0.f;
    #pragma unroll
    for (int j = 0; j < HB; ++j) {
      u32 ku = kp[j];
      dot += bflo(qv[j]) * bflo(ku) + bfhi(qv[j]) * bfhi(ku);
    }
    #pragma unroll
    for (int o = 1; o < LPH; o <<= 1) dot += __shfl_xor(dot, o);
    dot *= 0.08838834764831845f;   // 1/sqrt(128)
    float w;
    if (dot > m) {
      float sc = __expf(m - dot);
      z *= sc;
      #pragma unroll
      for (int j = 0; j < 2 * HB; ++j) acc[j] *= sc;
      m = dot; w = 1.f;
    } else {
      w = __expf(dot - m);
    }
    z += w;
    const u32* vp = (const u32*)v + (size_t)s * ks32 + lane * HB;
    #pragma unroll
    for (int j = 0; j < HB; ++j) {
      u32 vu = vp[j];
      acc[2 * j]     += w * bflo(vu);
      acc[2 * j + 1] += w * bfhi(vu);
    }
  }
  float inv = 0.25f / z;   // 1/H head-mean factor (H=4 overall)
  #pragma unroll
  for (int j = 0; j < 2 * HB; ++j) acc[j] *= inv;
  #pragma unroll
  for (int o = LPH; o < 64; o <<= 1) {
    #pragma unroll
    for (int j = 0; j < 2 * HB; ++j) acc[j] += __shfl_xor(acc[j], o);
  }
  if (lane < LPH) {
    float* op = agg + (size_t)node * DD + lane * 2 * HB;
    #pragma unroll
    for (int j = 0; j < 2 * HB; ++j) op[j] += acc[j];
  }
}

// ---------- LayerNorm + residual, one wave per node ----------
__global__ __launch_bounds__(256) void ln_kernel(const float* __restrict__ agg,
                                                 const float* __restrict__ g,
                                                 const float* __restrict__ b,
                                                 float* __restrict__ x,
                                                 int n) {
  int wid = (int)(((size_t)blockIdx.x * 256 + threadIdx.x) >> 6);
  int lane = threadIdx.x & 63;
  if (wid >= n) return;
  const float* ap = agg + (size_t)wid * DD;
  float v0 = ap[lane], v1 = ap[lane + 64];
  float s = v0 + v1;
  #pragma unroll
  for (int o = 1; o < 64; o <<= 1) s += __shfl_xor(s, o);
  float mean = s * (1.0f / DD);
  float d0 = v0 - mean, d1 = v1 - mean;
  float sq = d0 * d0 + d1 * d1;
  #pragma unroll
  for (int o = 1; o < 64; o <<= 1) sq += __shfl_xor(sq, o);
  float rstd = rsqrtf(sq * (1.0f / DD) + 1e-5f);
  float* xp = x + (size_t)wid * DD;
  xp[lane]      = g[lane]      * d0 * rstd + b[lane]      + xp[lane];
  xp[lane + 64] = g[lane + 64] * d1 * rstd + b[lane + 64] + xp[lane + 64];
}

extern "C" void kernel_launch(void* const* d_in, const int* in_sizes, int n_in,
                              void* d_out, int out_size, void* d_ws, size_t ws_size,
                              hipStream_t stream) {
  const float* emb_user = (const float*)d_in[0];
  const float* tv_tweet = (const float*)d_in[1];
  const float* W_qkv  = (const float*)d_in[2];
  const float* b_qkv  = (const float*)d_in[3];
  const float* W_skip = (const float*)d_in[4];
  const float* b_skip = (const float*)d_in[5];
  const float* ln_g   = (const float*)d_in[6];
  const float* ln_b   = (const float*)d_in[7];
  const int* edges[3] = { (const int*)d_in[8], (const int*)d_in[9], (const int*)d_in[10] };

  float* x_user  = (float*)d_out;
  float* x_tweet = x_user + (size_t)NUU * DD;

  // ---- workspace layout ----
  const size_t wtqB = (size_t)18 * 512 * 128 * 2;
  const size_t wtsB = (size_t)6 * 128 * 128 * 2;
  const size_t csrB = (size_t)3 * 100008 * 4 + (size_t)3 * 100000 * 4
                    + (size_t)2 * 100000 * 4 + 1600;
  auto need = [&](int hb) -> size_t {
    return wtqB + wtsB + (size_t)3 * 25600000 * hb + 76800000 + csrB + 4096;
  };
  int HB = (ws_size >= need(4)) ? 4 : (ws_size >= need(2)) ? 2 : 1;

  char* w = (char*)d_ws;
  u16* Wtq = (u16*)w;       w += wtqB;
  u16* Wts = (u16*)w;       w += wtsB;
  size_t qkvBytes = (size_t)100000 * HB * DD * 2;
  u16* qb = (u16*)w;        w += qkvBytes;
  u16* kb = (u16*)w;        w += qkvBytes;
  u16* vb = (u16*)w;        w += qkvBytes;
  float* agg_u = (float*)w; w += (size_t)NUU * DD * 4;
  float* agg_t = (float*)w; w += (size_t)NTT * DD * 4;
  int* rptrA[3]; int* csrcA[3];
  for (int r = 0; r < 3; ++r) { rptrA[r] = (int*)w; w += 100008 * 4; }
  for (int r = 0; r < 3; ++r) { csrcA[r] = (int*)w; w += 100000 * 4; }
  int* cnt = (int*)w;       w += 100000 * 4;
  int* cursor = (int*)w;    w += 100000 * 4;
  int* bsum = (int*)w;      /* 400 ints */

  init_x<<<(19200000 + 255) / 256, 256, 0, stream>>>(emb_user, tv_tweet, x_user, x_tweet);
  conv_w<<<(18 * 512 * 128 + 255) / 256, 256, 0, stream>>>(W_qkv, W_skip, Wtq, Wts);

  const int stt[3] = {0, 0, 1}, dtt[3] = {0, 1, 0};
  const int cnt2[2] = {NUU, NTT};
  float* xs[2]   = {x_user, x_tweet};
  float* aggs[2] = {agg_u, agg_t};

  // ---- build CSR per relation ----
  for (int r = 0; r < 3; ++r) {
    const int nd = cnt2[dtt[r]];
    const int* edst = edges[r] + EE;
    const int nb = (nd + 255) / 256;
    hipMemsetAsync(cnt, 0, (size_t)nd * 4, stream);
    hist_kernel<<<(EE + 255) / 256, 256, 0, stream>>>(edst, cnt);
    bsum_kernel<<<nb, 256, 0, stream>>>(cnt, nd, bsum);
    bscan_kernel<<<1, 256, 0, stream>>>(bsum, nb);
    rptr_kernel<<<nb, 256, 0, stream>>>(cnt, bsum, rptrA[r], cursor, nd);
    fill_kernel<<<(EE + 255) / 256, 256, 0, stream>>>(edges[r], edst, cursor, csrcA[r]);
  }

  for (int l = 0; l < 2; ++l) {
    hipMemsetAsync(agg_u, 0, (size_t)NUU * DD * 4, stream);
    hipMemsetAsync(agg_t, 0, (size_t)NTT * DD * 4, stream);
    for (int r = 0; r < 3; ++r) {
      const int st = stt[r], dt = dtt[r];
      const int ns = cnt2[st], nd = cnt2[dt];
      const int mat = l * 3 + r;
      const u16* Wfam = Wtq + (size_t)mat * 3 * 512 * 128;
      const float* bfam = b_qkv + (size_t)mat * 3 * HCC;
      const u16* WtS = Wts + (size_t)mat * 128 * 128;
      const float* bsk = b_skip + (size_t)mat * DD;

      const bool qDeg = (l == 0 && dt == 1);   // q over broadcast tweets
      const bool kDeg = (l == 0 && st == 1);   // k,v over broadcast tweets
      for (int h0 = 0; h0 < HH; h0 += HB) {
        const int ldy = HB * DD, col0 = h0 * DD;
        if (st == dt) {
          gemm_qkv3<<<dim3((nd + 127) / 128, 3), 256, 0, stream>>>(
              xs[dt], Wfam, bfam, qb, kb, vb, nd, ldy, col0, 0);
        } else {
          const int nq = qDeg ? 1 : nd;
          const int nk = kDeg ? 1 : ns;
          gemm_qkv3<<<dim3((nq + 127) / 128, 1), 256, 0, stream>>>(
              xs[dt], Wfam, bfam, qb, kb, vb, nq, ldy, col0, 0);
          gemm_qkv3<<<dim3((nk + 127) / 128, 2), 256, 0, stream>>>(
              xs[st], Wfam, bfam, qb, kb, vb, nk, ldy, col0, 1);
        }

        const int qs32 = qDeg ? 0 : HB * DD / 2;
        const int ks32 = kDeg ? 0 : HB * DD / 2;
        const int eblk = (nd + 3) / 4;
        if (HB == 4)
          edge_fused<4><<<eblk, 256, 0, stream>>>(qb, kb, vb, rptrA[r], csrcA[r], aggs[dt], nd, qs32, ks32);
        else if (HB == 2)
          edge_fused<2><<<eblk, 256, 0, stream>>>(qb, kb, vb, rptrA[r], csrcA[r], aggs[dt], nd, qs32, ks32);
        else
          edge_fused<1><<<eblk, 256, 0, stream>>>(qb, kb, vb, rptrA[r], csrcA[r], aggs[dt], nd, qs32, ks32);
      }

      gemm_skip2<<<(nd + 127) / 128, 256, 0, stream>>>(xs[dt], WtS, bsk, aggs[dt], nd);
    }
    ln_kernel<<<(NUU + 3) / 4, 256, 0, stream>>>(agg_u, ln_g + (size_t)(l * 2 + 0) * DD,
                                                 ln_b + (size_t)(l * 2 + 0) * DD, x_user, NUU);
    ln_kernel<<<(NTT + 3) / 4, 256, 0, stream>>>(agg_t, ln_g + (size_t)(l * 2 + 1) * DD,
                                                 ln_b + (size_t)(l * 2 + 1) * DD, x_tweet, NTT);
  }
}

// Round 6
// 1566.596 us; speedup vs baseline: 2.6449x; 1.1218x over previous
//
#include <hip/hip_runtime.h>
#include <hip/hip_bf16.h>
#include <math.h>

typedef unsigned short u16;
typedef unsigned int   u32;
typedef __attribute__((ext_vector_type(8))) short s8v;    // 8 x bf16 (4 VGPR)
typedef __attribute__((ext_vector_type(8))) unsigned short u16x8;
typedef __attribute__((ext_vector_type(4))) float f4v;    // MFMA accumulator

#define NUU 50000
#define NTT 100000
#define EE  100000
#define DD  128
#define HH  4
#define HCC 512

// ---------- helpers ----------
__device__ __forceinline__ float bflo(u32 u) { return __uint_as_float(u << 16); }
__device__ __forceinline__ float bfhi(u32 u) { return __uint_as_float(u & 0xFFFF0000u); }
__device__ __forceinline__ u16 f2bf(float f) {
  u32 u = __float_as_uint(f);
  u32 r = (u + 0x7FFFu + ((u >> 16) & 1u)) >> 16;
  return (u16)r;
}
__device__ __forceinline__ s8v cvt_row8(const float* __restrict__ p) {
  s8v r;
  #pragma unroll
  for (int i = 0; i < 8; ++i) r[i] = (short)f2bf(p[i]);
  return r;
}

// ---------- init: x_user = emb_user ; x_tweet[i,:] = tv_tweet ----------
__global__ __launch_bounds__(256) void init_x(const float* __restrict__ emb,
                                              const float* __restrict__ tv,
                                              float* __restrict__ xu,
                                              float* __restrict__ xt) {
  size_t idx = (size_t)blockIdx.x * 256 + threadIdx.x;
  size_t nu = (size_t)NUU * DD;
  size_t nt = (size_t)NTT * DD;
  if (idx < nu) {
    xu[idx] = emb[idx];
  } else {
    size_t j = idx - nu;
    if (j < nt) xt[j] = tv[j & (DD - 1)];
  }
}

// ---------- convert weights to bf16, transposed + column-permuted ----------
// Wt slot c' holds actual W column A(c') so that paired 16-col MFMA tiles give
// each lane 8 consecutive output columns (ushort8 stores in the GEMM).
__device__ __forceinline__ int colperm(int c) {
  return (c & ~31) | (((c >> 2) & 3) << 3) | (((c >> 4) & 1) << 2) | (c & 3);
}
__global__ __launch_bounds__(256) void conv_w(const float* __restrict__ Wq,
                                              const float* __restrict__ Wsk,
                                              u16* __restrict__ Wtq,
                                              u16* __restrict__ Wts) {
  int idx = blockIdx.x * 256 + threadIdx.x;
  if (idx < 18 * 512 * 128) {
    int k = idx & 127, cp = (idx >> 7) & 511, mat = idx >> 16;
    Wtq[idx] = f2bf(Wq[((size_t)mat * 128 + k) * 512 + colperm(cp)]);
  }
  if (idx < 6 * 128 * 128) {
    int k = idx & 127, col = (idx >> 7) & 127, mat = idx >> 14;
    Wts[idx] = f2bf(Wsk[((size_t)mat * 128 + k) * 128 + col]);
  }
}

// ---------- CSR build ----------
__global__ __launch_bounds__(256) void hist_kernel(const int* __restrict__ edst,
                                                   int* __restrict__ cnt) {
  int e = blockIdx.x * 256 + threadIdx.x;
  if (e < EE) atomicAdd(&cnt[edst[e]], 1);
}

__global__ __launch_bounds__(256) void bsum_kernel(const int* __restrict__ cnt, int n,
                                                   int* __restrict__ bsum) {
  int i = blockIdx.x * 256 + threadIdx.x;
  int v = (i < n) ? cnt[i] : 0;
  #pragma unroll
  for (int o = 1; o < 64; o <<= 1) v += __shfl_xor(v, o);
  __shared__ int ws4[4];
  if ((threadIdx.x & 63) == 0) ws4[threadIdx.x >> 6] = v;
  __syncthreads();
  if (threadIdx.x == 0) bsum[blockIdx.x] = ws4[0] + ws4[1] + ws4[2] + ws4[3];
}

__global__ __launch_bounds__(256) void bscan_kernel(int* __restrict__ bsum, int nb) {
  __shared__ int sh[256];
  __shared__ int runs;
  if (threadIdx.x == 0) runs = 0;
  __syncthreads();
  for (int base = 0; base < nb; base += 256) {
    int i = base + threadIdx.x;
    int v = (i < nb) ? bsum[i] : 0;
    sh[threadIdx.x] = v;
    __syncthreads();
    for (int o = 1; o < 256; o <<= 1) {
      int t = (threadIdx.x >= o) ? sh[threadIdx.x - o] : 0;
      __syncthreads();
      sh[threadIdx.x] += t;
      __syncthreads();
    }
    int incl = sh[threadIdx.x];
    int r0 = runs;
    if (i < nb) bsum[i] = r0 + incl - v;
    __syncthreads();
    if (threadIdx.x == 0) runs = r0 + sh[255];
    __syncthreads();
  }
}

__global__ __launch_bounds__(256) void rptr_kernel(const int* __restrict__ cnt,
                                                   const int* __restrict__ bsum,
                                                   int* __restrict__ rptr,
                                                   int* __restrict__ cursor, int n) {
  __shared__ int sh[256];
  int i = blockIdx.x * 256 + threadIdx.x;
  int v = (i < n) ? cnt[i] : 0;
  sh[threadIdx.x] = v;
  __syncthreads();
  for (int o = 1; o < 256; o <<= 1) {
    int t = (threadIdx.x >= o) ? sh[threadIdx.x - o] : 0;
    __syncthreads();
    sh[threadIdx.x] += t;
    __syncthreads();
  }
  int excl = sh[threadIdx.x] - v + bsum[blockIdx.x];
  if (i < n) { rptr[i] = excl; cursor[i] = excl; }
  if (i == 0) rptr[n] = EE;
}

__global__ __launch_bounds__(256) void fill_kernel(const int* __restrict__ esrc,
                                                   const int* __restrict__ edst,
                                                   int* __restrict__ cursor,
                                                   int* __restrict__ csrc) {
  int e = blockIdx.x * 256 + threadIdx.x;
  if (e < EE) {
    int pos = atomicAdd(&cursor[edst[e]], 1);
    csrc[pos] = esrc[e];
  }
}

// ---------- fused QKV GEMM (swapped MFMA, permuted W, ushort8 stores) ----------
__global__ __launch_bounds__(256) void gemm_qkv3(const float* __restrict__ X,
                                                 const u16* __restrict__ Wfam,
                                                 const float* __restrict__ bfam,
                                                 u16* __restrict__ oq,
                                                 u16* __restrict__ ok,
                                                 u16* __restrict__ ov,
                                                 int n, int ldy, int col0, int mat0) {
  const int bm = blockIdx.x * 128;
  const int matA = mat0 + blockIdx.y;
  const u16* Wt = Wfam + (size_t)matA * 512 * 128;
  const float* bias = bfam + (size_t)matA * HCC + col0;
  u16* Y = (matA == 0) ? oq : (matA == 1) ? ok : ov;

  const int wid = threadIdx.x >> 6, lane = threadIdx.x & 63;
  const int l15 = lane & 15, l4 = lane >> 4;
  const int rbase = bm + wid * 32;
  int r0 = rbase + l15;      if (r0 >= n) r0 = n - 1;
  int r1 = rbase + 16 + l15; if (r1 >= n) r1 = n - 1;
  const float* xp0 = X + (size_t)r0 * DD + l4 * 8;
  const float* xp1 = X + (size_t)r1 * DD + l4 * 8;
  s8v a0[4], a1[4];
  #pragma unroll
  for (int kk = 0; kk < 4; ++kk) {
    a0[kk] = cvt_row8(xp0 + kk * 32);
    a1[kk] = cvt_row8(xp1 + kk * 32);
  }

  const u16* wp = Wt + (size_t)(col0 + l15) * DD + l4 * 8;
  const bool ok0 = (rbase + l15 < n), ok1 = (rbase + 16 + l15 < n);
  u16* yp0 = Y + (size_t)(rbase + l15) * ldy;
  u16* yp1 = Y + (size_t)(rbase + 16 + l15) * ldy;
  const int pN = ldy >> 5;   // 32-col pairs

  for (int p = 0; p < pN; ++p) {
    f4v aE0 = {}, aE1 = {}, aO0 = {}, aO1 = {};
    const u16* wpE = wp + (size_t)(2 * p) * 16 * DD;
    const u16* wpO = wpE + 16 * DD;
    #pragma unroll
    for (int kk = 0; kk < 4; ++kk) {
      s8v bE = *(const s8v*)(wpE + kk * 32);
      s8v bO = *(const s8v*)(wpO + kk * 32);
      aE0 = __builtin_amdgcn_mfma_f32_16x16x32_bf16(bE, a0[kk], aE0, 0, 0, 0);
      aE1 = __builtin_amdgcn_mfma_f32_16x16x32_bf16(bE, a1[kk], aE1, 0, 0, 0);
      aO0 = __builtin_amdgcn_mfma_f32_16x16x32_bf16(bO, a0[kk], aO0, 0, 0, 0);
      aO1 = __builtin_amdgcn_mfma_f32_16x16x32_bf16(bO, a1[kk], aO1, 0, 0, 0);
    }
    // lane (l4) owns actual cols p*32 + l4*8 + 0..7  (E tile -> +0..3, O tile -> +4..7)
    const float4 bbE = *(const float4*)(bias + p * 32 + l4 * 8);
    const float4 bbO = *(const float4*)(bias + p * 32 + l4 * 8 + 4);
    if (ok0) {
      u16x8 pk;
      pk[0] = f2bf(aE0[0] + bbE.x); pk[1] = f2bf(aE0[1] + bbE.y);
      pk[2] = f2bf(aE0[2] + bbE.z); pk[3] = f2bf(aE0[3] + bbE.w);
      pk[4] = f2bf(aO0[0] + bbO.x); pk[5] = f2bf(aO0[1] + bbO.y);
      pk[6] = f2bf(aO0[2] + bbO.z); pk[7] = f2bf(aO0[3] + bbO.w);
      *(u16x8*)(yp0 + p * 32 + l4 * 8) = pk;
    }
    if (ok1) {
      u16x8 pk;
      pk[0] = f2bf(aE1[0] + bbE.x); pk[1] = f2bf(aE1[1] + bbE.y);
      pk[2] = f2bf(aE1[2] + bbE.z); pk[3] = f2bf(aE1[3] + bbE.w);
      pk[4] = f2bf(aO1[0] + bbO.x); pk[5] = f2bf(aO1[1] + bbO.y);
      pk[6] = f2bf(aO1[2] + bbO.z); pk[7] = f2bf(aO1[3] + bbO.w);
      *(u16x8*)(yp1 + p * 32 + l4 * 8) = pk;
    }
  }
}

// ---------- skip GEMM (swapped-operand, float4 RMW): agg += bf16(X)@Wt^T + bias ----------
__global__ __launch_bounds__(256) void gemm_skip2(const float* __restrict__ X,
                                                  const u16* __restrict__ Wt,
                                                  const float* __restrict__ bias,
                                                  float* __restrict__ agg, int n) {
  const int bm = blockIdx.x * 128;
  const int wid = threadIdx.x >> 6, lane = threadIdx.x & 63;
  const int l15 = lane & 15, l4 = lane >> 4;
  const int rbase = bm + wid * 32;
  int r0 = rbase + l15;      if (r0 >= n) r0 = n - 1;
  int r1 = rbase + 16 + l15; if (r1 >= n) r1 = n - 1;
  const float* xp0 = X + (size_t)r0 * DD + l4 * 8;
  const float* xp1 = X + (size_t)r1 * DD + l4 * 8;
  s8v a0[4], a1[4];
  #pragma unroll
  for (int kk = 0; kk < 4; ++kk) {
    a0[kk] = cvt_row8(xp0 + kk * 32);
    a1[kk] = cvt_row8(xp1 + kk * 32);
  }

  const u16* wp = Wt + (size_t)l15 * DD + l4 * 8;
  const bool ok0 = (rbase + l15 < n), ok1 = (rbase + 16 + l15 < n);
  float* yp0 = agg + (size_t)(rbase + l15) * DD + l4 * 4;
  float* yp1 = agg + (size_t)(rbase + 16 + l15) * DD + l4 * 4;

  #pragma unroll
  for (int nn = 0; nn < 8; ++nn) {
    f4v acc0 = {}, acc1 = {};
    const u16* wpn = wp + (size_t)nn * 16 * DD;
    #pragma unroll
    for (int kk = 0; kk < 4; ++kk) {
      s8v b = *(const s8v*)(wpn + kk * 32);
      acc0 = __builtin_amdgcn_mfma_f32_16x16x32_bf16(b, a0[kk], acc0, 0, 0, 0);
      acc1 = __builtin_amdgcn_mfma_f32_16x16x32_bf16(b, a1[kk], acc1, 0, 0, 0);
    }
    const float4 bb = *(const float4*)(bias + nn * 16 + l4 * 4);
    if (ok0) {
      float4 old = *(float4*)(yp0 + nn * 16);
      old.x += acc0[0] + bb.x; old.y += acc0[1] + bb.y;
      old.z += acc0[2] + bb.z; old.w += acc0[3] + bb.w;
      *(float4*)(yp0 + nn * 16) = old;
    }
    if (ok1) {
      float4 old = *(float4*)(yp1 + nn * 16);
      old.x += acc1[0] + bb.x; old.y += acc1[1] + bb.y;
      old.z += acc1[2] + bb.z; old.w += acc1[3] + bb.w;
      *(float4*)(yp1 + nn * 16) = old;
    }
  }
}

// ---------- fused edge kernel: one wave per dst node, K-prefetch + V-early-issue ----------
template<int HB>
__global__ __launch_bounds__(256) void edge_fused(const u16* __restrict__ q,
                                                  const u16* __restrict__ k,
                                                  const u16* __restrict__ v,
                                                  const int* __restrict__ rptr,
                                                  const int* __restrict__ csrc,
                                                  float* __restrict__ agg,
                                                  int nd, int qs32, int ks32) {
  constexpr int LPH = 64 / HB;          // lanes per head
  int node = (int)(((size_t)blockIdx.x * 256 + threadIdx.x) >> 6);
  int lane = threadIdx.x & 63;
  if (node >= nd) return;
  int e0 = rptr[node], e1 = rptr[node + 1];
  if (e0 == e1) return;

  const u32* qp = (const u32*)q + (size_t)node * qs32 + lane * HB;
  u32 qv[HB];
  #pragma unroll
  for (int j = 0; j < HB; ++j) qv[j] = qp[j];

  float m = -1e30f, z = 0.f;
  float acc[2 * HB] = {};

  int s_cur = csrc[e0];
  u32 kcur[HB];
  {
    const u32* kp = (const u32*)k + (size_t)s_cur * ks32 + lane * HB;
    #pragma unroll
    for (int j = 0; j < HB; ++j) kcur[j] = kp[j];
  }

  for (int e = e0; e < e1; ++e) {
    // issue V(current) and K(next) before the reduce/exp chain
    u32 vcur[HB];
    {
      const u32* vp = (const u32*)v + (size_t)s_cur * ks32 + lane * HB;
      #pragma unroll
      for (int j = 0; j < HB; ++j) vcur[j] = vp[j];
    }
    const bool has = (e + 1 < e1);
    int s_nxt = csrc[has ? e + 1 : e0];
    u32 knxt[HB];
    {
      const u32* kp = (const u32*)k + (size_t)s_nxt * ks32 + lane * HB;
      #pragma unroll
      for (int j = 0; j < HB; ++j) knxt[j] = kp[j];
    }

    float dot = 0.f;
    #pragma unroll
    for (int j = 0; j < HB; ++j)
      dot += bflo(qv[j]) * bflo(kcur[j]) + bfhi(qv[j]) * bfhi(kcur[j]);
    #pragma unroll
    for (int o = 1; o < LPH; o <<= 1) dot += __shfl_xor(dot, o);
    dot *= 0.08838834764831845f;   // 1/sqrt(128)
    float w;
    if (dot > m) {
      float sc = __expf(m - dot);
      z *= sc;
      #pragma unroll
      for (int j = 0; j < 2 * HB; ++j) acc[j] *= sc;
      m = dot; w = 1.f;
    } else {
      w = __expf(dot - m);
    }
    z += w;
    #pragma unroll
    for (int j = 0; j < HB; ++j) {
      acc[2 * j]     += w * bflo(vcur[j]);
      acc[2 * j + 1] += w * bfhi(vcur[j]);
    }
    if (has) {
      s_cur = s_nxt;
      #pragma unroll
      for (int j = 0; j < HB; ++j) kcur[j] = knxt[j];
    }
  }
  float inv = 0.25f / z;   // 1/H head-mean factor (H=4 overall)
  #pragma unroll
  for (int j = 0; j < 2 * HB; ++j) acc[j] *= inv;
  #pragma unroll
  for (int o = LPH; o < 64; o <<= 1) {
    #pragma unroll
    for (int j = 0; j < 2 * HB; ++j) acc[j] += __shfl_xor(acc[j], o);
  }
  if (lane < LPH) {
    float* op = agg + (size_t)node * DD + lane * 2 * HB;
    #pragma unroll
    for (int j = 0; j < 2 * HB; ++j) op[j] += acc[j];
  }
}

// ---------- LayerNorm + residual, one wave per node ----------
__global__ __launch_bounds__(256) void ln_kernel(const float* __restrict__ agg,
                                                 const float* __restrict__ g,
                                                 const float* __restrict__ b,
                                                 float* __restrict__ x,
                                                 int n) {
  int wid = (int)(((size_t)blockIdx.x * 256 + threadIdx.x) >> 6);
  int lane = threadIdx.x & 63;
  if (wid >= n) return;
  const float* ap = agg + (size_t)wid * DD;
  float v0 = ap[lane], v1 = ap[lane + 64];
  float s = v0 + v1;
  #pragma unroll
  for (int o = 1; o < 64; o <<= 1) s += __shfl_xor(s, o);
  float mean = s * (1.0f / DD);
  float d0 = v0 - mean, d1 = v1 - mean;
  float sq = d0 * d0 + d1 * d1;
  #pragma unroll
  for (int o = 1; o < 64; o <<= 1) sq += __shfl_xor(sq, o);
  float rstd = rsqrtf(sq * (1.0f / DD) + 1e-5f);
  float* xp = x + (size_t)wid * DD;
  xp[lane]      = g[lane]      * d0 * rstd + b[lane]      + xp[lane];
  xp[lane + 64] = g[lane + 64] * d1 * rstd + b[lane + 64] + xp[lane + 64];
}

extern "C" void kernel_launch(void* const* d_in, const int* in_sizes, int n_in,
                              void* d_out, int out_size, void* d_ws, size_t ws_size,
                              hipStream_t stream) {
  const float* emb_user = (const float*)d_in[0];
  const float* tv_tweet = (const float*)d_in[1];
  const float* W_qkv  = (const float*)d_in[2];
  const float* b_qkv  = (const float*)d_in[3];
  const float* W_skip = (const float*)d_in[4];
  const float* b_skip = (const float*)d_in[5];
  const float* ln_g   = (const float*)d_in[6];
  const float* ln_b   = (const float*)d_in[7];
  const int* edges[3] = { (const int*)d_in[8], (const int*)d_in[9], (const int*)d_in[10] };

  float* x_user  = (float*)d_out;
  float* x_tweet = x_user + (size_t)NUU * DD;

  // ---- workspace layout ----
  const size_t wtqB = (size_t)18 * 512 * 128 * 2;
  const size_t wtsB = (size_t)6 * 128 * 128 * 2;
  const size_t csrB = (size_t)3 * 100008 * 4 + (size_t)3 * 100000 * 4
                    + (size_t)2 * 100000 * 4 + 1600;
  auto need = [&](int hb) -> size_t {
    return wtqB + wtsB + (size_t)3 * 25600000 * hb + 76800000 + csrB + 4096;
  };
  int HB = (ws_size >= need(4)) ? 4 : (ws_size >= need(2)) ? 2 : 1;

  char* w = (char*)d_ws;
  u16* Wtq = (u16*)w;       w += wtqB;
  u16* Wts = (u16*)w;       w += wtsB;
  size_t qkvBytes = (size_t)100000 * HB * DD * 2;
  u16* qb = (u16*)w;        w += qkvBytes;
  u16* kb = (u16*)w;        w += qkvBytes;
  u16* vb = (u16*)w;        w += qkvBytes;
  float* agg_u = (float*)w; w += (size_t)NUU * DD * 4;
  float* agg_t = (float*)w; w += (size_t)NTT * DD * 4;
  int* rptrA[3]; int* csrcA[3];
  for (int r = 0; r < 3; ++r) { rptrA[r] = (int*)w; w += 100008 * 4; }
  for (int r = 0; r < 3; ++r) { csrcA[r] = (int*)w; w += 100000 * 4; }
  int* cnt = (int*)w;       w += 100000 * 4;
  int* cursor = (int*)w;    w += 100000 * 4;
  int* bsum = (int*)w;      /* 400 ints */

  init_x<<<(19200000 + 255) / 256, 256, 0, stream>>>(emb_user, tv_tweet, x_user, x_tweet);
  conv_w<<<(18 * 512 * 128 + 255) / 256, 256, 0, stream>>>(W_qkv, W_skip, Wtq, Wts);

  const int stt[3] = {0, 0, 1}, dtt[3] = {0, 1, 0};
  const int cnt2[2] = {NUU, NTT};
  float* xs[2]   = {x_user, x_tweet};
  float* aggs[2] = {agg_u, agg_t};

  // ---- build CSR per relation ----
  for (int r = 0; r < 3; ++r) {
    const int nd = cnt2[dtt[r]];
    const int* edst = edges[r] + EE;
    const int nb = (nd + 255) / 256;
    hipMemsetAsync(cnt, 0, (size_t)nd * 4, stream);
    hist_kernel<<<(EE + 255) / 256, 256, 0, stream>>>(edst, cnt);
    bsum_kernel<<<nb, 256, 0, stream>>>(cnt, nd, bsum);
    bscan_kernel<<<1, 256, 0, stream>>>(bsum, nb);
    rptr_kernel<<<nb, 256, 0, stream>>>(cnt, bsum, rptrA[r], cursor, nd);
    fill_kernel<<<(EE + 255) / 256, 256, 0, stream>>>(edges[r], edst, cursor, csrcA[r]);
  }

  for (int l = 0; l < 2; ++l) {
    hipMemsetAsync(agg_u, 0, (size_t)NUU * DD * 4, stream);
    hipMemsetAsync(agg_t, 0, (size_t)NTT * DD * 4, stream);
    for (int r = 0; r < 3; ++r) {
      const int st = stt[r], dt = dtt[r];
      const int ns = cnt2[st], nd = cnt2[dt];
      const int mat = l * 3 + r;
      const u16* Wfam = Wtq + (size_t)mat * 3 * 512 * 128;
      const float* bfam = b_qkv + (size_t)mat * 3 * HCC;
      const u16* WtS = Wts + (size_t)mat * 128 * 128;
      const float* bsk = b_skip + (size_t)mat * DD;

      const bool qDeg = (l == 0 && dt == 1);   // q over broadcast tweets
      const bool kDeg = (l == 0 && st == 1);   // k,v over broadcast tweets
      for (int h0 = 0; h0 < HH; h0 += HB) {
        const int ldy = HB * DD, col0 = h0 * DD;
        if (st == dt) {
          gemm_qkv3<<<dim3((nd + 127) / 128, 3), 256, 0, stream>>>(
              xs[dt], Wfam, bfam, qb, kb, vb, nd, ldy, col0, 0);
        } else {
          const int nq = qDeg ? 1 : nd;
          const int nk = kDeg ? 1 : ns;
          gemm_qkv3<<<dim3((nq + 127) / 128, 1), 256, 0, stream>>>(
              xs[dt], Wfam, bfam, qb, kb, vb, nq, ldy, col0, 0);
          gemm_qkv3<<<dim3((nk + 127) / 128, 2), 256, 0, stream>>>(
              xs[st], Wfam, bfam, qb, kb, vb, nk, ldy, col0, 1);
        }

        const int qs32 = qDeg ? 0 : HB * DD / 2;
        const int ks32 = kDeg ? 0 : HB * DD / 2;
        const int eblk = (nd + 3) / 4;
        if (HB == 4)
          edge_fused<4><<<eblk, 256, 0, stream>>>(qb, kb, vb, rptrA[r], csrcA[r], aggs[dt], nd, qs32, ks32);
        else if (HB == 2)
          edge_fused<2><<<eblk, 256, 0, stream>>>(qb, kb, vb, rptrA[r], csrcA[r], aggs[dt], nd, qs32, ks32);
        else
          edge_fused<1><<<eblk, 256, 0, stream>>>(qb, kb, vb, rptrA[r], csrcA[r], aggs[dt], nd, qs32, ks32);
      }

      gemm_skip2<<<(nd + 127) / 128, 256, 0, stream>>>(xs[dt], WtS, bsk, aggs[dt], nd);
    }
    ln_kernel<<<(NUU + 3) / 4, 256, 0, stream>>>(agg_u, ln_g + (size_t)(l * 2 + 0) * DD,
                                                 ln_b + (size_t)(l * 2 + 0) * DD, x_user, NUU);
    ln_kernel<<<(NTT + 3) / 4, 256, 0, stream>>>(agg_t, ln_g + (size_t)(l * 2 + 1) * DD,
                                                 ln_b + (size_t)(l * 2 + 1) * DD, x_tweet, NTT);
  }
}

// Round 7
// 1295.888 us; speedup vs baseline: 3.1974x; 1.2089x over previous
//
#include <hip/hip_runtime.h>
#include <hip/hip_bf16.h>
#include <math.h>

typedef unsigned short u16;
typedef unsigned int   u32;
typedef __attribute__((ext_vector_type(8))) short s8v;    // 8 x bf16
typedef __attribute__((ext_vector_type(8))) unsigned short u16x8;
typedef __attribute__((ext_vector_type(4))) float f4v;    // MFMA accumulator

#define NUU 50000
#define NTT 100000
#define EE  100000
#define DD  128
#define HH  4
#define HCC 512

// ---------- helpers ----------
__device__ __forceinline__ float bflo(u32 u) { return __uint_as_float(u << 16); }
__device__ __forceinline__ float bfhi(u32 u) { return __uint_as_float(u & 0xFFFF0000u); }
__device__ __forceinline__ u16 f2bf(float f) {
  u32 u = __float_as_uint(f);
  u32 r = (u + 0x7FFFu + ((u >> 16) & 1u)) >> 16;
  return (u16)r;
}
__device__ __forceinline__ s8v cvt_row8(const float* __restrict__ p) {
  float4 u = *(const float4*)p;
  float4 v = *(const float4*)(p + 4);
  s8v r;
  r[0] = (short)f2bf(u.x); r[1] = (short)f2bf(u.y);
  r[2] = (short)f2bf(u.z); r[3] = (short)f2bf(u.w);
  r[4] = (short)f2bf(v.x); r[5] = (short)f2bf(v.y);
  r[6] = (short)f2bf(v.z); r[7] = (short)f2bf(v.w);
  return r;
}
// column permutation so paired 16-col MFMA tiles give each lane 8 consecutive cols
__device__ __forceinline__ int colperm(int c) {
  return (c & ~31) | (((c >> 2) & 3) << 3) | (((c >> 4) & 1) << 2) | (c & 3);
}

// ---------- init: x_user = emb ; x_tweet = broadcast tv ; zero cnt ----------
__global__ __launch_bounds__(256) void init_x2(const float* __restrict__ emb,
                                               const float* __restrict__ tv,
                                               float* __restrict__ xu,
                                               float* __restrict__ xt,
                                               int* __restrict__ cz) {
  size_t idx = (size_t)blockIdx.x * 256 + threadIdx.x;
  const size_t nu = (size_t)NUU * DD;          // 6.4e6
  const size_t nt = (size_t)NTT * DD;          // 12.8e6
  if (idx < nu) {
    xu[idx] = emb[idx];
  } else if (idx < nu + nt) {
    size_t j = idx - nu;
    xt[j] = tv[j & (DD - 1)];
  } else {
    size_t j = idx - (nu + nt);
    if (j < 300000) cz[j] = 0;
  }
}

// ---------- weights: bf16, transposed, col-permuted; combined skip W ----------
__global__ __launch_bounds__(256) void conv_w(const float* __restrict__ Wq,
                                              const float* __restrict__ Wsk,
                                              const float* __restrict__ bsk,
                                              u16* __restrict__ Wtq,
                                              u16* __restrict__ WtsC,
                                              float* __restrict__ bskC) {
  int idx = blockIdx.x * 256 + threadIdx.x;
  if (idx < 18 * 512 * 128) {
    int k = idx & 127, cp = (idx >> 7) & 511, mat = idx >> 16;
    Wtq[idx] = f2bf(Wq[((size_t)mat * 128 + k) * 512 + colperm(cp)]);
  }
  if (idx < 4 * 128 * 128) {                        // mats: 2l + isTweet
    int k = idx & 127, cp = (idx >> 7) & 127, m = idx >> 14;
    int l = m >> 1, isT = m & 1, col = colperm(cp);
    float v;
    if (isT) v = Wsk[((size_t)(l * 3 + 1) * 128 + k) * 128 + col];
    else     v = Wsk[((size_t)(l * 3 + 0) * 128 + k) * 128 + col]
               + Wsk[((size_t)(l * 3 + 2) * 128 + k) * 128 + col];
    WtsC[idx] = f2bf(v);
  }
  if (idx < 4 * 128) {
    int m = idx >> 7, c = idx & 127;
    int l = m >> 1, isT = m & 1;
    bskC[idx] = isT ? bsk[(size_t)(l * 3 + 1) * 128 + c]
                    : bsk[(size_t)(l * 3 + 0) * 128 + c] + bsk[(size_t)(l * 3 + 2) * 128 + c];
  }
}

// ---------- CSR build (3 relations merged) ----------
__global__ __launch_bounds__(256) void hist3(const int* e0, const int* e1, const int* e2,
                                             int* c0, int* c1, int* c2) {
  int idx = blockIdx.x * 256 + threadIdx.x;
  if (idx >= 3 * EE) return;
  int r = idx / EE, e = idx - r * EE;
  const int* edst = (r == 0 ? e0 : r == 1 ? e1 : e2) + EE;
  int* cnt = r == 0 ? c0 : r == 1 ? c1 : c2;
  atomicAdd(&cnt[edst[e]], 1);
}

__global__ __launch_bounds__(256) void bsum3(const int* c0, const int* c1, const int* c2,
                                             int* __restrict__ bsumA) {
  int b = blockIdx.x;
  int r, lb, n;
  if (b < 196)      { r = 0; lb = b;       n = NUU; }
  else if (b < 587) { r = 1; lb = b - 196; n = NTT; }
  else              { r = 2; lb = b - 587; n = NUU; }
  const int* cnt = r == 0 ? c0 : r == 1 ? c1 : c2;
  int i = lb * 256 + threadIdx.x;
  int v = (i < n) ? cnt[i] : 0;
  #pragma unroll
  for (int o = 1; o < 64; o <<= 1) v += __shfl_xor(v, o);
  __shared__ int ws4[4];
  if ((threadIdx.x & 63) == 0) ws4[threadIdx.x >> 6] = v;
  __syncthreads();
  if (threadIdx.x == 0) bsumA[r * 400 + lb] = ws4[0] + ws4[1] + ws4[2] + ws4[3];
}

__global__ __launch_bounds__(256) void bscan3(int* __restrict__ bsumA) {
  int r = blockIdx.x;
  int* bsum = bsumA + r * 400;
  const int nb = (r == 1) ? 391 : 196;
  __shared__ int sh[256];
  __shared__ int runs;
  if (threadIdx.x == 0) runs = 0;
  __syncthreads();
  for (int base = 0; base < nb; base += 256) {
    int i = base + threadIdx.x;
    int v = (i < nb) ? bsum[i] : 0;
    sh[threadIdx.x] = v;
    __syncthreads();
    for (int o = 1; o < 256; o <<= 1) {
      int t = (threadIdx.x >= o) ? sh[threadIdx.x - o] : 0;
      __syncthreads();
      sh[threadIdx.x] += t;
      __syncthreads();
    }
    int incl = sh[threadIdx.x];
    int r0 = runs;
    if (i < nb) bsum[i] = r0 + incl - v;
    __syncthreads();
    if (threadIdx.x == 0) runs = r0 + sh[255];
    __syncthreads();
  }
}

// scan cnt -> rptr; cnt becomes the fill cursor (aliased)
__global__ __launch_bounds__(256) void rptr3(int* c0, int* c1, int* c2,
                                             const int* __restrict__ bsumA,
                                             int* r0p, int* r1p, int* r2p) {
  int b = blockIdx.x;
  int r, lb, n;
  if (b < 196)      { r = 0; lb = b;       n = NUU; }
  else if (b < 587) { r = 1; lb = b - 196; n = NTT; }
  else              { r = 2; lb = b - 587; n = NUU; }
  int* cnt = r == 0 ? c0 : r == 1 ? c1 : c2;
  int* rptr = r == 0 ? r0p : r == 1 ? r1p : r2p;
  __shared__ int sh[256];
  int i = lb * 256 + threadIdx.x;
  int v = (i < n) ? cnt[i] : 0;
  sh[threadIdx.x] = v;
  __syncthreads();
  for (int o = 1; o < 256; o <<= 1) {
    int t = (threadIdx.x >= o) ? sh[threadIdx.x - o] : 0;
    __syncthreads();
    sh[threadIdx.x] += t;
    __syncthreads();
  }
  int excl = sh[threadIdx.x] - v + bsumA[r * 400 + lb];
  if (i < n) { rptr[i] = excl; cnt[i] = excl; }
  if (i == 0) rptr[n] = EE;
}

__global__ __launch_bounds__(256) void fill3(const int* e0, const int* e1, const int* e2,
                                             int* c0, int* c1, int* c2,
                                             int* s0, int* s1, int* s2) {
  int idx = blockIdx.x * 256 + threadIdx.x;
  if (idx >= 3 * EE) return;
  int r = idx / EE, e = idx - r * EE;
  const int* ebase = (r == 0 ? e0 : r == 1 ? e1 : e2);
  int* cursor = r == 0 ? c0 : r == 1 ? c1 : c2;
  int* csrc = r == 0 ? s0 : r == 1 ? s1 : s2;
  int pos = atomicAdd(&cursor[ebase[EE + e]], 1);
  csrc[pos] = ebase[e];
}

// ---------- per-relation fused QKV GEMM, ping-pong W prefetch ----------
struct GRel {
  const float* Xq; const float* Xkv;
  const u16* Wfam; const float* bfam;
  u16* oq; u16* ok; u16* ov;
  int nq, nkv, ldy, col0;
};

template<int PN>
__global__ __launch_bounds__(256) void gemm_rel(GRel a) {
  const int mat = blockIdx.y;
  const int n = (mat == 0) ? a.nq : a.nkv;
  const int bm = blockIdx.x * 128;
  if (bm >= n) return;
  const float* X = (mat == 0) ? a.Xq : a.Xkv;
  const u16* Wt = a.Wfam + (size_t)mat * 512 * 128;
  const float* bias = a.bfam + (size_t)mat * HCC + a.col0;
  u16* Y = (mat == 0) ? a.oq : (mat == 1) ? a.ok : a.ov;
  const int ldy = a.ldy;

  const int wid = threadIdx.x >> 6, lane = threadIdx.x & 63;
  const int l15 = lane & 15, l4 = lane >> 4;
  const int rbase = bm + wid * 32;
  int r0 = rbase + l15;      if (r0 >= n) r0 = n - 1;
  int r1 = rbase + 16 + l15; if (r1 >= n) r1 = n - 1;
  const float* xp0 = X + (size_t)r0 * DD + l4 * 8;
  const float* xp1 = X + (size_t)r1 * DD + l4 * 8;
  s8v a0[4], a1[4];
  #pragma unroll
  for (int kk = 0; kk < 4; ++kk) {
    a0[kk] = cvt_row8(xp0 + kk * 32);
    a1[kk] = cvt_row8(xp1 + kk * 32);
  }

  const u16* wp = Wt + (size_t)(a.col0 + l15) * DD + l4 * 8;
  const bool ok0 = (rbase + l15 < n), ok1 = (rbase + 16 + l15 < n);
  u16* yp0 = Y + (size_t)(rbase + l15) * ldy + l4 * 8;
  u16* yp1 = Y + (size_t)(rbase + 16 + l15) * ldy + l4 * 8;

  s8v w0[8], w1[8];
  #pragma unroll
  for (int kk = 0; kk < 4; ++kk) {
    w0[kk]     = *(const s8v*)(wp + kk * 32);
    w0[4 + kk] = *(const s8v*)(wp + 16 * DD + kk * 32);
  }
  #pragma unroll
  for (int p = 0; p < PN; ++p) {
    const s8v* cw = (p & 1) ? w1 : w0;
    s8v* nw = (p & 1) ? w0 : w1;
    if (p + 1 < PN) {
      const u16* wq = wp + (size_t)(2 * (p + 1)) * 16 * DD;
      #pragma unroll
      for (int kk = 0; kk < 4; ++kk) {
        nw[kk]     = *(const s8v*)(wq + kk * 32);
        nw[4 + kk] = *(const s8v*)(wq + 16 * DD + kk * 32);
      }
    }
    f4v aE0 = {}, aE1 = {}, aO0 = {}, aO1 = {};
    #pragma unroll
    for (int kk = 0; kk < 4; ++kk) {
      aE0 = __builtin_amdgcn_mfma_f32_16x16x32_bf16(cw[kk], a0[kk], aE0, 0, 0, 0);
      aE1 = __builtin_amdgcn_mfma_f32_16x16x32_bf16(cw[kk], a1[kk], aE1, 0, 0, 0);
      aO0 = __builtin_amdgcn_mfma_f32_16x16x32_bf16(cw[4 + kk], a0[kk], aO0, 0, 0, 0);
      aO1 = __builtin_amdgcn_mfma_f32_16x16x32_bf16(cw[4 + kk], a1[kk], aO1, 0, 0, 0);
    }
    const float4 bbE = *(const float4*)(bias + p * 32 + l4 * 8);
    const float4 bbO = *(const float4*)(bias + p * 32 + l4 * 8 + 4);
    if (ok0) {
      u16x8 pk;
      pk[0] = f2bf(aE0[0] + bbE.x); pk[1] = f2bf(aE0[1] + bbE.y);
      pk[2] = f2bf(aE0[2] + bbE.z); pk[3] = f2bf(aE0[3] + bbE.w);
      pk[4] = f2bf(aO0[0] + bbO.x); pk[5] = f2bf(aO0[1] + bbO.y);
      pk[6] = f2bf(aO0[2] + bbO.z); pk[7] = f2bf(aO0[3] + bbO.w);
      *(u16x8*)(yp0 + p * 32) = pk;
    }
    if (ok1) {
      u16x8 pk;
      pk[0] = f2bf(aE1[0] + bbE.x); pk[1] = f2bf(aE1[1] + bbE.y);
      pk[2] = f2bf(aE1[2] + bbE.z); pk[3] = f2bf(aE1[3] + bbE.w);
      pk[4] = f2bf(aO1[0] + bbO.x); pk[5] = f2bf(aO1[1] + bbO.y);
      pk[6] = f2bf(aO1[2] + bbO.z); pk[7] = f2bf(aO1[3] + bbO.w);
      *(u16x8*)(yp1 + p * 32) = pk;
    }
  }
}

// ---------- skip GEMM (both node types, STORE): agg = bf16(X)@W^T + bias ----------
__global__ __launch_bounds__(256) void gemm_skip3(const float* Xu, const float* Xt,
                                                  const u16* Wu, const u16* Wtw,
                                                  const float* bu, const float* btw,
                                                  float* aggu, float* aggt) {
  const int job = blockIdx.y;
  const int n = job ? NTT : NUU;
  const int bm = blockIdx.x * 128;
  if (bm >= n) return;
  const float* X = job ? Xt : Xu;
  const u16* Wt = job ? Wtw : Wu;
  const float* bias = job ? btw : bu;
  float* out = job ? aggt : aggu;

  const int wid = threadIdx.x >> 6, lane = threadIdx.x & 63;
  const int l15 = lane & 15, l4 = lane >> 4;
  const int rbase = bm + wid * 32;
  int r0 = rbase + l15;      if (r0 >= n) r0 = n - 1;
  int r1 = rbase + 16 + l15; if (r1 >= n) r1 = n - 1;
  const float* xp0 = X + (size_t)r0 * DD + l4 * 8;
  const float* xp1 = X + (size_t)r1 * DD + l4 * 8;
  s8v a0[4], a1[4];
  #pragma unroll
  for (int kk = 0; kk < 4; ++kk) {
    a0[kk] = cvt_row8(xp0 + kk * 32);
    a1[kk] = cvt_row8(xp1 + kk * 32);
  }

  const u16* wp = Wt + (size_t)l15 * DD + l4 * 8;
  const bool ok0 = (rbase + l15 < n), ok1 = (rbase + 16 + l15 < n);
  float* yp0 = out + (size_t)(rbase + l15) * DD + l4 * 8;
  float* yp1 = out + (size_t)(rbase + 16 + l15) * DD + l4 * 8;

  s8v w0[8], w1[8];
  #pragma unroll
  for (int kk = 0; kk < 4; ++kk) {
    w0[kk]     = *(const s8v*)(wp + kk * 32);
    w0[4 + kk] = *(const s8v*)(wp + 16 * DD + kk * 32);
  }
  #pragma unroll
  for (int p = 0; p < 4; ++p) {
    const s8v* cw = (p & 1) ? w1 : w0;
    s8v* nw = (p & 1) ? w0 : w1;
    if (p + 1 < 4) {
      const u16* wq = wp + (size_t)(2 * (p + 1)) * 16 * DD;
      #pragma unroll
      for (int kk = 0; kk < 4; ++kk) {
        nw[kk]     = *(const s8v*)(wq + kk * 32);
        nw[4 + kk] = *(const s8v*)(wq + 16 * DD + kk * 32);
      }
    }
    f4v aE0 = {}, aE1 = {}, aO0 = {}, aO1 = {};
    #pragma unroll
    for (int kk = 0; kk < 4; ++kk) {
      aE0 = __builtin_amdgcn_mfma_f32_16x16x32_bf16(cw[kk], a0[kk], aE0, 0, 0, 0);
      aE1 = __builtin_amdgcn_mfma_f32_16x16x32_bf16(cw[kk], a1[kk], aE1, 0, 0, 0);
      aO0 = __builtin_amdgcn_mfma_f32_16x16x32_bf16(cw[4 + kk], a0[kk], aO0, 0, 0, 0);
      aO1 = __builtin_amdgcn_mfma_f32_16x16x32_bf16(cw[4 + kk], a1[kk], aO1, 0, 0, 0);
    }
    const float4 bbE = *(const float4*)(bias + p * 32 + l4 * 8);
    const float4 bbO = *(const float4*)(bias + p * 32 + l4 * 8 + 4);
    if (ok0) {
      float4 e = make_float4(aE0[0] + bbE.x, aE0[1] + bbE.y, aE0[2] + bbE.z, aE0[3] + bbE.w);
      float4 o = make_float4(aO0[0] + bbO.x, aO0[1] + bbO.y, aO0[2] + bbO.z, aO0[3] + bbO.w);
      *(float4*)(yp0 + p * 32) = e;
      *(float4*)(yp0 + p * 32 + 4) = o;
    }
    if (ok1) {
      float4 e = make_float4(aE1[0] + bbE.x, aE1[1] + bbE.y, aE1[2] + bbE.z, aE1[3] + bbE.w);
      float4 o = make_float4(aO1[0] + bbO.x, aO1[1] + bbO.y, aO1[2] + bbO.z, aO1[3] + bbO.w);
      *(float4*)(yp1 + p * 32) = e;
      *(float4*)(yp1 + p * 32 + 4) = o;
    }
  }
}

// ---------- fused edge kernel: one wave per dst node, K-prefetch ----------
template<int HB>
__global__ __launch_bounds__(256) void edge_fused(const u16* __restrict__ q,
                                                  const u16* __restrict__ k,
                                                  const u16* __restrict__ v,
                                                  const int* __restrict__ rptr,
                                                  const int* __restrict__ csrc,
                                                  float* __restrict__ agg,
                                                  int nd, int qs32, int ks32) {
  constexpr int LPH = 64 / HB;
  int node = (int)(((size_t)blockIdx.x * 256 + threadIdx.x) >> 6);
  int lane = threadIdx.x & 63;
  if (node >= nd) return;
  int e0 = rptr[node], e1 = rptr[node + 1];
  if (e0 == e1) return;

  const u32* qp = (const u32*)q + (size_t)node * qs32 + lane * HB;
  u32 qv[HB];
  #pragma unroll
  for (int j = 0; j < HB; ++j) qv[j] = qp[j];

  float m = -1e30f, z = 0.f;
  float acc[2 * HB] = {};

  int s_cur = csrc[e0];
  u32 kcur[HB];
  {
    const u32* kp = (const u32*)k + (size_t)s_cur * ks32 + lane * HB;
    #pragma unroll
    for (int j = 0; j < HB; ++j) kcur[j] = kp[j];
  }

  for (int e = e0; e < e1; ++e) {
    u32 vcur[HB];
    {
      const u32* vp = (const u32*)v + (size_t)s_cur * ks32 + lane * HB;
      #pragma unroll
      for (int j = 0; j < HB; ++j) vcur[j] = vp[j];
    }
    const bool has = (e + 1 < e1);
    int s_nxt = csrc[has ? e + 1 : e0];
    u32 knxt[HB];
    {
      const u32* kp = (const u32*)k + (size_t)s_nxt * ks32 + lane * HB;
      #pragma unroll
      for (int j = 0; j < HB; ++j) knxt[j] = kp[j];
    }

    float dot = 0.f;
    #pragma unroll
    for (int j = 0; j < HB; ++j)
      dot += bflo(qv[j]) * bflo(kcur[j]) + bfhi(qv[j]) * bfhi(kcur[j]);
    #pragma unroll
    for (int o = 1; o < LPH; o <<= 1) dot += __shfl_xor(dot, o);
    dot *= 0.08838834764831845f;   // 1/sqrt(128)
    float w;
    if (dot > m) {
      float sc = __expf(m - dot);
      z *= sc;
      #pragma unroll
      for (int j = 0; j < 2 * HB; ++j) acc[j] *= sc;
      m = dot; w = 1.f;
    } else {
      w = __expf(dot - m);
    }
    z += w;
    #pragma unroll
    for (int j = 0; j < HB; ++j) {
      acc[2 * j]     += w * bflo(vcur[j]);
      acc[2 * j + 1] += w * bfhi(vcur[j]);
    }
    if (has) {
      s_cur = s_nxt;
      #pragma unroll
      for (int j = 0; j < HB; ++j) kcur[j] = knxt[j];
    }
  }
  float inv = 0.25f / z;
  #pragma unroll
  for (int j = 0; j < 2 * HB; ++j) acc[j] *= inv;
  #pragma unroll
  for (int o = LPH; o < 64; o <<= 1) {
    #pragma unroll
    for (int j = 0; j < 2 * HB; ++j) acc[j] += __shfl_xor(acc[j], o);
  }
  if (lane < LPH) {
    float* op = agg + (size_t)node * DD + lane * 2 * HB;
    #pragma unroll
    for (int j = 0; j < 2 * HB; ++j) op[j] += acc[j];
  }
}

// ---------- LayerNorm + residual for BOTH node types ----------
__global__ __launch_bounds__(256) void ln2(const float* __restrict__ aggu,
                                           const float* __restrict__ aggt,
                                           const float* __restrict__ g2,
                                           const float* __restrict__ b2,
                                           float* __restrict__ xu,
                                           float* __restrict__ xt) {
  int wid = (int)(((size_t)blockIdx.x * 256 + threadIdx.x) >> 6);
  int lane = threadIdx.x & 63;
  if (wid >= NUU + NTT) return;
  const float* ap; float* xp; const float* g; const float* b;
  if (wid < NUU) { ap = aggu + (size_t)wid * DD; xp = xu + (size_t)wid * DD; g = g2; b = b2; }
  else { int t = wid - NUU; ap = aggt + (size_t)t * DD; xp = xt + (size_t)t * DD; g = g2 + DD; b = b2 + DD; }
  float v0 = ap[lane], v1 = ap[lane + 64];
  float s = v0 + v1;
  #pragma unroll
  for (int o = 1; o < 64; o <<= 1) s += __shfl_xor(s, o);
  float mean = s * (1.0f / DD);
  float d0 = v0 - mean, d1 = v1 - mean;
  float sq = d0 * d0 + d1 * d1;
  #pragma unroll
  for (int o = 1; o < 64; o <<= 1) sq += __shfl_xor(sq, o);
  float rstd = rsqrtf(sq * (1.0f / DD) + 1e-5f);
  xp[lane]      = g[lane]      * d0 * rstd + b[lane]      + xp[lane];
  xp[lane + 64] = g[lane + 64] * d1 * rstd + b[lane + 64] + xp[lane + 64];
}

extern "C" void kernel_launch(void* const* d_in, const int* in_sizes, int n_in,
                              void* d_out, int out_size, void* d_ws, size_t ws_size,
                              hipStream_t stream) {
  const float* emb_user = (const float*)d_in[0];
  const float* tv_tweet = (const float*)d_in[1];
  const float* W_qkv  = (const float*)d_in[2];
  const float* b_qkv  = (const float*)d_in[3];
  const float* W_skip = (const float*)d_in[4];
  const float* b_skip = (const float*)d_in[5];
  const float* ln_g   = (const float*)d_in[6];
  const float* ln_b   = (const float*)d_in[7];
  const int* edges[3] = { (const int*)d_in[8], (const int*)d_in[9], (const int*)d_in[10] };

  float* x_user  = (float*)d_out;
  float* x_tweet = x_user + (size_t)NUU * DD;

  // ---- workspace layout ----
  auto need = [](int hb) -> size_t {
    return 2359296 + 131072 + 2048
         + (size_t)3 * 100000 * hb * 128 * 2   // q,k,v
         + 76800000                            // agg
         + (size_t)3 * 400032                  // rptr
         + (size_t)3 * 400000                  // csrc
         + 1200000 + 4800 + 4096;              // cnt(=cursor), bsum, pad
  };
  const int HB = (ws_size >= need(4)) ? 4 : (ws_size >= need(2)) ? 2 : 1;

  char* w = (char*)d_ws;
  u16* Wtq = (u16*)w;        w += 2359296;
  u16* WtsC = (u16*)w;       w += 131072;
  float* bskC = (float*)w;   w += 2048;
  size_t qkvBytes = (size_t)100000 * HB * DD * 2;
  u16* qb = (u16*)w;         w += qkvBytes;
  u16* kb = (u16*)w;         w += qkvBytes;
  u16* vb = (u16*)w;         w += qkvBytes;
  float* agg_u = (float*)w;  w += (size_t)NUU * DD * 4;
  float* agg_t = (float*)w;  w += (size_t)NTT * DD * 4;
  int* rptrA[3]; int* csrcA[3]; int* cntA[3];
  for (int r = 0; r < 3; ++r) { rptrA[r] = (int*)w; w += 400032; }
  for (int r = 0; r < 3; ++r) { csrcA[r] = (int*)w; w += 400000; }
  cntA[0] = (int*)w; cntA[1] = cntA[0] + 100000; cntA[2] = cntA[0] + 200000; w += 1200000;
  int* bsumA = (int*)w;

  init_x2<<<(19500000 + 255) / 256, 256, 0, stream>>>(emb_user, tv_tweet, x_user, x_tweet, cntA[0]);
  conv_w<<<(18 * 512 * 128 + 255) / 256, 256, 0, stream>>>(W_qkv, W_skip, b_skip, Wtq, WtsC, bskC);

  hist3<<<(3 * EE + 255) / 256, 256, 0, stream>>>(edges[0], edges[1], edges[2],
                                                  cntA[0], cntA[1], cntA[2]);
  bsum3<<<783, 256, 0, stream>>>(cntA[0], cntA[1], cntA[2], bsumA);
  bscan3<<<3, 256, 0, stream>>>(bsumA);
  rptr3<<<783, 256, 0, stream>>>(cntA[0], cntA[1], cntA[2], bsumA, rptrA[0], rptrA[1], rptrA[2]);
  fill3<<<(3 * EE + 255) / 256, 256, 0, stream>>>(edges[0], edges[1], edges[2],
                                                  cntA[0], cntA[1], cntA[2],
                                                  csrcA[0], csrcA[1], csrcA[2]);

  const int stt[3] = {0, 0, 1}, dtt[3] = {0, 1, 0};
  const int cnt2[2] = {NUU, NTT};
  float* xs[2]   = {x_user, x_tweet};
  float* aggs[2] = {agg_u, agg_t};

  for (int l = 0; l < 2; ++l) {
    gemm_skip3<<<dim3((NTT + 127) / 128, 2), 256, 0, stream>>>(
        x_user, x_tweet,
        WtsC + (size_t)(2 * l) * 128 * 128, WtsC + (size_t)(2 * l + 1) * 128 * 128,
        bskC + (size_t)(2 * l) * 128, bskC + (size_t)(2 * l + 1) * 128,
        agg_u, agg_t);

    for (int r = 0; r < 3; ++r) {
      const int st = stt[r], dt = dtt[r];
      const int ns = cnt2[st], nd = cnt2[dt];
      const int mat = l * 3 + r;
      const bool qDeg = (l == 0 && dt == 1);
      const bool kDeg = (l == 0 && st == 1);

      for (int h0 = 0; h0 < HH; h0 += HB) {
        GRel ga;
        ga.Xq = xs[dt]; ga.Xkv = xs[st];
        ga.Wfam = Wtq + (size_t)mat * 3 * 512 * 128;
        ga.bfam = b_qkv + (size_t)mat * 3 * HCC;
        ga.oq = qb; ga.ok = kb; ga.ov = vb;
        ga.nq = qDeg ? 1 : nd;
        ga.nkv = kDeg ? 1 : ns;
        ga.ldy = HB * DD; ga.col0 = h0 * DD;
        const int gmax = (ga.nq > ga.nkv) ? ga.nq : ga.nkv;
        dim3 gg((gmax + 127) / 128, 3);
        if (HB == 4)      gemm_rel<16><<<gg, 256, 0, stream>>>(ga);
        else if (HB == 2) gemm_rel<8><<<gg, 256, 0, stream>>>(ga);
        else              gemm_rel<4><<<gg, 256, 0, stream>>>(ga);

        const int qs32 = qDeg ? 0 : HB * DD / 2;
        const int ks32 = kDeg ? 0 : HB * DD / 2;
        const int eblk = (nd + 3) / 4;
        if (HB == 4)
          edge_fused<4><<<eblk, 256, 0, stream>>>(qb, kb, vb, rptrA[r], csrcA[r], aggs[dt], nd, qs32, ks32);
        else if (HB == 2)
          edge_fused<2><<<eblk, 256, 0, stream>>>(qb, kb, vb, rptrA[r], csrcA[r], aggs[dt], nd, qs32, ks32);
        else
          edge_fused<1><<<eblk, 256, 0, stream>>>(qb, kb, vb, rptrA[r], csrcA[r], aggs[dt], nd, qs32, ks32);
      }
    }
    ln2<<<(NUU + NTT + 3) / 4, 256, 0, stream>>>(agg_u, agg_t,
                                                 ln_g + (size_t)l * 2 * DD,
                                                 ln_b + (size_t)l * 2 * DD,
                                                 x_user, x_tweet);
  }
}

// Round 8
// 1196.888 us; speedup vs baseline: 3.4619x; 1.0827x over previous
//
#include <hip/hip_runtime.h>
#include <hip/hip_bf16.h>
#include <math.h>

typedef unsigned short u16;
typedef unsigned int   u32;
typedef __attribute__((ext_vector_type(8))) short s8v;    // 8 x bf16
typedef __attribute__((ext_vector_type(8))) unsigned short u16x8;
typedef __attribute__((ext_vector_type(4))) float f4v;    // MFMA accumulator

#define NUU 50000
#define NTT 100000
#define EE  100000
#define DD  128
#define HH  4
#define HCC 512
#define BU  391                 // ceil(NUU/128)
#define BT  782                 // ceil(NTT/128)

// ---------- helpers ----------
__device__ __forceinline__ float bflo(u32 u) { return __uint_as_float(u << 16); }
__device__ __forceinline__ float bfhi(u32 u) { return __uint_as_float(u & 0xFFFF0000u); }
__device__ __forceinline__ u16 f2bf(float f) {
  u32 u = __float_as_uint(f);
  u32 r = (u + 0x7FFFu + ((u >> 16) & 1u)) >> 16;
  return (u16)r;
}
__device__ __forceinline__ s8v cvt_row8(const float* __restrict__ p) {
  float4 u = *(const float4*)p;
  float4 v = *(const float4*)(p + 4);
  s8v r;
  r[0] = (short)f2bf(u.x); r[1] = (short)f2bf(u.y);
  r[2] = (short)f2bf(u.z); r[3] = (short)f2bf(u.w);
  r[4] = (short)f2bf(v.x); r[5] = (short)f2bf(v.y);
  r[6] = (short)f2bf(v.z); r[7] = (short)f2bf(v.w);
  return r;
}
__device__ __forceinline__ int colperm(int c) {
  return (c & ~31) | (((c >> 2) & 3) << 3) | (((c >> 4) & 1) << 2) | (c & 3);
}

// ---------- init: x_user = emb ; x_tweet = broadcast tv ; zero cnt ; bf16 mirror ----------
__global__ __launch_bounds__(256) void init_x2(const float* __restrict__ emb,
                                               const float* __restrict__ tv,
                                               float* __restrict__ xu,
                                               float* __restrict__ xt,
                                               int* __restrict__ cz,
                                               u16* __restrict__ xbu,
                                               u16* __restrict__ xbt,
                                               int useb) {
  size_t idx = (size_t)blockIdx.x * 256 + threadIdx.x;
  const size_t nu = (size_t)NUU * DD;
  const size_t nt = (size_t)NTT * DD;
  if (idx < nu) {
    float v = emb[idx];
    xu[idx] = v;
    if (useb) xbu[idx] = f2bf(v);
  } else if (idx < nu + nt) {
    size_t j = idx - nu;
    float v = tv[j & (DD - 1)];
    xt[j] = v;
    if (useb) xbt[j] = f2bf(v);
  } else {
    size_t j = idx - (nu + nt);
    if (j < 300000) cz[j] = 0;
  }
}

// ---------- weights: bf16, transposed, col-permuted; combined skip W ----------
__global__ __launch_bounds__(256) void conv_w(const float* __restrict__ Wq,
                                              const float* __restrict__ Wsk,
                                              const float* __restrict__ bsk,
                                              u16* __restrict__ Wtq,
                                              u16* __restrict__ WtsC,
                                              float* __restrict__ bskC) {
  int idx = blockIdx.x * 256 + threadIdx.x;
  if (idx < 18 * 512 * 128) {
    int k = idx & 127, cp = (idx >> 7) & 511, mat = idx >> 16;
    Wtq[idx] = f2bf(Wq[((size_t)mat * 128 + k) * 512 + colperm(cp)]);
  }
  if (idx < 4 * 128 * 128) {
    int k = idx & 127, cp = (idx >> 7) & 127, m = idx >> 14;
    int l = m >> 1, isT = m & 1, col = colperm(cp);
    float v;
    if (isT) v = Wsk[((size_t)(l * 3 + 1) * 128 + k) * 128 + col];
    else     v = Wsk[((size_t)(l * 3 + 0) * 128 + k) * 128 + col]
               + Wsk[((size_t)(l * 3 + 2) * 128 + k) * 128 + col];
    WtsC[idx] = f2bf(v);
  }
  if (idx < 4 * 128) {
    int m = idx >> 7, c = idx & 127;
    int l = m >> 1, isT = m & 1;
    bskC[idx] = isT ? bsk[(size_t)(l * 3 + 1) * 128 + c]
                    : bsk[(size_t)(l * 3 + 0) * 128 + c] + bsk[(size_t)(l * 3 + 2) * 128 + c];
  }
}

// ---------- CSR build (3 relations merged) ----------
__global__ __launch_bounds__(256) void hist3(const int* e0, const int* e1, const int* e2,
                                             int* c0, int* c1, int* c2) {
  int idx = blockIdx.x * 256 + threadIdx.x;
  if (idx >= 3 * EE) return;
  int r = idx / EE, e = idx - r * EE;
  const int* edst = (r == 0 ? e0 : r == 1 ? e1 : e2) + EE;
  int* cnt = r == 0 ? c0 : r == 1 ? c1 : c2;
  atomicAdd(&cnt[edst[e]], 1);
}

__global__ __launch_bounds__(256) void bsum3(const int* c0, const int* c1, const int* c2,
                                             int* __restrict__ bsumA) {
  int b = blockIdx.x;
  int r, lb, n;
  if (b < 196)      { r = 0; lb = b;       n = NUU; }
  else if (b < 587) { r = 1; lb = b - 196; n = NTT; }
  else              { r = 2; lb = b - 587; n = NUU; }
  const int* cnt = r == 0 ? c0 : r == 1 ? c1 : c2;
  int i = lb * 256 + threadIdx.x;
  int v = (i < n) ? cnt[i] : 0;
  #pragma unroll
  for (int o = 1; o < 64; o <<= 1) v += __shfl_xor(v, o);
  __shared__ int ws4[4];
  if ((threadIdx.x & 63) == 0) ws4[threadIdx.x >> 6] = v;
  __syncthreads();
  if (threadIdx.x == 0) bsumA[r * 400 + lb] = ws4[0] + ws4[1] + ws4[2] + ws4[3];
}

__global__ __launch_bounds__(256) void bscan3(int* __restrict__ bsumA) {
  int r = blockIdx.x;
  int* bsum = bsumA + r * 400;
  const int nb = (r == 1) ? 391 : 196;
  __shared__ int sh[256];
  __shared__ int runs;
  if (threadIdx.x == 0) runs = 0;
  __syncthreads();
  for (int base = 0; base < nb; base += 256) {
    int i = base + threadIdx.x;
    int v = (i < nb) ? bsum[i] : 0;
    sh[threadIdx.x] = v;
    __syncthreads();
    for (int o = 1; o < 256; o <<= 1) {
      int t = (threadIdx.x >= o) ? sh[threadIdx.x - o] : 0;
      __syncthreads();
      sh[threadIdx.x] += t;
      __syncthreads();
    }
    int incl = sh[threadIdx.x];
    int r0 = runs;
    if (i < nb) bsum[i] = r0 + incl - v;
    __syncthreads();
    if (threadIdx.x == 0) runs = r0 + sh[255];
    __syncthreads();
  }
}

__global__ __launch_bounds__(256) void rptr3(int* c0, int* c1, int* c2,
                                             const int* __restrict__ bsumA,
                                             int* r0p, int* r1p, int* r2p) {
  int b = blockIdx.x;
  int r, lb, n;
  if (b < 196)      { r = 0; lb = b;       n = NUU; }
  else if (b < 587) { r = 1; lb = b - 196; n = NTT; }
  else              { r = 2; lb = b - 587; n = NUU; }
  int* cnt = r == 0 ? c0 : r == 1 ? c1 : c2;
  int* rptr = r == 0 ? r0p : r == 1 ? r1p : r2p;
  __shared__ int sh[256];
  int i = lb * 256 + threadIdx.x;
  int v = (i < n) ? cnt[i] : 0;
  sh[threadIdx.x] = v;
  __syncthreads();
  for (int o = 1; o < 256; o <<= 1) {
    int t = (threadIdx.x >= o) ? sh[threadIdx.x - o] : 0;
    __syncthreads();
    sh[threadIdx.x] += t;
    __syncthreads();
  }
  int excl = sh[threadIdx.x] - v + bsumA[r * 400 + lb];
  if (i < n) { rptr[i] = excl; cnt[i] = excl; }
  if (i == 0) rptr[n] = EE;
}

__global__ __launch_bounds__(256) void fill3(const int* e0, const int* e1, const int* e2,
                                             int* c0, int* c1, int* c2,
                                             int* s0, int* s1, int* s2) {
  int idx = blockIdx.x * 256 + threadIdx.x;
  if (idx >= 3 * EE) return;
  int r = idx / EE, e = idx - r * EE;
  const int* ebase = (r == 0 ? e0 : r == 1 ? e1 : e2);
  int* cursor = r == 0 ? c0 : r == 1 ? c1 : c2;
  int* csrc = r == 0 ? s0 : r == 1 ? s1 : s2;
  int pos = atomicAdd(&cursor[ebase[EE + e]], 1);
  csrc[pos] = ebase[e];
}

// ---------- per-relation fused QKV GEMM, flat grid, bf16-x fast path ----------
struct GRel {
  const u16* Xqb; const u16* Xkvb;
  const float* Xqf; const float* Xkvf;
  const u16* Wfam; const float* bfam;
  u16 *oq, *ok, *ov;
  int nq, nkv, bq, bkv, ldy, col0, usexb;
};

template<int PN>
__global__ __launch_bounds__(256) void gemm_rel(GRel a) {
  const int bx = blockIdx.x;
  int mat, lb, n; const u16* Xb; const float* Xf;
  if (bx < a.bq) { mat = 0; lb = bx; n = a.nq; Xb = a.Xqb; Xf = a.Xqf; }
  else {
    int t = bx - a.bq;
    if (t < a.bkv) { mat = 1; lb = t; } else { mat = 2; lb = t - a.bkv; }
    n = a.nkv; Xb = a.Xkvb; Xf = a.Xkvf;
  }
  const int bm = lb * 128;
  const u16* Wt = a.Wfam + (size_t)mat * 512 * 128;
  const float* bias = a.bfam + (size_t)mat * HCC + a.col0;
  u16* Y = (mat == 0) ? a.oq : (mat == 1) ? a.ok : a.ov;
  const int ldy = a.ldy;

  const int wid = threadIdx.x >> 6, lane = threadIdx.x & 63;
  const int l15 = lane & 15, l4 = lane >> 4;
  const int rbase = bm + wid * 32;
  int r0 = rbase + l15;      if (r0 >= n) r0 = n - 1;
  int r1 = rbase + 16 + l15; if (r1 >= n) r1 = n - 1;
  s8v a0[4], a1[4];
  if (a.usexb) {
    const u16* xb0 = Xb + (size_t)r0 * DD + l4 * 8;
    const u16* xb1 = Xb + (size_t)r1 * DD + l4 * 8;
    #pragma unroll
    for (int kk = 0; kk < 4; ++kk) {
      a0[kk] = *(const s8v*)(xb0 + kk * 32);
      a1[kk] = *(const s8v*)(xb1 + kk * 32);
    }
  } else {
    const float* xp0 = Xf + (size_t)r0 * DD + l4 * 8;
    const float* xp1 = Xf + (size_t)r1 * DD + l4 * 8;
    #pragma unroll
    for (int kk = 0; kk < 4; ++kk) {
      a0[kk] = cvt_row8(xp0 + kk * 32);
      a1[kk] = cvt_row8(xp1 + kk * 32);
    }
  }

  const u16* wp = Wt + (size_t)(a.col0 + l15) * DD + l4 * 8;
  const bool ok0 = (rbase + l15 < n), ok1 = (rbase + 16 + l15 < n);
  u16* yp0 = Y + (size_t)(rbase + l15) * ldy + l4 * 8;
  u16* yp1 = Y + (size_t)(rbase + 16 + l15) * ldy + l4 * 8;

  s8v w0[8], w1[8];
  #pragma unroll
  for (int kk = 0; kk < 4; ++kk) {
    w0[kk]     = *(const s8v*)(wp + kk * 32);
    w0[4 + kk] = *(const s8v*)(wp + 16 * DD + kk * 32);
  }
  #pragma unroll
  for (int p = 0; p < PN; ++p) {
    const s8v* cw = (p & 1) ? w1 : w0;
    s8v* nw = (p & 1) ? w0 : w1;
    if (p + 1 < PN) {
      const u16* wq = wp + (size_t)(2 * (p + 1)) * 16 * DD;
      #pragma unroll
      for (int kk = 0; kk < 4; ++kk) {
        nw[kk]     = *(const s8v*)(wq + kk * 32);
        nw[4 + kk] = *(const s8v*)(wq + 16 * DD + kk * 32);
      }
    }
    f4v aE0 = {}, aE1 = {}, aO0 = {}, aO1 = {};
    #pragma unroll
    for (int kk = 0; kk < 4; ++kk) {
      aE0 = __builtin_amdgcn_mfma_f32_16x16x32_bf16(cw[kk], a0[kk], aE0, 0, 0, 0);
      aE1 = __builtin_amdgcn_mfma_f32_16x16x32_bf16(cw[kk], a1[kk], aE1, 0, 0, 0);
      aO0 = __builtin_amdgcn_mfma_f32_16x16x32_bf16(cw[4 + kk], a0[kk], aO0, 0, 0, 0);
      aO1 = __builtin_amdgcn_mfma_f32_16x16x32_bf16(cw[4 + kk], a1[kk], aO1, 0, 0, 0);
    }
    const float4 bbE = *(const float4*)(bias + p * 32 + l4 * 8);
    const float4 bbO = *(const float4*)(bias + p * 32 + l4 * 8 + 4);
    if (ok0) {
      u16x8 pk;
      pk[0] = f2bf(aE0[0] + bbE.x); pk[1] = f2bf(aE0[1] + bbE.y);
      pk[2] = f2bf(aE0[2] + bbE.z); pk[3] = f2bf(aE0[3] + bbE.w);
      pk[4] = f2bf(aO0[0] + bbO.x); pk[5] = f2bf(aO0[1] + bbO.y);
      pk[6] = f2bf(aO0[2] + bbO.z); pk[7] = f2bf(aO0[3] + bbO.w);
      *(u16x8*)(yp0 + p * 32) = pk;
    }
    if (ok1) {
      u16x8 pk;
      pk[0] = f2bf(aE1[0] + bbE.x); pk[1] = f2bf(aE1[1] + bbE.y);
      pk[2] = f2bf(aE1[2] + bbE.z); pk[3] = f2bf(aE1[3] + bbE.w);
      pk[4] = f2bf(aO1[0] + bbO.x); pk[5] = f2bf(aO1[1] + bbO.y);
      pk[6] = f2bf(aO1[2] + bbO.z); pk[7] = f2bf(aO1[3] + bbO.w);
      *(u16x8*)(yp1 + p * 32) = pk;
    }
  }
}

// ---------- skip GEMM (flat grid, STORE): agg = bf16(X)@W^T + bias ----------
__global__ __launch_bounds__(256) void gemm_skip3(const u16* xbu, const u16* xbt,
                                                  const float* xfu, const float* xft,
                                                  const u16* Wu, const u16* Wtw,
                                                  const float* bu, const float* btw,
                                                  float* aggu, float* aggt, int usexb) {
  const int bx = blockIdx.x;
  int job, lb;
  if (bx < BU) { job = 0; lb = bx; } else { job = 1; lb = bx - BU; }
  const int n = job ? NTT : NUU;
  const int bm = lb * 128;
  const u16* XB = job ? xbt : xbu;
  const float* XF = job ? xft : xfu;
  const u16* Wt = job ? Wtw : Wu;
  const float* bias = job ? btw : bu;
  float* out = job ? aggt : aggu;

  const int wid = threadIdx.x >> 6, lane = threadIdx.x & 63;
  const int l15 = lane & 15, l4 = lane >> 4;
  const int rbase = bm + wid * 32;
  int r0 = rbase + l15;      if (r0 >= n) r0 = n - 1;
  int r1 = rbase + 16 + l15; if (r1 >= n) r1 = n - 1;
  s8v a0[4], a1[4];
  if (usexb) {
    const u16* xb0 = XB + (size_t)r0 * DD + l4 * 8;
    const u16* xb1 = XB + (size_t)r1 * DD + l4 * 8;
    #pragma unroll
    for (int kk = 0; kk < 4; ++kk) {
      a0[kk] = *(const s8v*)(xb0 + kk * 32);
      a1[kk] = *(const s8v*)(xb1 + kk * 32);
    }
  } else {
    const float* xp0 = XF + (size_t)r0 * DD + l4 * 8;
    const float* xp1 = XF + (size_t)r1 * DD + l4 * 8;
    #pragma unroll
    for (int kk = 0; kk < 4; ++kk) {
      a0[kk] = cvt_row8(xp0 + kk * 32);
      a1[kk] = cvt_row8(xp1 + kk * 32);
    }
  }

  const u16* wp = Wt + (size_t)l15 * DD + l4 * 8;
  const bool ok0 = (rbase + l15 < n), ok1 = (rbase + 16 + l15 < n);
  float* yp0 = out + (size_t)(rbase + l15) * DD + l4 * 8;
  float* yp1 = out + (size_t)(rbase + 16 + l15) * DD + l4 * 8;

  s8v w0[8], w1[8];
  #pragma unroll
  for (int kk = 0; kk < 4; ++kk) {
    w0[kk]     = *(const s8v*)(wp + kk * 32);
    w0[4 + kk] = *(const s8v*)(wp + 16 * DD + kk * 32);
  }
  #pragma unroll
  for (int p = 0; p < 4; ++p) {
    const s8v* cw = (p & 1) ? w1 : w0;
    s8v* nw = (p & 1) ? w0 : w1;
    if (p + 1 < 4) {
      const u16* wq = wp + (size_t)(2 * (p + 1)) * 16 * DD;
      #pragma unroll
      for (int kk = 0; kk < 4; ++kk) {
        nw[kk]     = *(const s8v*)(wq + kk * 32);
        nw[4 + kk] = *(const s8v*)(wq + 16 * DD + kk * 32);
      }
    }
    f4v aE0 = {}, aE1 = {}, aO0 = {}, aO1 = {};
    #pragma unroll
    for (int kk = 0; kk < 4; ++kk) {
      aE0 = __builtin_amdgcn_mfma_f32_16x16x32_bf16(cw[kk], a0[kk], aE0, 0, 0, 0);
      aE1 = __builtin_amdgcn_mfma_f32_16x16x32_bf16(cw[kk], a1[kk], aE1, 0, 0, 0);
      aO0 = __builtin_amdgcn_mfma_f32_16x16x32_bf16(cw[4 + kk], a0[kk], aO0, 0, 0, 0);
      aO1 = __builtin_amdgcn_mfma_f32_16x16x32_bf16(cw[4 + kk], a1[kk], aO1, 0, 0, 0);
    }
    const float4 bbE = *(const float4*)(bias + p * 32 + l4 * 8);
    const float4 bbO = *(const float4*)(bias + p * 32 + l4 * 8 + 4);
    if (ok0) {
      *(float4*)(yp0 + p * 32) = make_float4(aE0[0] + bbE.x, aE0[1] + bbE.y, aE0[2] + bbE.z, aE0[3] + bbE.w);
      *(float4*)(yp0 + p * 32 + 4) = make_float4(aO0[0] + bbO.x, aO0[1] + bbO.y, aO0[2] + bbO.z, aO0[3] + bbO.w);
    }
    if (ok1) {
      *(float4*)(yp1 + p * 32) = make_float4(aE1[0] + bbE.x, aE1[1] + bbE.y, aE1[2] + bbE.z, aE1[3] + bbE.w);
      *(float4*)(yp1 + p * 32 + 4) = make_float4(aO1[0] + bbO.x, aO1[1] + bbO.y, aO1[2] + bbO.z, aO1[3] + bbO.w);
    }
  }
}

// ---------- fused edge kernel: one wave per dst node, K-prefetch ----------
template<int HB>
__global__ __launch_bounds__(256) void edge_fused(const u16* __restrict__ q,
                                                  const u16* __restrict__ k,
                                                  const u16* __restrict__ v,
                                                  const int* __restrict__ rptr,
                                                  const int* __restrict__ csrc,
                                                  float* __restrict__ agg,
                                                  int nd, int qs32, int ks32) {
  constexpr int LPH = 64 / HB;
  int node = (int)(((size_t)blockIdx.x * 256 + threadIdx.x) >> 6);
  int lane = threadIdx.x & 63;
  if (node >= nd) return;
  int e0 = rptr[node], e1 = rptr[node + 1];
  if (e0 == e1) return;

  const u32* qp = (const u32*)q + (size_t)node * qs32 + lane * HB;
  u32 qv[HB];
  #pragma unroll
  for (int j = 0; j < HB; ++j) qv[j] = qp[j];

  float m = -1e30f, z = 0.f;
  float acc[2 * HB] = {};

  int s_cur = csrc[e0];
  u32 kcur[HB];
  {
    const u32* kp = (const u32*)k + (size_t)s_cur * ks32 + lane * HB;
    #pragma unroll
    for (int j = 0; j < HB; ++j) kcur[j] = kp[j];
  }

  for (int e = e0; e < e1; ++e) {
    u32 vcur[HB];
    {
      const u32* vp = (const u32*)v + (size_t)s_cur * ks32 + lane * HB;
      #pragma unroll
      for (int j = 0; j < HB; ++j) vcur[j] = vp[j];
    }
    const bool has = (e + 1 < e1);
    int s_nxt = csrc[has ? e + 1 : e0];
    u32 knxt[HB];
    {
      const u32* kp = (const u32*)k + (size_t)s_nxt * ks32 + lane * HB;
      #pragma unroll
      for (int j = 0; j < HB; ++j) knxt[j] = kp[j];
    }

    float dot = 0.f;
    #pragma unroll
    for (int j = 0; j < HB; ++j)
      dot += bflo(qv[j]) * bflo(kcur[j]) + bfhi(qv[j]) * bfhi(kcur[j]);
    #pragma unroll
    for (int o = 1; o < LPH; o <<= 1) dot += __shfl_xor(dot, o);
    dot *= 0.08838834764831845f;   // 1/sqrt(128)
    float w;
    if (dot > m) {
      float sc = __expf(m - dot);
      z *= sc;
      #pragma unroll
      for (int j = 0; j < 2 * HB; ++j) acc[j] *= sc;
      m = dot; w = 1.f;
    } else {
      w = __expf(dot - m);
    }
    z += w;
    #pragma unroll
    for (int j = 0; j < HB; ++j) {
      acc[2 * j]     += w * bflo(vcur[j]);
      acc[2 * j + 1] += w * bfhi(vcur[j]);
    }
    if (has) {
      s_cur = s_nxt;
      #pragma unroll
      for (int j = 0; j < HB; ++j) kcur[j] = knxt[j];
    }
  }
  float inv = 0.25f / z;
  #pragma unroll
  for (int j = 0; j < 2 * HB; ++j) acc[j] *= inv;
  #pragma unroll
  for (int o = LPH; o < 64; o <<= 1) {
    #pragma unroll
    for (int j = 0; j < 2 * HB; ++j) acc[j] += __shfl_xor(acc[j], o);
  }
  if (lane < LPH) {
    float* op = agg + (size_t)node * DD + lane * 2 * HB;
    #pragma unroll
    for (int j = 0; j < 2 * HB; ++j) op[j] += acc[j];
  }
}

// ---------- l0-tu shortcut: uniform softmax over broadcast K/V ----------
// agg[node] += 0.25 * sum_h v0[h]  for nodes with deg > 0 (exact).
template<int HB>
__global__ __launch_bounds__(256) void add_bcast(const u16* __restrict__ v,
                                                 const int* __restrict__ rptr,
                                                 float* __restrict__ agg, int nd) {
  int node = (int)(((size_t)blockIdx.x * 256 + threadIdx.x) >> 6);
  int lane = threadIdx.x & 63;
  if (node >= nd) return;
  if (rptr[node + 1] <= rptr[node]) return;
  const u32* vp = (const u32*)v;   // row 0
  float a0 = 0.f, a1 = 0.f;
  #pragma unroll
  for (int h = 0; h < HB; ++h) {
    u32 u = vp[h * 64 + lane];
    a0 += bflo(u); a1 += bfhi(u);
  }
  float* op = agg + (size_t)node * DD + 2 * lane;
  op[0] += 0.25f * a0;
  op[1] += 0.25f * a1;
}

// ---------- LayerNorm + residual for BOTH node types (+ bf16 mirror write) ----------
__global__ __launch_bounds__(256) void ln2(const float* __restrict__ aggu,
                                           const float* __restrict__ aggt,
                                           const float* __restrict__ g2,
                                           const float* __restrict__ b2,
                                           float* __restrict__ xu,
                                           float* __restrict__ xt,
                                           u16* __restrict__ xbu,
                                           u16* __restrict__ xbt,
                                           int wrb) {
  int wid = (int)(((size_t)blockIdx.x * 256 + threadIdx.x) >> 6);
  int lane = threadIdx.x & 63;
  if (wid >= NUU + NTT) return;
  const float* ap; float* xp; const float* g; const float* b; u16* xbp;
  if (wid < NUU) {
    ap = aggu + (size_t)wid * DD; xp = xu + (size_t)wid * DD;
    xbp = xbu + (size_t)wid * DD; g = g2; b = b2;
  } else {
    int t = wid - NUU;
    ap = aggt + (size_t)t * DD; xp = xt + (size_t)t * DD;
    xbp = xbt + (size_t)t * DD; g = g2 + DD; b = b2 + DD;
  }
  float v0 = ap[lane], v1 = ap[lane + 64];
  float s = v0 + v1;
  #pragma unroll
  for (int o = 1; o < 64; o <<= 1) s += __shfl_xor(s, o);
  float mean = s * (1.0f / DD);
  float d0 = v0 - mean, d1 = v1 - mean;
  float sq = d0 * d0 + d1 * d1;
  #pragma unroll
  for (int o = 1; o < 64; o <<= 1) sq += __shfl_xor(sq, o);
  float rstd = rsqrtf(sq * (1.0f / DD) + 1e-5f);
  float n0 = g[lane]      * d0 * rstd + b[lane]      + xp[lane];
  float n1 = g[lane + 64] * d1 * rstd + b[lane + 64] + xp[lane + 64];
  xp[lane] = n0;
  xp[lane + 64] = n1;
  if (wrb) {
    xbp[lane] = f2bf(n0);
    xbp[lane + 64] = f2bf(n1);
  }
}

extern "C" void kernel_launch(void* const* d_in, const int* in_sizes, int n_in,
                              void* d_out, int out_size, void* d_ws, size_t ws_size,
                              hipStream_t stream) {
  const float* emb_user = (const float*)d_in[0];
  const float* tv_tweet = (const float*)d_in[1];
  const float* W_qkv  = (const float*)d_in[2];
  const float* b_qkv  = (const float*)d_in[3];
  const float* W_skip = (const float*)d_in[4];
  const float* b_skip = (const float*)d_in[5];
  const float* ln_g   = (const float*)d_in[6];
  const float* ln_b   = (const float*)d_in[7];
  const int* edges[3] = { (const int*)d_in[8], (const int*)d_in[9], (const int*)d_in[10] };

  float* x_user  = (float*)d_out;
  float* x_tweet = x_user + (size_t)NUU * DD;

  // ---- workspace layout ----
  auto base = [](int hb) -> size_t {
    return 2359296 + 131072 + 2048
         + (size_t)3 * 100000 * hb * 128 * 2   // q,k,v
         + 76800000                            // agg
         + (size_t)3 * 400032 + (size_t)3 * 400000
         + 1200000 + 4800 + 4096;
  };
  const size_t xbB = 38400000;   // bf16 x mirror (user+tweet)
  int HB, XB;
  if      (ws_size >= base(4) + xbB) { HB = 4; XB = 1; }
  else if (ws_size >= base(4))       { HB = 4; XB = 0; }
  else if (ws_size >= base(2) + xbB) { HB = 2; XB = 1; }
  else if (ws_size >= base(2))       { HB = 2; XB = 0; }
  else if (ws_size >= base(1) + xbB) { HB = 1; XB = 1; }
  else                               { HB = 1; XB = 0; }

  char* w = (char*)d_ws;
  u16* Wtq = (u16*)w;        w += 2359296;
  u16* WtsC = (u16*)w;       w += 131072;
  float* bskC = (float*)w;   w += 2048;
  size_t qkvBytes = (size_t)100000 * HB * DD * 2;
  u16* qb = (u16*)w;         w += qkvBytes;
  u16* kb = (u16*)w;         w += qkvBytes;
  u16* vb = (u16*)w;         w += qkvBytes;
  float* agg_u = (float*)w;  w += (size_t)NUU * DD * 4;
  float* agg_t = (float*)w;  w += (size_t)NTT * DD * 4;
  int* rptrA[3]; int* csrcA[3]; int* cntA[3];
  for (int r = 0; r < 3; ++r) { rptrA[r] = (int*)w; w += 400032; }
  for (int r = 0; r < 3; ++r) { csrcA[r] = (int*)w; w += 400000; }
  cntA[0] = (int*)w; cntA[1] = cntA[0] + 100000; cntA[2] = cntA[0] + 200000; w += 1200000;
  int* bsumA = (int*)w;      w += 4800;
  u16* xb_user = nullptr; u16* xb_tweet = nullptr;
  if (XB) {
    xb_user = (u16*)w;  w += (size_t)NUU * DD * 2;
    xb_tweet = (u16*)w; w += (size_t)NTT * DD * 2;
  }

  init_x2<<<(19500000 + 255) / 256, 256, 0, stream>>>(emb_user, tv_tweet, x_user, x_tweet,
                                                      cntA[0], xb_user, xb_tweet, XB);
  conv_w<<<(18 * 512 * 128 + 255) / 256, 256, 0, stream>>>(W_qkv, W_skip, b_skip, Wtq, WtsC, bskC);

  hist3<<<(3 * EE + 255) / 256, 256, 0, stream>>>(edges[0], edges[1], edges[2],
                                                  cntA[0], cntA[1], cntA[2]);
  bsum3<<<783, 256, 0, stream>>>(cntA[0], cntA[1], cntA[2], bsumA);
  bscan3<<<3, 256, 0, stream>>>(bsumA);
  rptr3<<<783, 256, 0, stream>>>(cntA[0], cntA[1], cntA[2], bsumA, rptrA[0], rptrA[1], rptrA[2]);
  fill3<<<(3 * EE + 255) / 256, 256, 0, stream>>>(edges[0], edges[1], edges[2],
                                                  cntA[0], cntA[1], cntA[2],
                                                  csrcA[0], csrcA[1], csrcA[2]);

  const int stt[3] = {0, 0, 1}, dtt[3] = {0, 1, 0};
  const int cnt2[2] = {NUU, NTT};
  float* xs[2]   = {x_user, x_tweet};
  u16* xbs[2]    = {xb_user, xb_tweet};
  float* aggs[2] = {agg_u, agg_t};

  for (int l = 0; l < 2; ++l) {
    gemm_skip3<<<BU + BT, 256, 0, stream>>>(
        xb_user, xb_tweet, x_user, x_tweet,
        WtsC + (size_t)(2 * l) * 128 * 128, WtsC + (size_t)(2 * l + 1) * 128 * 128,
        bskC + (size_t)(2 * l) * 128, bskC + (size_t)(2 * l + 1) * 128,
        agg_u, agg_t, XB);

    for (int r = 0; r < 3; ++r) {
      const int st = stt[r], dt = dtt[r];
      const int ns = cnt2[st], nd = cnt2[dt];
      const int mat = l * 3 + r;
      const bool qDeg = (l == 0 && dt == 1);   // ut l0: q broadcast
      const bool kDeg = (l == 0 && st == 1);   // tu l0: k,v broadcast
      const bool uniSM = kDeg;                 // uniform softmax shortcut

      for (int h0 = 0; h0 < HH; h0 += HB) {
        GRel ga;
        ga.Xqb = xbs[dt]; ga.Xkvb = xbs[st];
        ga.Xqf = xs[dt];  ga.Xkvf = xs[st];
        ga.Wfam = Wtq + (size_t)mat * 3 * 512 * 128;
        ga.bfam = b_qkv + (size_t)mat * 3 * HCC;
        ga.oq = qb; ga.ok = kb; ga.ov = vb;
        ga.nq = (qDeg || uniSM) ? 1 : nd;      // uniSM: q unused, skip its GEMM
        ga.nkv = kDeg ? 1 : ns;
        ga.bq = (ga.nq + 127) / 128;
        ga.bkv = (ga.nkv + 127) / 128;
        ga.ldy = HB * DD; ga.col0 = h0 * DD;
        ga.usexb = XB;
        dim3 gg(ga.bq + 2 * ga.bkv, 1);
        if (HB == 4)      gemm_rel<16><<<gg, 256, 0, stream>>>(ga);
        else if (HB == 2) gemm_rel<8><<<gg, 256, 0, stream>>>(ga);
        else              gemm_rel<4><<<gg, 256, 0, stream>>>(ga);

        const int eblk = (nd + 3) / 4;
        if (uniSM) {
          if (HB == 4)      add_bcast<4><<<eblk, 256, 0, stream>>>(vb, rptrA[r], aggs[dt], nd);
          else if (HB == 2) add_bcast<2><<<eblk, 256, 0, stream>>>(vb, rptrA[r], aggs[dt], nd);
          else              add_bcast<1><<<eblk, 256, 0, stream>>>(vb, rptrA[r], aggs[dt], nd);
        } else {
          const int qs32 = qDeg ? 0 : HB * DD / 2;
          const int ks32 = kDeg ? 0 : HB * DD / 2;
          if (HB == 4)
            edge_fused<4><<<eblk, 256, 0, stream>>>(qb, kb, vb, rptrA[r], csrcA[r], aggs[dt], nd, qs32, ks32);
          else if (HB == 2)
            edge_fused<2><<<eblk, 256, 0, stream>>>(qb, kb, vb, rptrA[r], csrcA[r], aggs[dt], nd, qs32, ks32);
          else
            edge_fused<1><<<eblk, 256, 0, stream>>>(qb, kb, vb, rptrA[r], csrcA[r], aggs[dt], nd, qs32, ks32);
        }
      }
    }
    ln2<<<(NUU + NTT + 3) / 4, 256, 0, stream>>>(agg_u, agg_t,
                                                 ln_g + (size_t)l * 2 * DD,
                                                 ln_b + (size_t)l * 2 * DD,
                                                 x_user, x_tweet,
                                                 xb_user, xb_tweet, XB && l == 0);
  }
}

// Round 9
// 1162.707 us; speedup vs baseline: 3.5637x; 1.0294x over previous
//
#include <hip/hip_runtime.h>
#include <hip/hip_bf16.h>
#include <math.h>

typedef unsigned short u16;
typedef unsigned int   u32;
typedef __attribute__((ext_vector_type(8))) short s8v;    // 8 x bf16
typedef __attribute__((ext_vector_type(8))) unsigned short u16x8;
typedef __attribute__((ext_vector_type(4))) float f4v;    // MFMA accumulator

#define NUU 50000
#define NTT 100000
#define EE  100000
#define DD  128
#define HH  4
#define HCC 512
#define BU  391                 // ceil(NUU/128)
#define BT  782                 // ceil(NTT/128)

// ---------- helpers ----------
__device__ __forceinline__ float bflo(u32 u) { return __uint_as_float(u << 16); }
__device__ __forceinline__ float bfhi(u32 u) { return __uint_as_float(u & 0xFFFF0000u); }
__device__ __forceinline__ u16 f2bf(float f) {
  u32 u = __float_as_uint(f);
  u32 r = (u + 0x7FFFu + ((u >> 16) & 1u)) >> 16;
  return (u16)r;
}
__device__ __forceinline__ s8v cvt_row8(const float* __restrict__ p) {
  float4 u = *(const float4*)p;
  float4 v = *(const float4*)(p + 4);
  s8v r;
  r[0] = (short)f2bf(u.x); r[1] = (short)f2bf(u.y);
  r[2] = (short)f2bf(u.z); r[3] = (short)f2bf(u.w);
  r[4] = (short)f2bf(v.x); r[5] = (short)f2bf(v.y);
  r[6] = (short)f2bf(v.z); r[7] = (short)f2bf(v.w);
  return r;
}
__device__ __forceinline__ int colperm(int c) {
  return (c & ~31) | (((c >> 2) & 3) << 3) | (((c >> 4) & 1) << 2) | (c & 3);
}

// ---------- init ----------
__global__ __launch_bounds__(256) void init_x2(const float* __restrict__ emb,
                                               const float* __restrict__ tv,
                                               float* __restrict__ xu,
                                               float* __restrict__ xt,
                                               int* __restrict__ cz,
                                               u16* __restrict__ xbu,
                                               u16* __restrict__ xbt,
                                               int useb) {
  size_t idx = (size_t)blockIdx.x * 256 + threadIdx.x;
  const size_t nu = (size_t)NUU * DD;
  const size_t nt = (size_t)NTT * DD;
  if (idx < nu) {
    float v = emb[idx];
    xu[idx] = v;
    if (useb) xbu[idx] = f2bf(v);
  } else if (idx < nu + nt) {
    size_t j = idx - nu;
    float v = tv[j & (DD - 1)];
    xt[j] = v;
    if (useb) xbt[j] = f2bf(v);
  } else {
    size_t j = idx - (nu + nt);
    if (j < 300000) cz[j] = 0;
  }
}

// ---------- weights ----------
__global__ __launch_bounds__(256) void conv_w(const float* __restrict__ Wq,
                                              const float* __restrict__ Wsk,
                                              const float* __restrict__ bsk,
                                              u16* __restrict__ Wtq,
                                              u16* __restrict__ WtsC,
                                              float* __restrict__ bskC) {
  int idx = blockIdx.x * 256 + threadIdx.x;
  if (idx < 18 * 512 * 128) {
    int k = idx & 127, cp = (idx >> 7) & 511, mat = idx >> 16;
    Wtq[idx] = f2bf(Wq[((size_t)mat * 128 + k) * 512 + colperm(cp)]);
  }
  if (idx < 4 * 128 * 128) {
    int k = idx & 127, cp = (idx >> 7) & 127, m = idx >> 14;
    int l = m >> 1, isT = m & 1, col = colperm(cp);
    float v;
    if (isT) v = Wsk[((size_t)(l * 3 + 1) * 128 + k) * 128 + col];
    else     v = Wsk[((size_t)(l * 3 + 0) * 128 + k) * 128 + col]
               + Wsk[((size_t)(l * 3 + 2) * 128 + k) * 128 + col];
    WtsC[idx] = f2bf(v);
  }
  if (idx < 4 * 128) {
    int m = idx >> 7, c = idx & 127;
    int l = m >> 1, isT = m & 1;
    bskC[idx] = isT ? bsk[(size_t)(l * 3 + 1) * 128 + c]
                    : bsk[(size_t)(l * 3 + 0) * 128 + c] + bsk[(size_t)(l * 3 + 2) * 128 + c];
  }
}

// ---------- CSR build (3 relations merged) ----------
__global__ __launch_bounds__(256) void hist3(const int* e0, const int* e1, const int* e2,
                                             int* c0, int* c1, int* c2) {
  int idx = blockIdx.x * 256 + threadIdx.x;
  if (idx >= 3 * EE) return;
  int r = idx / EE, e = idx - r * EE;
  const int* edst = (r == 0 ? e0 : r == 1 ? e1 : e2) + EE;
  int* cnt = r == 0 ? c0 : r == 1 ? c1 : c2;
  atomicAdd(&cnt[edst[e]], 1);
}

__global__ __launch_bounds__(256) void bsum3(const int* c0, const int* c1, const int* c2,
                                             int* __restrict__ bsumA) {
  int b = blockIdx.x;
  int r, lb, n;
  if (b < 196)      { r = 0; lb = b;       n = NUU; }
  else if (b < 587) { r = 1; lb = b - 196; n = NTT; }
  else              { r = 2; lb = b - 587; n = NUU; }
  const int* cnt = r == 0 ? c0 : r == 1 ? c1 : c2;
  int i = lb * 256 + threadIdx.x;
  int v = (i < n) ? cnt[i] : 0;
  #pragma unroll
  for (int o = 1; o < 64; o <<= 1) v += __shfl_xor(v, o);
  __shared__ int ws4[4];
  if ((threadIdx.x & 63) == 0) ws4[threadIdx.x >> 6] = v;
  __syncthreads();
  if (threadIdx.x == 0) bsumA[r * 400 + lb] = ws4[0] + ws4[1] + ws4[2] + ws4[3];
}

__global__ __launch_bounds__(256) void bscan3(int* __restrict__ bsumA) {
  int r = blockIdx.x;
  int* bsum = bsumA + r * 400;
  const int nb = (r == 1) ? 391 : 196;
  __shared__ int sh[256];
  __shared__ int runs;
  if (threadIdx.x == 0) runs = 0;
  __syncthreads();
  for (int base = 0; base < nb; base += 256) {
    int i = base + threadIdx.x;
    int v = (i < nb) ? bsum[i] : 0;
    sh[threadIdx.x] = v;
    __syncthreads();
    for (int o = 1; o < 256; o <<= 1) {
      int t = (threadIdx.x >= o) ? sh[threadIdx.x - o] : 0;
      __syncthreads();
      sh[threadIdx.x] += t;
      __syncthreads();
    }
    int incl = sh[threadIdx.x];
    int r0 = runs;
    if (i < nb) bsum[i] = r0 + incl - v;
    __syncthreads();
    if (threadIdx.x == 0) runs = r0 + sh[255];
    __syncthreads();
  }
}

__global__ __launch_bounds__(256) void rptr3(int* c0, int* c1, int* c2,
                                             const int* __restrict__ bsumA,
                                             int* r0p, int* r1p, int* r2p) {
  int b = blockIdx.x;
  int r, lb, n;
  if (b < 196)      { r = 0; lb = b;       n = NUU; }
  else if (b < 587) { r = 1; lb = b - 196; n = NTT; }
  else              { r = 2; lb = b - 587; n = NUU; }
  int* cnt = r == 0 ? c0 : r == 1 ? c1 : c2;
  int* rptr = r == 0 ? r0p : r == 1 ? r1p : r2p;
  __shared__ int sh[256];
  int i = lb * 256 + threadIdx.x;
  int v = (i < n) ? cnt[i] : 0;
  sh[threadIdx.x] = v;
  __syncthreads();
  for (int o = 1; o < 256; o <<= 1) {
    int t = (threadIdx.x >= o) ? sh[threadIdx.x - o] : 0;
    __syncthreads();
    sh[threadIdx.x] += t;
    __syncthreads();
  }
  int excl = sh[threadIdx.x] - v + bsumA[r * 400 + lb];
  if (i < n) { rptr[i] = excl; cnt[i] = excl; }
  if (i == 0) rptr[n] = EE;
}

__global__ __launch_bounds__(256) void fill3(const int* e0, const int* e1, const int* e2,
                                             int* c0, int* c1, int* c2,
                                             int* s0, int* s1, int* s2) {
  int idx = blockIdx.x * 256 + threadIdx.x;
  if (idx >= 3 * EE) return;
  int r = idx / EE, e = idx - r * EE;
  const int* ebase = (r == 0 ? e0 : r == 1 ? e1 : e2);
  int* cursor = r == 0 ? c0 : r == 1 ? c1 : c2;
  int* csrc = r == 0 ? s0 : r == 1 ? s1 : s2;
  int pos = atomicAdd(&cursor[ebase[EE + e]], 1);
  csrc[pos] = ebase[e];
}

// ---------- per-relation fused QKV GEMM ----------
struct GRel {
  const u16* Xqb; const u16* Xkvb;
  const float* Xqf; const float* Xkvf;
  const u16* Wfam; const float* bfam;
  u16 *oq, *ok, *ov;
  int nq, nkv, bq, bkv, ldy, col0, usexb;
};

template<int PN>
__global__ __launch_bounds__(256) void gemm_rel(GRel a) {
  const int bx = blockIdx.x;
  int mat, lb, n; const u16* Xb; const float* Xf;
  if (bx < a.bq) { mat = 0; lb = bx; n = a.nq; Xb = a.Xqb; Xf = a.Xqf; }
  else {
    int t = bx - a.bq;
    if (t < a.bkv) { mat = 1; lb = t; } else { mat = 2; lb = t - a.bkv; }
    n = a.nkv; Xb = a.Xkvb; Xf = a.Xkvf;
  }
  const int bm = lb * 128;
  const u16* Wt = a.Wfam + (size_t)mat * 512 * 128;
  const float* bias = a.bfam + (size_t)mat * HCC + a.col0;
  u16* Y = (mat == 0) ? a.oq : (mat == 1) ? a.ok : a.ov;
  const int ldy = a.ldy;

  const int wid = threadIdx.x >> 6, lane = threadIdx.x & 63;
  const int l15 = lane & 15, l4 = lane >> 4;
  const int rbase = bm + wid * 32;
  int r0 = rbase + l15;      if (r0 >= n) r0 = n - 1;
  int r1 = rbase + 16 + l15; if (r1 >= n) r1 = n - 1;
  s8v a0[4], a1[4];
  if (a.usexb) {
    const u16* xb0 = Xb + (size_t)r0 * DD + l4 * 8;
    const u16* xb1 = Xb + (size_t)r1 * DD + l4 * 8;
    #pragma unroll
    for (int kk = 0; kk < 4; ++kk) {
      a0[kk] = *(const s8v*)(xb0 + kk * 32);
      a1[kk] = *(const s8v*)(xb1 + kk * 32);
    }
  } else {
    const float* xp0 = Xf + (size_t)r0 * DD + l4 * 8;
    const float* xp1 = Xf + (size_t)r1 * DD + l4 * 8;
    #pragma unroll
    for (int kk = 0; kk < 4; ++kk) {
      a0[kk] = cvt_row8(xp0 + kk * 32);
      a1[kk] = cvt_row8(xp1 + kk * 32);
    }
  }

  const u16* wp = Wt + (size_t)(a.col0 + l15) * DD + l4 * 8;
  const bool ok0 = (rbase + l15 < n), ok1 = (rbase + 16 + l15 < n);
  u16* yp0 = Y + (size_t)(rbase + l15) * ldy + l4 * 8;
  u16* yp1 = Y + (size_t)(rbase + 16 + l15) * ldy + l4 * 8;

  s8v w0[8], w1[8];
  #pragma unroll
  for (int kk = 0; kk < 4; ++kk) {
    w0[kk]     = *(const s8v*)(wp + kk * 32);
    w0[4 + kk] = *(const s8v*)(wp + 16 * DD + kk * 32);
  }
  #pragma unroll
  for (int p = 0; p < PN; ++p) {
    const s8v* cw = (p & 1) ? w1 : w0;
    s8v* nw = (p & 1) ? w0 : w1;
    if (p + 1 < PN) {
      const u16* wq = wp + (size_t)(2 * (p + 1)) * 16 * DD;
      #pragma unroll
      for (int kk = 0; kk < 4; ++kk) {
        nw[kk]     = *(const s8v*)(wq + kk * 32);
        nw[4 + kk] = *(const s8v*)(wq + 16 * DD + kk * 32);
      }
    }
    f4v aE0 = {}, aE1 = {}, aO0 = {}, aO1 = {};
    #pragma unroll
    for (int kk = 0; kk < 4; ++kk) {
      aE0 = __builtin_amdgcn_mfma_f32_16x16x32_bf16(cw[kk], a0[kk], aE0, 0, 0, 0);
      aE1 = __builtin_amdgcn_mfma_f32_16x16x32_bf16(cw[kk], a1[kk], aE1, 0, 0, 0);
      aO0 = __builtin_amdgcn_mfma_f32_16x16x32_bf16(cw[4 + kk], a0[kk], aO0, 0, 0, 0);
      aO1 = __builtin_amdgcn_mfma_f32_16x16x32_bf16(cw[4 + kk], a1[kk], aO1, 0, 0, 0);
    }
    const float4 bbE = *(const float4*)(bias + p * 32 + l4 * 8);
    const float4 bbO = *(const float4*)(bias + p * 32 + l4 * 8 + 4);
    if (ok0) {
      u16x8 pk;
      pk[0] = f2bf(aE0[0] + bbE.x); pk[1] = f2bf(aE0[1] + bbE.y);
      pk[2] = f2bf(aE0[2] + bbE.z); pk[3] = f2bf(aE0[3] + bbE.w);
      pk[4] = f2bf(aO0[0] + bbO.x); pk[5] = f2bf(aO0[1] + bbO.y);
      pk[6] = f2bf(aO0[2] + bbO.z); pk[7] = f2bf(aO0[3] + bbO.w);
      *(u16x8*)(yp0 + p * 32) = pk;
    }
    if (ok1) {
      u16x8 pk;
      pk[0] = f2bf(aE1[0] + bbE.x); pk[1] = f2bf(aE1[1] + bbE.y);
      pk[2] = f2bf(aE1[2] + bbE.z); pk[3] = f2bf(aE1[3] + bbE.w);
      pk[4] = f2bf(aO1[0] + bbO.x); pk[5] = f2bf(aO1[1] + bbO.y);
      pk[6] = f2bf(aO1[2] + bbO.z); pk[7] = f2bf(aO1[3] + bbO.w);
      *(u16x8*)(yp1 + p * 32) = pk;
    }
  }
}

// ---------- skip GEMM (flat grid, STORE) ----------
__global__ __launch_bounds__(256) void gemm_skip3(const u16* xbu, const u16* xbt,
                                                  const float* xfu, const float* xft,
                                                  const u16* Wu, const u16* Wtw,
                                                  const float* bu, const float* btw,
                                                  float* aggu, float* aggt, int usexb) {
  const int bx = blockIdx.x;
  int job, lb;
  if (bx < BU) { job = 0; lb = bx; } else { job = 1; lb = bx - BU; }
  const int n = job ? NTT : NUU;
  const int bm = lb * 128;
  const u16* XB = job ? xbt : xbu;
  const float* XF = job ? xft : xfu;
  const u16* Wt = job ? Wtw : Wu;
  const float* bias = job ? btw : bu;
  float* out = job ? aggt : aggu;

  const int wid = threadIdx.x >> 6, lane = threadIdx.x & 63;
  const int l15 = lane & 15, l4 = lane >> 4;
  const int rbase = bm + wid * 32;
  int r0 = rbase + l15;      if (r0 >= n) r0 = n - 1;
  int r1 = rbase + 16 + l15; if (r1 >= n) r1 = n - 1;
  s8v a0[4], a1[4];
  if (usexb) {
    const u16* xb0 = XB + (size_t)r0 * DD + l4 * 8;
    const u16* xb1 = XB + (size_t)r1 * DD + l4 * 8;
    #pragma unroll
    for (int kk = 0; kk < 4; ++kk) {
      a0[kk] = *(const s8v*)(xb0 + kk * 32);
      a1[kk] = *(const s8v*)(xb1 + kk * 32);
    }
  } else {
    const float* xp0 = XF + (size_t)r0 * DD + l4 * 8;
    const float* xp1 = XF + (size_t)r1 * DD + l4 * 8;
    #pragma unroll
    for (int kk = 0; kk < 4; ++kk) {
      a0[kk] = cvt_row8(xp0 + kk * 32);
      a1[kk] = cvt_row8(xp1 + kk * 32);
    }
  }

  const u16* wp = Wt + (size_t)l15 * DD + l4 * 8;
  const bool ok0 = (rbase + l15 < n), ok1 = (rbase + 16 + l15 < n);
  float* yp0 = out + (size_t)(rbase + l15) * DD + l4 * 8;
  float* yp1 = out + (size_t)(rbase + 16 + l15) * DD + l4 * 8;

  s8v w0[8], w1[8];
  #pragma unroll
  for (int kk = 0; kk < 4; ++kk) {
    w0[kk]     = *(const s8v*)(wp + kk * 32);
    w0[4 + kk] = *(const s8v*)(wp + 16 * DD + kk * 32);
  }
  #pragma unroll
  for (int p = 0; p < 4; ++p) {
    const s8v* cw = (p & 1) ? w1 : w0;
    s8v* nw = (p & 1) ? w0 : w1;
    if (p + 1 < 4) {
      const u16* wq = wp + (size_t)(2 * (p + 1)) * 16 * DD;
      #pragma unroll
      for (int kk = 0; kk < 4; ++kk) {
        nw[kk]     = *(const s8v*)(wq + kk * 32);
        nw[4 + kk] = *(const s8v*)(wq + 16 * DD + kk * 32);
      }
    }
    f4v aE0 = {}, aE1 = {}, aO0 = {}, aO1 = {};
    #pragma unroll
    for (int kk = 0; kk < 4; ++kk) {
      aE0 = __builtin_amdgcn_mfma_f32_16x16x32_bf16(cw[kk], a0[kk], aE0, 0, 0, 0);
      aE1 = __builtin_amdgcn_mfma_f32_16x16x32_bf16(cw[kk], a1[kk], aE1, 0, 0, 0);
      aO0 = __builtin_amdgcn_mfma_f32_16x16x32_bf16(cw[4 + kk], a0[kk], aO0, 0, 0, 0);
      aO1 = __builtin_amdgcn_mfma_f32_16x16x32_bf16(cw[4 + kk], a1[kk], aO1, 0, 0, 0);
    }
    const float4 bbE = *(const float4*)(bias + p * 32 + l4 * 8);
    const float4 bbO = *(const float4*)(bias + p * 32 + l4 * 8 + 4);
    if (ok0) {
      *(float4*)(yp0 + p * 32) = make_float4(aE0[0] + bbE.x, aE0[1] + bbE.y, aE0[2] + bbE.z, aE0[3] + bbE.w);
      *(float4*)(yp0 + p * 32 + 4) = make_float4(aO0[0] + bbO.x, aO0[1] + bbO.y, aO0[2] + bbO.z, aO0[3] + bbO.w);
    }
    if (ok1) {
      *(float4*)(yp1 + p * 32) = make_float4(aE1[0] + bbE.x, aE1[1] + bbE.y, aE1[2] + bbE.z, aE1[3] + bbE.w);
      *(float4*)(yp1 + p * 32 + 4) = make_float4(aO1[0] + bbO.x, aO1[1] + bbO.y, aO1[2] + bbO.z, aO1[3] + bbO.w);
    }
  }
}

// ---------- fused edge kernel: one wave per dst node; deg-1 fast path ----------
template<int HB>
__global__ __launch_bounds__(256) void edge_fused(const u16* __restrict__ q,
                                                  const u16* __restrict__ k,
                                                  const u16* __restrict__ v,
                                                  const int* __restrict__ rptr,
                                                  const int* __restrict__ csrc,
                                                  float* __restrict__ agg,
                                                  int nd, int qs32, int ks32) {
  constexpr int LPH = 64 / HB;
  int node = (int)(((size_t)blockIdx.x * 256 + threadIdx.x) >> 6);
  int lane = threadIdx.x & 63;
  if (node >= nd) return;
  int e0 = rptr[node], e1 = rptr[node + 1];
  if (e0 == e1) return;

  float acc[2 * HB];

  if (e1 - e0 == 1) {
    // single edge: softmax weight = 1 exactly; no q/K needed
    int s = csrc[e0];
    const u32* vp = (const u32*)v + (size_t)s * ks32 + lane * HB;
    #pragma unroll
    for (int j = 0; j < HB; ++j) {
      u32 u = vp[j];
      acc[2 * j] = bflo(u);
      acc[2 * j + 1] = bfhi(u);
    }
  } else {
    const u32* qp = (const u32*)q + (size_t)node * qs32 + lane * HB;
    u32 qv[HB];
    #pragma unroll
    for (int j = 0; j < HB; ++j) qv[j] = qp[j];

    float m = -1e30f, z = 0.f;
    #pragma unroll
    for (int j = 0; j < 2 * HB; ++j) acc[j] = 0.f;

    int s_cur = csrc[e0];
    u32 kcur[HB];
    {
      const u32* kp = (const u32*)k + (size_t)s_cur * ks32 + lane * HB;
      #pragma unroll
      for (int j = 0; j < HB; ++j) kcur[j] = kp[j];
    }

    for (int e = e0; e < e1; ++e) {
      u32 vcur[HB];
      {
        const u32* vp = (const u32*)v + (size_t)s_cur * ks32 + lane * HB;
        #pragma unroll
        for (int j = 0; j < HB; ++j) vcur[j] = vp[j];
      }
      const bool has = (e + 1 < e1);
      int s_nxt = csrc[has ? e + 1 : e0];
      u32 knxt[HB];
      {
        const u32* kp = (const u32*)k + (size_t)s_nxt * ks32 + lane * HB;
        #pragma unroll
        for (int j = 0; j < HB; ++j) knxt[j] = kp[j];
      }

      float dot = 0.f;
      #pragma unroll
      for (int j = 0; j < HB; ++j)
        dot += bflo(qv[j]) * bflo(kcur[j]) + bfhi(qv[j]) * bfhi(kcur[j]);
      #pragma unroll
      for (int o = 1; o < LPH; o <<= 1) dot += __shfl_xor(dot, o);
      dot *= 0.08838834764831845f;   // 1/sqrt(128)
      float w;
      if (dot > m) {
        float sc = __expf(m - dot);
        z *= sc;
        #pragma unroll
        for (int j = 0; j < 2 * HB; ++j) acc[j] *= sc;
        m = dot; w = 1.f;
      } else {
        w = __expf(dot - m);
      }
      z += w;
      #pragma unroll
      for (int j = 0; j < HB; ++j) {
        acc[2 * j]     += w * bflo(vcur[j]);
        acc[2 * j + 1] += w * bfhi(vcur[j]);
      }
      if (has) {
        s_cur = s_nxt;
        #pragma unroll
        for (int j = 0; j < HB; ++j) kcur[j] = knxt[j];
      }
    }
    float iz = 1.f / z;
    #pragma unroll
    for (int j = 0; j < 2 * HB; ++j) acc[j] *= iz;
  }

  #pragma unroll
  for (int j = 0; j < 2 * HB; ++j) acc[j] *= 0.25f;
  #pragma unroll
  for (int o = LPH; o < 64; o <<= 1) {
    #pragma unroll
    for (int j = 0; j < 2 * HB; ++j) acc[j] += __shfl_xor(acc[j], o);
  }
  if (lane < LPH) {
    float* op = agg + (size_t)node * DD + lane * 2 * HB;
    #pragma unroll
    for (int j = 0; j < 2 * HB; ++j) op[j] += acc[j];
  }
}

// ---------- l0-tu shortcut: uniform softmax over broadcast K/V ----------
template<int HB>
__global__ __launch_bounds__(256) void add_bcast(const u16* __restrict__ v,
                                                 const int* __restrict__ rptr,
                                                 float* __restrict__ agg, int nd) {
  int node = (int)(((size_t)blockIdx.x * 256 + threadIdx.x) >> 6);
  int lane = threadIdx.x & 63;
  if (node >= nd) return;
  if (rptr[node + 1] <= rptr[node]) return;
  const u32* vp = (const u32*)v;   // row 0
  float a0 = 0.f, a1 = 0.f;
  #pragma unroll
  for (int h = 0; h < HB; ++h) {
    u32 u = vp[h * 64 + lane];
    a0 += bflo(u); a1 += bfhi(u);
  }
  float* op = agg + (size_t)node * DD + 2 * lane;
  op[0] += 0.25f * a0;
  op[1] += 0.25f * a1;
}

// ---------- LayerNorm + residual (+ bf16 mirror write) ----------
__global__ __launch_bounds__(256) void ln2(const float* __restrict__ aggu,
                                           const float* __restrict__ aggt,
                                           const float* __restrict__ g2,
                                           const float* __restrict__ b2,
                                           float* __restrict__ xu,
                                           float* __restrict__ xt,
                                           u16* __restrict__ xbu,
                                           u16* __restrict__ xbt,
                                           int wrb) {
  int wid = (int)(((size_t)blockIdx.x * 256 + threadIdx.x) >> 6);
  int lane = threadIdx.x & 63;
  if (wid >= NUU + NTT) return;
  const float* ap; float* xp; const float* g; const float* b; u16* xbp;
  if (wid < NUU) {
    ap = aggu + (size_t)wid * DD; xp = xu + (size_t)wid * DD;
    xbp = xbu + (size_t)wid * DD; g = g2; b = b2;
  } else {
    int t = wid - NUU;
    ap = aggt + (size_t)t * DD; xp = xt + (size_t)t * DD;
    xbp = xbt + (size_t)t * DD; g = g2 + DD; b = b2 + DD;
  }
  float v0 = ap[lane], v1 = ap[lane + 64];
  float s = v0 + v1;
  #pragma unroll
  for (int o = 1; o < 64; o <<= 1) s += __shfl_xor(s, o);
  float mean = s * (1.0f / DD);
  float d0 = v0 - mean, d1 = v1 - mean;
  float sq = d0 * d0 + d1 * d1;
  #pragma unroll
  for (int o = 1; o < 64; o <<= 1) sq += __shfl_xor(sq, o);
  float rstd = rsqrtf(sq * (1.0f / DD) + 1e-5f);
  float n0 = g[lane]      * d0 * rstd + b[lane]      + xp[lane];
  float n1 = g[lane + 64] * d1 * rstd + b[lane + 64] + xp[lane + 64];
  xp[lane] = n0;
  xp[lane + 64] = n1;
  if (wrb) {
    xbp[lane] = f2bf(n0);
    xbp[lane + 64] = f2bf(n1);
  }
}

extern "C" void kernel_launch(void* const* d_in, const int* in_sizes, int n_in,
                              void* d_out, int out_size, void* d_ws, size_t ws_size,
                              hipStream_t stream) {
  const float* emb_user = (const float*)d_in[0];
  const float* tv_tweet = (const float*)d_in[1];
  const float* W_qkv  = (const float*)d_in[2];
  const float* b_qkv  = (const float*)d_in[3];
  const float* W_skip = (const float*)d_in[4];
  const float* b_skip = (const float*)d_in[5];
  const float* ln_g   = (const float*)d_in[6];
  const float* ln_b   = (const float*)d_in[7];
  const int* edges[3] = { (const int*)d_in[8], (const int*)d_in[9], (const int*)d_in[10] };

  float* x_user  = (float*)d_out;
  float* x_tweet = x_user + (size_t)NUU * DD;

  // ---- workspace tiers ----
  // common = weights + agg + csr + pad
  const size_t common = 2359296 + 131072 + 2048 + 76800000
                      + (size_t)3 * 400032 + (size_t)3 * 400000
                      + 1200000 + 4800 + 4096;
  const size_t fwArena = 256000000;                 // tight per-relation full-width q/k/v
  const size_t xbB = 38400000;
  int FW = 0, HB = 2, XB = 0;
  if      (ws_size >= common + fwArena + xbB)              { FW = 1; HB = 4; XB = 1; }
  else if (ws_size >= common + fwArena)                    { FW = 1; HB = 4; XB = 0; }
  else if (ws_size >= common + (size_t)3 * 51200000 + xbB) { HB = 2; XB = 1; }
  else if (ws_size >= common + (size_t)3 * 51200000)       { HB = 2; XB = 0; }
  else if (ws_size >= common + (size_t)3 * 25600000 + xbB) { HB = 1; XB = 1; }
  else                                                     { HB = 1; XB = 0; }

  char* w = (char*)d_ws;
  u16* Wtq = (u16*)w;        w += 2359296;
  u16* WtsC = (u16*)w;       w += 131072;
  float* bskC = (float*)w;   w += 2048;
  u16* arena = (u16*)w;      // FW mode: packed per relation; chunk mode: 3 fixed buffers
  size_t qkvBytes = FW ? fwArena : (size_t)3 * 100000 * HB * DD * 2;
  u16* qb = arena;
  u16* kb = arena + (size_t)100000 * HB * DD;
  u16* vb = arena + (size_t)200000 * HB * DD;
  w += qkvBytes;
  float* agg_u = (float*)w;  w += (size_t)NUU * DD * 4;
  float* agg_t = (float*)w;  w += (size_t)NTT * DD * 4;
  int* rptrA[3]; int* csrcA[3]; int* cntA[3];
  for (int r = 0; r < 3; ++r) { rptrA[r] = (int*)w; w += 400032; }
  for (int r = 0; r < 3; ++r) { csrcA[r] = (int*)w; w += 400000; }
  cntA[0] = (int*)w; cntA[1] = cntA[0] + 100000; cntA[2] = cntA[0] + 200000; w += 1200000;
  int* bsumA = (int*)w;      w += 4800;
  u16* xb_user = nullptr; u16* xb_tweet = nullptr;
  if (XB) {
    xb_user = (u16*)w;  w += (size_t)NUU * DD * 2;
    xb_tweet = (u16*)w; w += (size_t)NTT * DD * 2;
  }

  init_x2<<<(19500000 + 255) / 256, 256, 0, stream>>>(emb_user, tv_tweet, x_user, x_tweet,
                                                      cntA[0], xb_user, xb_tweet, XB);
  conv_w<<<(18 * 512 * 128 + 255) / 256, 256, 0, stream>>>(W_qkv, W_skip, b_skip, Wtq, WtsC, bskC);

  hist3<<<(3 * EE + 255) / 256, 256, 0, stream>>>(edges[0], edges[1], edges[2],
                                                  cntA[0], cntA[1], cntA[2]);
  bsum3<<<783, 256, 0, stream>>>(cntA[0], cntA[1], cntA[2], bsumA);
  bscan3<<<3, 256, 0, stream>>>(bsumA);
  rptr3<<<783, 256, 0, stream>>>(cntA[0], cntA[1], cntA[2], bsumA, rptrA[0], rptrA[1], rptrA[2]);
  fill3<<<(3 * EE + 255) / 256, 256, 0, stream>>>(edges[0], edges[1], edges[2],
                                                  cntA[0], cntA[1], cntA[2],
                                                  csrcA[0], csrcA[1], csrcA[2]);

  const int stt[3] = {0, 0, 1}, dtt[3] = {0, 1, 0};
  const int cnt2[2] = {NUU, NTT};
  float* xs[2]   = {x_user, x_tweet};
  u16* xbs[2]    = {xb_user, xb_tweet};
  float* aggs[2] = {agg_u, agg_t};

  for (int l = 0; l < 2; ++l) {
    gemm_skip3<<<BU + BT, 256, 0, stream>>>(
        xb_user, xb_tweet, x_user, x_tweet,
        WtsC + (size_t)(2 * l) * 128 * 128, WtsC + (size_t)(2 * l + 1) * 128 * 128,
        bskC + (size_t)(2 * l) * 128, bskC + (size_t)(2 * l + 1) * 128,
        agg_u, agg_t, XB);

    for (int r = 0; r < 3; ++r) {
      const int st = stt[r], dt = dtt[r];
      const int ns = cnt2[st], nd = cnt2[dt];
      const int mat = l * 3 + r;
      const bool qDeg = (l == 0 && dt == 1);   // ut l0: q over broadcast tweets
      const bool kDeg = (l == 0 && st == 1);   // tu l0: k,v over broadcast tweets
      const bool uniSM = kDeg;                 // uniform softmax shortcut

      const int nq_eff = (qDeg || uniSM) ? 1 : nd;
      const int nkv_eff = kDeg ? 1 : ns;

      u16 *qb_r = qb, *kb_r = kb, *vb_r = vb;
      if (FW) {  // tight packing: q = nq rows, k/v = nkv rows, 512 cols
        qb_r = arena;
        kb_r = qb_r + (size_t)nq_eff * HCC;
        vb_r = kb_r + (size_t)nkv_eff * HCC;
      }

      for (int h0 = 0; h0 < HH; h0 += HB) {
        GRel ga;
        ga.Xqb = xbs[dt]; ga.Xkvb = xbs[st];
        ga.Xqf = xs[dt];  ga.Xkvf = xs[st];
        ga.Wfam = Wtq + (size_t)mat * 3 * 512 * 128;
        ga.bfam = b_qkv + (size_t)mat * 3 * HCC;
        ga.oq = qb_r; ga.ok = kb_r; ga.ov = vb_r;
        ga.nq = nq_eff;
        ga.nkv = nkv_eff;
        ga.bq = (ga.nq + 127) / 128;
        ga.bkv = (ga.nkv + 127) / 128;
        ga.ldy = HB * DD; ga.col0 = h0 * DD;
        ga.usexb = XB;
        dim3 gg(ga.bq + 2 * ga.bkv, 1);
        if (HB == 4)      gemm_rel<16><<<gg, 256, 0, stream>>>(ga);
        else if (HB == 2) gemm_rel<8><<<gg, 256, 0, stream>>>(ga);
        else              gemm_rel<4><<<gg, 256, 0, stream>>>(ga);

        const int eblk = (nd + 3) / 4;
        if (uniSM) {
          if (HB == 4)      add_bcast<4><<<eblk, 256, 0, stream>>>(vb_r, rptrA[r], aggs[dt], nd);
          else if (HB == 2) add_bcast<2><<<eblk, 256, 0, stream>>>(vb_r, rptrA[r], aggs[dt], nd);
          else              add_bcast<1><<<eblk, 256, 0, stream>>>(vb_r, rptrA[r], aggs[dt], nd);
        } else {
          const int qs32 = qDeg ? 0 : HB * DD / 2;
          const int ks32 = HB * DD / 2;   // kDeg handled by uniSM branch
          if (HB == 4)
            edge_fused<4><<<eblk, 256, 0, stream>>>(qb_r, kb_r, vb_r, rptrA[r], csrcA[r], aggs[dt], nd, qs32, ks32);
          else if (HB == 2)
            edge_fused<2><<<eblk, 256, 0, stream>>>(qb_r, kb_r, vb_r, rptrA[r], csrcA[r], aggs[dt], nd, qs32, ks32);
          else
            edge_fused<1><<<eblk, 256, 0, stream>>>(qb_r, kb_r, vb_r, rptrA[r], csrcA[r], aggs[dt], nd, qs32, ks32);
        }
      }
    }
    ln2<<<(NUU + NTT + 3) / 4, 256, 0, stream>>>(agg_u, agg_t,
                                                 ln_g + (size_t)l * 2 * DD,
                                                 ln_b + (size_t)l * 2 * DD,
                                                 x_user, x_tweet,
                                                 xb_user, xb_tweet, XB && l == 0);
  }
}

// Round 10
// 1091.118 us; speedup vs baseline: 3.7975x; 1.0656x over previous
//
#include <hip/hip_runtime.h>
#include <hip/hip_bf16.h>
#include <math.h>

typedef unsigned short u16;
typedef unsigned int   u32;
typedef __attribute__((ext_vector_type(8))) short s8v;    // 8 x bf16
typedef __attribute__((ext_vector_type(8))) unsigned short u16x8;
typedef __attribute__((ext_vector_type(4))) float f4v;    // MFMA accumulator

#define NUU 50000
#define NTT 100000
#define EE  100000
#define DD  128
#define HH  4
#define HCC 512
#define BU  391
#define BT  782

// ---------- helpers ----------
__device__ __forceinline__ float bflo(u32 u) { return __uint_as_float(u << 16); }
__device__ __forceinline__ float bfhi(u32 u) { return __uint_as_float(u & 0xFFFF0000u); }
__device__ __forceinline__ u16 f2bf(float f) {
  u32 u = __float_as_uint(f);
  u32 r = (u + 0x7FFFu + ((u >> 16) & 1u)) >> 16;
  return (u16)r;
}
__device__ __forceinline__ s8v cvt_row8(const float* __restrict__ p) {
  float4 u = *(const float4*)p;
  float4 v = *(const float4*)(p + 4);
  s8v r;
  r[0] = (short)f2bf(u.x); r[1] = (short)f2bf(u.y);
  r[2] = (short)f2bf(u.z); r[3] = (short)f2bf(u.w);
  r[4] = (short)f2bf(v.x); r[5] = (short)f2bf(v.y);
  r[6] = (short)f2bf(v.z); r[7] = (short)f2bf(v.w);
  return r;
}
__device__ __forceinline__ int colperm(int c) {
  return (c & ~31) | (((c >> 2) & 3) << 3) | (((c >> 4) & 1) << 2) | (c & 3);
}

// ---------- init: x + bf16 mirrors + zero cnt ----------
__global__ __launch_bounds__(256) void init_x2(const float* __restrict__ emb,
                                               const float* __restrict__ tv,
                                               float* __restrict__ xu,
                                               float* __restrict__ xt,
                                               int* __restrict__ cz,
                                               u16* __restrict__ xbu,
                                               u16* __restrict__ xbt,
                                               int fu, int ft) {
  size_t idx = (size_t)blockIdx.x * 256 + threadIdx.x;
  const size_t nu = (size_t)NUU * DD;
  const size_t nt = (size_t)NTT * DD;
  if (idx < nu) {
    float v = emb[idx];
    xu[idx] = v;
    if (fu) xbu[idx] = f2bf(v);
  } else if (idx < nu + nt) {
    size_t j = idx - nu;
    float v = tv[j & (DD - 1)];
    xt[j] = v;
    if (ft) xbt[j] = f2bf(v);
  } else {
    size_t j = idx - (nu + nt);
    if (j < 300000) cz[j] = 0;
  }
}

// ---------- weights: Wv (6 mats) bf16 transposed+permuted; combined skip W; zeros ----------
__global__ __launch_bounds__(256) void conv_w(const float* __restrict__ Wq,
                                              const float* __restrict__ Wsk,
                                              const float* __restrict__ bsk,
                                              u16* __restrict__ Wtv,
                                              u16* __restrict__ WtsC,
                                              float* __restrict__ bskC,
                                              float* __restrict__ zeros) {
  int idx = blockIdx.x * 256 + threadIdx.x;
  if (idx < 6 * 512 * 128) {
    int k = idx & 127, cp = (idx >> 7) & 511, mat = idx >> 16;
    Wtv[idx] = f2bf(Wq[((size_t)(mat * 3 + 2) * 128 + k) * 512 + colperm(cp)]);
  }
  if (idx < 4 * 128 * 128) {
    int k = idx & 127, cp = (idx >> 7) & 127, m = idx >> 14;
    int l = m >> 1, isT = m & 1, col = colperm(cp);
    float v;
    if (isT) v = Wsk[((size_t)(l * 3 + 1) * 128 + k) * 128 + col];
    else     v = Wsk[((size_t)(l * 3 + 0) * 128 + k) * 128 + col]
               + Wsk[((size_t)(l * 3 + 2) * 128 + k) * 128 + col];
    WtsC[idx] = f2bf(v);
  }
  if (idx < 4 * 128) {
    int m = idx >> 7, c = idx & 127;
    int l = m >> 1, isT = m & 1;
    bskC[idx] = isT ? bsk[(size_t)(l * 3 + 1) * 128 + c]
                    : bsk[(size_t)(l * 3 + 0) * 128 + c] + bsk[(size_t)(l * 3 + 2) * 128 + c];
  }
  if (idx < 512) zeros[idx] = 0.f;
}

// ---------- M = Wq_h @ Wk_h^T (per rel,head) + U = Wk_h @ bq_h ----------
__global__ __launch_bounds__(256) void mk_m(const float* __restrict__ Wq_all,
                                            const float* __restrict__ bq_all,
                                            u16* __restrict__ Mwt,
                                            float* __restrict__ Uw) {
  int rel = blockIdx.x >> 2, h = blockIdx.x & 3;
  const float* Wq = Wq_all + (size_t)(rel * 3 + 0) * 128 * 512;
  const float* Wk = Wq_all + (size_t)(rel * 3 + 1) * 128 * 512;
  const float* bq = bq_all + (size_t)(rel * 3 + 0) * 512 + h * 128;
  __shared__ float Q[128][132];
  __shared__ float K[128][132];
  __shared__ float bqs[128];
  for (int idx = threadIdx.x; idx < 16384; idx += 256) {
    int a = idx >> 7, c = idx & 127;
    Q[a][c] = Wq[(size_t)a * 512 + h * 128 + c];
    K[a][c] = Wk[(size_t)a * 512 + h * 128 + c];
  }
  if (threadIdx.x < 128) bqs[threadIdx.x] = bq[threadIdx.x];
  __syncthreads();
  if (threadIdx.x < 128) {
    int d = threadIdx.x;
    float s = 0.f;
    for (int c = 0; c < 128; ++c) s += K[d][c] * bqs[c];
    Uw[((size_t)rel * 4 + h) * 128 + d] = s * 0.08838834764831845f;
  }
  for (int idx = threadIdx.x; idx < 16384; idx += 256) {
    int cp = idx >> 7, a = idx & 127;
    int d = colperm(cp) & 127;
    float s = 0.f;
    #pragma unroll 4
    for (int c = 0; c < 128; ++c) s += Q[a][c] * K[d][c];
    Mwt[((size_t)rel * 512 + h * 128 + cp) * 128 + a] = f2bf(s);
  }
}

// ---------- CSR build ----------
__global__ __launch_bounds__(256) void hist3(const int* e0, const int* e1, const int* e2,
                                             int* c0, int* c1, int* c2) {
  int idx = blockIdx.x * 256 + threadIdx.x;
  if (idx >= 3 * EE) return;
  int r = idx / EE, e = idx - r * EE;
  const int* edst = (r == 0 ? e0 : r == 1 ? e1 : e2) + EE;
  int* cnt = r == 0 ? c0 : r == 1 ? c1 : c2;
  atomicAdd(&cnt[edst[e]], 1);
}

__global__ __launch_bounds__(256) void bsum3(const int* c0, const int* c1, const int* c2,
                                             int* __restrict__ bsumA) {
  int b = blockIdx.x;
  int r, lb, n;
  if (b < 196)      { r = 0; lb = b;       n = NUU; }
  else if (b < 587) { r = 1; lb = b - 196; n = NTT; }
  else              { r = 2; lb = b - 587; n = NUU; }
  const int* cnt = r == 0 ? c0 : r == 1 ? c1 : c2;
  int i = lb * 256 + threadIdx.x;
  int v = (i < n) ? cnt[i] : 0;
  #pragma unroll
  for (int o = 1; o < 64; o <<= 1) v += __shfl_xor(v, o);
  __shared__ int ws4[4];
  if ((threadIdx.x & 63) == 0) ws4[threadIdx.x >> 6] = v;
  __syncthreads();
  if (threadIdx.x == 0) bsumA[r * 400 + lb] = ws4[0] + ws4[1] + ws4[2] + ws4[3];
}

__global__ __launch_bounds__(256) void bscan3(int* __restrict__ bsumA) {
  int r = blockIdx.x;
  int* bsum = bsumA + r * 400;
  const int nb = (r == 1) ? 391 : 196;
  __shared__ int sh[256];
  __shared__ int runs;
  if (threadIdx.x == 0) runs = 0;
  __syncthreads();
  for (int base = 0; base < nb; base += 256) {
    int i = base + threadIdx.x;
    int v = (i < nb) ? bsum[i] : 0;
    sh[threadIdx.x] = v;
    __syncthreads();
    for (int o = 1; o < 256; o <<= 1) {
      int t = (threadIdx.x >= o) ? sh[threadIdx.x - o] : 0;
      __syncthreads();
      sh[threadIdx.x] += t;
      __syncthreads();
    }
    int incl = sh[threadIdx.x];
    int r0 = runs;
    if (i < nb) bsum[i] = r0 + incl - v;
    __syncthreads();
    if (threadIdx.x == 0) runs = r0 + sh[255];
    __syncthreads();
  }
}

__global__ __launch_bounds__(256) void rptr3(int* c0, int* c1, int* c2,
                                             const int* __restrict__ bsumA,
                                             int* r0p, int* r1p, int* r2p) {
  int b = blockIdx.x;
  int r, lb, n;
  if (b < 196)      { r = 0; lb = b;       n = NUU; }
  else if (b < 587) { r = 1; lb = b - 196; n = NTT; }
  else              { r = 2; lb = b - 587; n = NUU; }
  int* cnt = r == 0 ? c0 : r == 1 ? c1 : c2;
  int* rptr = r == 0 ? r0p : r == 1 ? r1p : r2p;
  __shared__ int sh[256];
  int i = lb * 256 + threadIdx.x;
  int v = (i < n) ? cnt[i] : 0;
  sh[threadIdx.x] = v;
  __syncthreads();
  for (int o = 1; o < 256; o <<= 1) {
    int t = (threadIdx.x >= o) ? sh[threadIdx.x - o] : 0;
    __syncthreads();
    sh[threadIdx.x] += t;
    __syncthreads();
  }
  int excl = sh[threadIdx.x] - v + bsumA[r * 400 + lb];
  if (i < n) { rptr[i] = excl; cnt[i] = excl; }
  if (i == 0) rptr[n] = EE;
}

__global__ __launch_bounds__(256) void fill3(const int* e0, const int* e1, const int* e2,
                                             int* c0, int* c1, int* c2,
                                             int* s0, int* s1, int* s2) {
  int idx = blockIdx.x * 256 + threadIdx.x;
  if (idx >= 3 * EE) return;
  int r = idx / EE, e = idx - r * EE;
  const int* ebase = (r == 0 ? e0 : r == 1 ? e1 : e2);
  int* cursor = r == 0 ? c0 : r == 1 ? c1 : c2;
  int* csrc = r == 0 ? s0 : r == 1 ? s1 : s2;
  int pos = atomicAdd(&cursor[ebase[EE + e]], 1);
  csrc[pos] = ebase[e];
}

// ---------- c kernel: c[s][h] = scale * x_s . u_h ----------
__global__ __launch_bounds__(256) void c_kernel(const u16* __restrict__ xsb,
                                                const float* __restrict__ xsf,
                                                const float* __restrict__ u,
                                                float* __restrict__ cbuf,
                                                int ns, int XF) {
  int node = (int)(((size_t)blockIdx.x * 256 + threadIdx.x) >> 6);
  int lane = threadIdx.x & 63;
  if (node >= ns) return;
  float x0, x1;
  if (XF) {
    u32 xu = ((const u32*)xsb)[(size_t)node * 64 + lane];
    x0 = bflo(xu); x1 = bfhi(xu);
  } else {
    const float* xp = xsf + (size_t)node * 128 + 2 * lane;
    x0 = xp[0]; x1 = xp[1];
  }
  #pragma unroll
  for (int h = 0; h < 4; ++h) {
    float d = x0 * u[h * 128 + 2 * lane] + x1 * u[h * 128 + 2 * lane + 1];
    #pragma unroll
    for (int o = 1; o < 64; o <<= 1) d += __shfl_xor(d, o);
    if (lane == 0) cbuf[(size_t)node * 4 + h] = d;
  }
}

// ---------- per-relation q'/V GEMM (flat grid, ldy=512, PN=16) ----------
struct GRel2 {
  const u16* Xqb; const float* Xqf;
  const u16* Xvb; const float* Xvf;
  const u16* Wq; const u16* Wv;
  const float* bzq; const float* bzv;
  u16 *oq, *ov;
  int nq, nv, bq, bv, xbq, xbv;
};

__global__ __launch_bounds__(256) void gemm_rel2(GRel2 a) {
  const int bx = blockIdx.x;
  int lb, n, usexb; const u16* Xb; const float* Xf; const u16* Wt; const float* bias; u16* Y;
  if (bx < a.bq) { lb = bx; n = a.nq; Xb = a.Xqb; Xf = a.Xqf; Wt = a.Wq; bias = a.bzq; Y = a.oq; usexb = a.xbq; }
  else { lb = bx - a.bq; n = a.nv; Xb = a.Xvb; Xf = a.Xvf; Wt = a.Wv; bias = a.bzv; Y = a.ov; usexb = a.xbv; }
  const int bm = lb * 128;
  if (bm >= n) return;

  const int wid = threadIdx.x >> 6, lane = threadIdx.x & 63;
  const int l15 = lane & 15, l4 = lane >> 4;
  const int rbase = bm + wid * 32;
  int r0 = rbase + l15;      if (r0 >= n) r0 = n - 1;
  int r1 = rbase + 16 + l15; if (r1 >= n) r1 = n - 1;
  s8v a0[4], a1[4];
  if (usexb) {
    const u16* xb0 = Xb + (size_t)r0 * DD + l4 * 8;
    const u16* xb1 = Xb + (size_t)r1 * DD + l4 * 8;
    #pragma unroll
    for (int kk = 0; kk < 4; ++kk) {
      a0[kk] = *(const s8v*)(xb0 + kk * 32);
      a1[kk] = *(const s8v*)(xb1 + kk * 32);
    }
  } else {
    const float* xp0 = Xf + (size_t)r0 * DD + l4 * 8;
    const float* xp1 = Xf + (size_t)r1 * DD + l4 * 8;
    #pragma unroll
    for (int kk = 0; kk < 4; ++kk) {
      a0[kk] = cvt_row8(xp0 + kk * 32);
      a1[kk] = cvt_row8(xp1 + kk * 32);
    }
  }

  const u16* wp = Wt + (size_t)l15 * DD + l4 * 8;
  const bool ok0 = (rbase + l15 < n), ok1 = (rbase + 16 + l15 < n);
  u16* yp0 = Y + (size_t)(rbase + l15) * HCC + l4 * 8;
  u16* yp1 = Y + (size_t)(rbase + 16 + l15) * HCC + l4 * 8;

  s8v w0[8], w1[8];
  #pragma unroll
  for (int kk = 0; kk < 4; ++kk) {
    w0[kk]     = *(const s8v*)(wp + kk * 32);
    w0[4 + kk] = *(const s8v*)(wp + 16 * DD + kk * 32);
  }
  #pragma unroll
  for (int p = 0; p < 16; ++p) {
    const s8v* cw = (p & 1) ? w1 : w0;
    s8v* nw = (p & 1) ? w0 : w1;
    if (p + 1 < 16) {
      const u16* wq = wp + (size_t)(2 * (p + 1)) * 16 * DD;
      #pragma unroll
      for (int kk = 0; kk < 4; ++kk) {
        nw[kk]     = *(const s8v*)(wq + kk * 32);
        nw[4 + kk] = *(const s8v*)(wq + 16 * DD + kk * 32);
      }
    }
    f4v aE0 = {}, aE1 = {}, aO0 = {}, aO1 = {};
    #pragma unroll
    for (int kk = 0; kk < 4; ++kk) {
      aE0 = __builtin_amdgcn_mfma_f32_16x16x32_bf16(cw[kk], a0[kk], aE0, 0, 0, 0);
      aE1 = __builtin_amdgcn_mfma_f32_16x16x32_bf16(cw[kk], a1[kk], aE1, 0, 0, 0);
      aO0 = __builtin_amdgcn_mfma_f32_16x16x32_bf16(cw[4 + kk], a0[kk], aO0, 0, 0, 0);
      aO1 = __builtin_amdgcn_mfma_f32_16x16x32_bf16(cw[4 + kk], a1[kk], aO1, 0, 0, 0);
    }
    const float4 bbE = *(const float4*)(bias + p * 32 + l4 * 8);
    const float4 bbO = *(const float4*)(bias + p * 32 + l4 * 8 + 4);
    if (ok0) {
      u16x8 pk;
      pk[0] = f2bf(aE0[0] + bbE.x); pk[1] = f2bf(aE0[1] + bbE.y);
      pk[2] = f2bf(aE0[2] + bbE.z); pk[3] = f2bf(aE0[3] + bbE.w);
      pk[4] = f2bf(aO0[0] + bbO.x); pk[5] = f2bf(aO0[1] + bbO.y);
      pk[6] = f2bf(aO0[2] + bbO.z); pk[7] = f2bf(aO0[3] + bbO.w);
      *(u16x8*)(yp0 + p * 32) = pk;
    }
    if (ok1) {
      u16x8 pk;
      pk[0] = f2bf(aE1[0] + bbE.x); pk[1] = f2bf(aE1[1] + bbE.y);
      pk[2] = f2bf(aE1[2] + bbE.z); pk[3] = f2bf(aE1[3] + bbE.w);
      pk[4] = f2bf(aO1[0] + bbO.x); pk[5] = f2bf(aO1[1] + bbO.y);
      pk[6] = f2bf(aO1[2] + bbO.z); pk[7] = f2bf(aO1[3] + bbO.w);
      *(u16x8*)(yp1 + p * 32) = pk;
    }
  }
}

// ---------- skip GEMM (flat grid, STORE) ----------
__global__ __launch_bounds__(256) void gemm_skip3(const u16* xbu, const u16* xbt,
                                                  const float* xfu, const float* xft,
                                                  const u16* Wu, const u16* Wtw,
                                                  const float* bu, const float* btw,
                                                  float* aggu, float* aggt,
                                                  int fu, int ft) {
  const int bx = blockIdx.x;
  int job, lb;
  if (bx < BU) { job = 0; lb = bx; } else { job = 1; lb = bx - BU; }
  const int n = job ? NTT : NUU;
  const int bm = lb * 128;
  const u16* XB = job ? xbt : xbu;
  const float* XF = job ? xft : xfu;
  const u16* Wt = job ? Wtw : Wu;
  const float* bias = job ? btw : bu;
  float* out = job ? aggt : aggu;
  const int usexb = job ? ft : fu;

  const int wid = threadIdx.x >> 6, lane = threadIdx.x & 63;
  const int l15 = lane & 15, l4 = lane >> 4;
  const int rbase = bm + wid * 32;
  int r0 = rbase + l15;      if (r0 >= n) r0 = n - 1;
  int r1 = rbase + 16 + l15; if (r1 >= n) r1 = n - 1;
  s8v a0[4], a1[4];
  if (usexb) {
    const u16* xb0 = XB + (size_t)r0 * DD + l4 * 8;
    const u16* xb1 = XB + (size_t)r1 * DD + l4 * 8;
    #pragma unroll
    for (int kk = 0; kk < 4; ++kk) {
      a0[kk] = *(const s8v*)(xb0 + kk * 32);
      a1[kk] = *(const s8v*)(xb1 + kk * 32);
    }
  } else {
    const float* xp0 = XF + (size_t)r0 * DD + l4 * 8;
    const float* xp1 = XF + (size_t)r1 * DD + l4 * 8;
    #pragma unroll
    for (int kk = 0; kk < 4; ++kk) {
      a0[kk] = cvt_row8(xp0 + kk * 32);
      a1[kk] = cvt_row8(xp1 + kk * 32);
    }
  }

  const u16* wp = Wt + (size_t)l15 * DD + l4 * 8;
  const bool ok0 = (rbase + l15 < n), ok1 = (rbase + 16 + l15 < n);
  float* yp0 = out + (size_t)(rbase + l15) * DD + l4 * 8;
  float* yp1 = out + (size_t)(rbase + 16 + l15) * DD + l4 * 8;

  s8v w0[8], w1[8];
  #pragma unroll
  for (int kk = 0; kk < 4; ++kk) {
    w0[kk]     = *(const s8v*)(wp + kk * 32);
    w0[4 + kk] = *(const s8v*)(wp + 16 * DD + kk * 32);
  }
  #pragma unroll
  for (int p = 0; p < 4; ++p) {
    const s8v* cw = (p & 1) ? w1 : w0;
    s8v* nw = (p & 1) ? w0 : w1;
    if (p + 1 < 4) {
      const u16* wq = wp + (size_t)(2 * (p + 1)) * 16 * DD;
      #pragma unroll
      for (int kk = 0; kk < 4; ++kk) {
        nw[kk]     = *(const s8v*)(wq + kk * 32);
        nw[4 + kk] = *(const s8v*)(wq + 16 * DD + kk * 32);
      }
    }
    f4v aE0 = {}, aE1 = {}, aO0 = {}, aO1 = {};
    #pragma unroll
    for (int kk = 0; kk < 4; ++kk) {
      aE0 = __builtin_amdgcn_mfma_f32_16x16x32_bf16(cw[kk], a0[kk], aE0, 0, 0, 0);
      aE1 = __builtin_amdgcn_mfma_f32_16x16x32_bf16(cw[kk], a1[kk], aE1, 0, 0, 0);
      aO0 = __builtin_amdgcn_mfma_f32_16x16x32_bf16(cw[4 + kk], a0[kk], aO0, 0, 0, 0);
      aO1 = __builtin_amdgcn_mfma_f32_16x16x32_bf16(cw[4 + kk], a1[kk], aO1, 0, 0, 0);
    }
    const float4 bbE = *(const float4*)(bias + p * 32 + l4 * 8);
    const float4 bbO = *(const float4*)(bias + p * 32 + l4 * 8 + 4);
    if (ok0) {
      *(float4*)(yp0 + p * 32) = make_float4(aE0[0] + bbE.x, aE0[1] + bbE.y, aE0[2] + bbE.z, aE0[3] + bbE.w);
      *(float4*)(yp0 + p * 32 + 4) = make_float4(aO0[0] + bbO.x, aO0[1] + bbO.y, aO0[2] + bbO.z, aO0[3] + bbO.w);
    }
    if (ok1) {
      *(float4*)(yp1 + p * 32) = make_float4(aE1[0] + bbE.x, aE1[1] + bbE.y, aE1[2] + bbE.z, aE1[3] + bbE.w);
      *(float4*)(yp1 + p * 32 + 4) = make_float4(aO1[0] + bbO.x, aO1[1] + bbO.y, aO1[2] + bbO.z, aO1[3] + bbO.w);
    }
  }
}

// ---------- edge kernel: logits via q'.x_s + c(s); V gather; deg-1 fast path ----------
template<int XF>
__global__ __launch_bounds__(256) void edge_fused2(const u16* __restrict__ qp,
                                                   const u16* __restrict__ v,
                                                   const u16* __restrict__ xsb,
                                                   const float* __restrict__ xsf,
                                                   const float* __restrict__ cbuf,
                                                   const int* __restrict__ rptr,
                                                   const int* __restrict__ csrc,
                                                   float* __restrict__ agg,
                                                   int nd, int qs32) {
  int node = (int)(((size_t)blockIdx.x * 256 + threadIdx.x) >> 6);
  int lane = threadIdx.x & 63;
  if (node >= nd) return;
  int e0 = rptr[node], e1 = rptr[node + 1];
  if (e0 == e1) return;
  const int g = lane >> 4, i = lane & 15;
  float acc[8];

  if (e1 - e0 == 1) {
    int s = csrc[e0];
    const u32* vp = (const u32*)v + (size_t)s * 256 + lane * 4;
    #pragma unroll
    for (int j = 0; j < 4; ++j) { u32 u = vp[j]; acc[2 * j] = bflo(u); acc[2 * j + 1] = bfhi(u); }
  } else {
    u32 qv[4];
    {
      const u32* qq = (const u32*)qp + (size_t)node * qs32 + g * 64 + i * 4;
      #pragma unroll
      for (int j = 0; j < 4; ++j) qv[j] = qq[j];
    }
    float m = -1e30f, z = 0.f;
    #pragma unroll
    for (int j = 0; j < 8; ++j) acc[j] = 0.f;

    int s_cur = csrc[e0];
    u32 xc[4]; float xf[8];
    if (XF) {
      const u32* xp = (const u32*)xsb + (size_t)s_cur * 64 + i * 4;
      #pragma unroll
      for (int j = 0; j < 4; ++j) xc[j] = xp[j];
    } else {
      const float* xp = xsf + (size_t)s_cur * 128 + i * 8;
      #pragma unroll
      for (int j = 0; j < 8; ++j) xf[j] = xp[j];
    }

    for (int e = e0; e < e1; ++e) {
      // issue V(current), x(next), c(current) before the reduce/exp chain
      u32 vcur[4];
      {
        const u32* vp = (const u32*)v + (size_t)s_cur * 256 + lane * 4;
        #pragma unroll
        for (int j = 0; j < 4; ++j) vcur[j] = vp[j];
      }
      float cs = cbuf[(size_t)s_cur * 4 + g];
      const bool has = (e + 1 < e1);
      int s_nxt = csrc[has ? e + 1 : e0];
      u32 xn[4]; float xnf[8];
      if (XF) {
        const u32* xp = (const u32*)xsb + (size_t)s_nxt * 64 + i * 4;
        #pragma unroll
        for (int j = 0; j < 4; ++j) xn[j] = xp[j];
      } else {
        const float* xp = xsf + (size_t)s_nxt * 128 + i * 8;
        #pragma unroll
        for (int j = 0; j < 8; ++j) xnf[j] = xp[j];
      }

      float dot = 0.f;
      if (XF) {
        #pragma unroll
        for (int j = 0; j < 4; ++j)
          dot += bflo(qv[j]) * bflo(xc[j]) + bfhi(qv[j]) * bfhi(xc[j]);
      } else {
        #pragma unroll
        for (int j = 0; j < 4; ++j)
          dot += bflo(qv[j]) * xf[2 * j] + bfhi(qv[j]) * xf[2 * j + 1];
      }
      dot += __shfl_xor(dot, 1);
      dot += __shfl_xor(dot, 2);
      dot += __shfl_xor(dot, 4);
      dot += __shfl_xor(dot, 8);
      float lg = dot * 0.08838834764831845f + cs;
      float w;
      if (lg > m) {
        float sc = __expf(m - lg);
        z *= sc;
        #pragma unroll
        for (int j = 0; j < 8; ++j) acc[j] *= sc;
        m = lg; w = 1.f;
      } else {
        w = __expf(lg - m);
      }
      z += w;
      #pragma unroll
      for (int j = 0; j < 4; ++j) {
        acc[2 * j]     += w * bflo(vcur[j]);
        acc[2 * j + 1] += w * bfhi(vcur[j]);
      }
      if (has) {
        s_cur = s_nxt;
        if (XF) {
          #pragma unroll
          for (int j = 0; j < 4; ++j) xc[j] = xn[j];
        } else {
          #pragma unroll
          for (int j = 0; j < 8; ++j) xf[j] = xnf[j];
        }
      }
    }
    float iz = 1.f / z;
    #pragma unroll
    for (int j = 0; j < 8; ++j) acc[j] *= iz;
  }

  #pragma unroll
  for (int j = 0; j < 8; ++j) acc[j] *= 0.25f;
  #pragma unroll
  for (int o = 16; o < 64; o <<= 1) {
    #pragma unroll
    for (int j = 0; j < 8; ++j) acc[j] += __shfl_xor(acc[j], o);
  }
  if (lane < 16) {
    float* op = agg + (size_t)node * DD + lane * 8;
    #pragma unroll
    for (int j = 0; j < 8; ++j) op[j] += acc[j];
  }
}

// ---------- l0-tu shortcut: uniform softmax over broadcast K/V ----------
__global__ __launch_bounds__(256) void add_bcast4(const u16* __restrict__ v,
                                                  const int* __restrict__ rptr,
                                                  float* __restrict__ agg, int nd) {
  int node = (int)(((size_t)blockIdx.x * 256 + threadIdx.x) >> 6);
  int lane = threadIdx.x & 63;
  if (node >= nd) return;
  if (rptr[node + 1] <= rptr[node]) return;
  const u32* vp = (const u32*)v;   // row 0
  float a0 = 0.f, a1 = 0.f;
  #pragma unroll
  for (int h = 0; h < 4; ++h) {
    u32 u = vp[h * 64 + lane];
    a0 += bflo(u); a1 += bfhi(u);
  }
  float* op = agg + (size_t)node * DD + 2 * lane;
  op[0] += 0.25f * a0;
  op[1] += 0.25f * a1;
}

// ---------- LayerNorm + residual (+ bf16 mirror writes) ----------
__global__ __launch_bounds__(256) void ln2(const float* __restrict__ aggu,
                                           const float* __restrict__ aggt,
                                           const float* __restrict__ g2,
                                           const float* __restrict__ b2,
                                           float* __restrict__ xu,
                                           float* __restrict__ xt,
                                           u16* __restrict__ xbu,
                                           u16* __restrict__ xbt,
                                           int wbu, int wbt) {
  int wid = (int)(((size_t)blockIdx.x * 256 + threadIdx.x) >> 6);
  int lane = threadIdx.x & 63;
  if (wid >= NUU + NTT) return;
  const float* ap; float* xp; const float* g; const float* b; u16* xbp; int wb;
  if (wid < NUU) {
    ap = aggu + (size_t)wid * DD; xp = xu + (size_t)wid * DD;
    xbp = xbu ? xbu + (size_t)wid * DD : nullptr; g = g2; b = b2; wb = wbu;
  } else {
    int t = wid - NUU;
    ap = aggt + (size_t)t * DD; xp = xt + (size_t)t * DD;
    xbp = xbt ? xbt + (size_t)t * DD : nullptr; g = g2 + DD; b = b2 + DD; wb = wbt;
  }
  float v0 = ap[lane], v1 = ap[lane + 64];
  float s = v0 + v1;
  #pragma unroll
  for (int o = 1; o < 64; o <<= 1) s += __shfl_xor(s, o);
  float mean = s * (1.0f / DD);
  float d0 = v0 - mean, d1 = v1 - mean;
  float sq = d0 * d0 + d1 * d1;
  #pragma unroll
  for (int o = 1; o < 64; o <<= 1) sq += __shfl_xor(sq, o);
  float rstd = rsqrtf(sq * (1.0f / DD) + 1e-5f);
  float n0 = g[lane]      * d0 * rstd + b[lane]      + xp[lane];
  float n1 = g[lane + 64] * d1 * rstd + b[lane + 64] + xp[lane + 64];
  xp[lane] = n0;
  xp[lane + 64] = n1;
  if (wb) {
    xbp[lane] = f2bf(n0);
    xbp[lane + 64] = f2bf(n1);
  }
}

extern "C" void kernel_launch(void* const* d_in, const int* in_sizes, int n_in,
                              void* d_out, int out_size, void* d_ws, size_t ws_size,
                              hipStream_t stream) {
  const float* emb_user = (const float*)d_in[0];
  const float* tv_tweet = (const float*)d_in[1];
  const float* W_qkv  = (const float*)d_in[2];
  const float* b_qkv  = (const float*)d_in[3];
  const float* W_skip = (const float*)d_in[4];
  const float* b_skip = (const float*)d_in[5];
  const float* ln_g   = (const float*)d_in[6];
  const float* ln_b   = (const float*)d_in[7];
  const int* edges[3] = { (const int*)d_in[8], (const int*)d_in[9], (const int*)d_in[10] };

  float* x_user  = (float*)d_out;
  float* x_tweet = x_user + (size_t)NUU * DD;

  // ---- workspace layout ----
  const size_t fixed = 786432 + 131072 + 2048 + 786432 + 12288 + 2048 + 1600000
                     + 76800000 + (size_t)3 * 400032 + (size_t)3 * 400000 + 4800
                     + 153600000 + 4096;
  int XBU = 0, XBT = 0;
  if      (ws_size >= fixed + 38400000) { XBU = 1; XBT = 1; }
  else if (ws_size >= fixed + 25600000) { XBT = 1; }

  char* w = (char*)d_ws;
  u16* Wtv = (u16*)w;        w += 786432;
  u16* WtsC = (u16*)w;       w += 131072;
  float* bskC = (float*)w;   w += 2048;
  u16* Mwt = (u16*)w;        w += 786432;
  float* Uw = (float*)w;     w += 12288;
  float* zeros = (float*)w;  w += 2048;
  float* cbuf = (float*)w;   w += 1600000;
  float* agg_u = (float*)w;  w += (size_t)NUU * DD * 4;
  float* agg_t = (float*)w;  w += (size_t)NTT * DD * 4;
  int* rptrA[3]; int* csrcA[3];
  for (int r = 0; r < 3; ++r) { rptrA[r] = (int*)w; w += 400032; }
  for (int r = 0; r < 3; ++r) { csrcA[r] = (int*)w; w += 400000; }
  int* bsumA = (int*)w;      w += 4800;
  u16* xb_user = nullptr; u16* xb_tweet = nullptr;
  if (XBT) { xb_tweet = (u16*)w; w += (size_t)NTT * DD * 2; }
  if (XBU) { xb_user = (u16*)w;  w += (size_t)NUU * DD * 2; }
  u16* arena = (u16*)w;      // 153.6 MB; CSR cnt/cursor aliases its start
  int* cntA[3];
  cntA[0] = (int*)arena; cntA[1] = cntA[0] + 100000; cntA[2] = cntA[0] + 200000;

  init_x2<<<(19500000 + 255) / 256, 256, 0, stream>>>(emb_user, tv_tweet, x_user, x_tweet,
                                                      cntA[0], xb_user, xb_tweet, XBU, XBT);
  conv_w<<<(6 * 512 * 128 + 255) / 256, 256, 0, stream>>>(W_qkv, W_skip, b_skip,
                                                          Wtv, WtsC, bskC, zeros);
  mk_m<<<24, 256, 0, stream>>>(W_qkv, b_qkv, Mwt, Uw);

  hist3<<<(3 * EE + 255) / 256, 256, 0, stream>>>(edges[0], edges[1], edges[2],
                                                  cntA[0], cntA[1], cntA[2]);
  bsum3<<<783, 256, 0, stream>>>(cntA[0], cntA[1], cntA[2], bsumA);
  bscan3<<<3, 256, 0, stream>>>(bsumA);
  rptr3<<<783, 256, 0, stream>>>(cntA[0], cntA[1], cntA[2], bsumA, rptrA[0], rptrA[1], rptrA[2]);
  fill3<<<(3 * EE + 255) / 256, 256, 0, stream>>>(edges[0], edges[1], edges[2],
                                                  cntA[0], cntA[1], cntA[2],
                                                  csrcA[0], csrcA[1], csrcA[2]);

  const int stt[3] = {0, 0, 1}, dtt[3] = {0, 1, 0};
  const int cnt2[2] = {NUU, NTT};
  float* xs[2]   = {x_user, x_tweet};
  u16* xbs[2]    = {xb_user, xb_tweet};
  const int xbf[2] = {XBU, XBT};
  float* aggs[2] = {agg_u, agg_t};

  for (int l = 0; l < 2; ++l) {
    gemm_skip3<<<BU + BT, 256, 0, stream>>>(
        xb_user, xb_tweet, x_user, x_tweet,
        WtsC + (size_t)(2 * l) * 128 * 128, WtsC + (size_t)(2 * l + 1) * 128 * 128,
        bskC + (size_t)(2 * l) * 128, bskC + (size_t)(2 * l + 1) * 128,
        agg_u, agg_t, XBU, XBT);

    for (int r = 0; r < 3; ++r) {
      const int st = stt[r], dt = dtt[r];
      const int ns = cnt2[st], nd = cnt2[dt];
      const int rel = l * 3 + r;
      const bool qDeg = (l == 0 && dt == 1);   // ut-l0: broadcast dst
      const bool uniSM = (l == 0 && st == 1);  // tu-l0: broadcast src -> uniform softmax

      const int nq_eff = uniSM ? 0 : (qDeg ? 1 : nd);
      const int nv_eff = uniSM ? 1 : ns;
      u16* qb_r = arena;
      u16* vb_r = arena + (size_t)nq_eff * HCC;

      GRel2 ga;
      ga.Xqb = xbs[dt]; ga.Xqf = xs[dt]; ga.xbq = xbf[dt];
      ga.Xvb = xbs[st]; ga.Xvf = xs[st]; ga.xbv = xbf[st];
      ga.Wq = Mwt + (size_t)rel * 512 * 128;
      ga.Wv = Wtv + (size_t)rel * 512 * 128;
      ga.bzq = zeros;
      ga.bzv = b_qkv + (size_t)(rel * 3 + 2) * HCC;
      ga.oq = qb_r; ga.ov = vb_r;
      ga.nq = nq_eff; ga.nv = nv_eff;
      ga.bq = (nq_eff + 127) / 128; ga.bv = (nv_eff + 127) / 128;
      gemm_rel2<<<ga.bq + ga.bv, 256, 0, stream>>>(ga);

      const int eblk = (nd + 3) / 4;
      if (uniSM) {
        add_bcast4<<<eblk, 256, 0, stream>>>(vb_r, rptrA[r], aggs[dt], nd);
      } else {
        c_kernel<<<(ns + 3) / 4, 256, 0, stream>>>(xbs[st], xs[st], Uw + (size_t)rel * 512,
                                                   cbuf, ns, xbf[st]);
        const int qs32 = qDeg ? 0 : 256;
        if (xbf[st])
          edge_fused2<1><<<eblk, 256, 0, stream>>>(qb_r, vb_r, xbs[st], xs[st], cbuf,
                                                   rptrA[r], csrcA[r], aggs[dt], nd, qs32);
        else
          edge_fused2<0><<<eblk, 256, 0, stream>>>(qb_r, vb_r, xbs[st], xs[st], cbuf,
                                                   rptrA[r], csrcA[r], aggs[dt], nd, qs32);
      }
    }
    ln2<<<(NUU + NTT + 3) / 4, 256, 0, stream>>>(agg_u, agg_t,
                                                 ln_g + (size_t)l * 2 * DD,
                                                 ln_b + (size_t)l * 2 * DD,
                                                 x_user, x_tweet,
                                                 xb_user, xb_tweet,
                                                 XBU && l == 0, XBT && l == 0);
  }
}

// Round 11
// 996.087 us; speedup vs baseline: 4.1598x; 1.0954x over previous
//
#include <hip/hip_runtime.h>
#include <hip/hip_bf16.h>
#include <math.h>

typedef unsigned short u16;
typedef unsigned int   u32;
typedef __attribute__((ext_vector_type(8))) short s8v;    // 8 x bf16
typedef __attribute__((ext_vector_type(8))) unsigned short u16x8;
typedef __attribute__((ext_vector_type(4))) float f4v;    // MFMA accumulator

#define NUU 50000
#define NTT 100000
#define EE  100000
#define DD  128
#define HH  4
#define HCC 512
#define BU  391
#define BT  782

// ---------- helpers ----------
__device__ __forceinline__ float bflo(u32 u) { return __uint_as_float(u << 16); }
__device__ __forceinline__ float bfhi(u32 u) { return __uint_as_float(u & 0xFFFF0000u); }
__device__ __forceinline__ u16 f2bf(float f) {
  u32 u = __float_as_uint(f);
  u32 r = (u + 0x7FFFu + ((u >> 16) & 1u)) >> 16;
  return (u16)r;
}
__device__ __forceinline__ s8v cvt_row8(const float* __restrict__ p) {
  float4 u = *(const float4*)p;
  float4 v = *(const float4*)(p + 4);
  s8v r;
  r[0] = (short)f2bf(u.x); r[1] = (short)f2bf(u.y);
  r[2] = (short)f2bf(u.z); r[3] = (short)f2bf(u.w);
  r[4] = (short)f2bf(v.x); r[5] = (short)f2bf(v.y);
  r[6] = (short)f2bf(v.z); r[7] = (short)f2bf(v.w);
  return r;
}
__device__ __forceinline__ int colperm(int c) {
  return (c & ~31) | (((c >> 2) & 3) << 3) | (((c >> 4) & 1) << 2) | (c & 3);
}

// ---------- init: x + bf16 mirrors + zero cnt ----------
__global__ __launch_bounds__(256) void init_x2(const float* __restrict__ emb,
                                               const float* __restrict__ tv,
                                               float* __restrict__ xu,
                                               float* __restrict__ xt,
                                               int* __restrict__ cz,
                                               u16* __restrict__ xbu,
                                               u16* __restrict__ xbt,
                                               int fu, int ft) {
  size_t idx = (size_t)blockIdx.x * 256 + threadIdx.x;
  const size_t nu = (size_t)NUU * DD;
  const size_t nt = (size_t)NTT * DD;
  if (idx < nu) {
    float v = emb[idx];
    xu[idx] = v;
    if (fu) xbu[idx] = f2bf(v);
  } else if (idx < nu + nt) {
    size_t j = idx - nu;
    float v = tv[j & (DD - 1)];
    xt[j] = v;
    if (ft) xbt[j] = f2bf(v);
  } else {
    size_t j = idx - (nu + nt);
    if (j < 300000) cz[j] = 0;
  }
}

// ---------- weights: Wv (6 mats) bf16 transposed+permuted; combined skip W; zeros ----------
__global__ __launch_bounds__(256) void conv_w(const float* __restrict__ Wq,
                                              const float* __restrict__ Wsk,
                                              const float* __restrict__ bsk,
                                              u16* __restrict__ Wtv,
                                              u16* __restrict__ WtsC,
                                              float* __restrict__ bskC,
                                              float* __restrict__ zeros) {
  int idx = blockIdx.x * 256 + threadIdx.x;
  if (idx < 6 * 512 * 128) {
    int k = idx & 127, cp = (idx >> 7) & 511, mat = idx >> 16;
    Wtv[idx] = f2bf(Wq[((size_t)(mat * 3 + 2) * 128 + k) * 512 + colperm(cp)]);
  }
  if (idx < 4 * 128 * 128) {
    int k = idx & 127, cp = (idx >> 7) & 127, m = idx >> 14;
    int l = m >> 1, isT = m & 1, col = colperm(cp);
    float v;
    if (isT) v = Wsk[((size_t)(l * 3 + 1) * 128 + k) * 128 + col];
    else     v = Wsk[((size_t)(l * 3 + 0) * 128 + k) * 128 + col]
               + Wsk[((size_t)(l * 3 + 2) * 128 + k) * 128 + col];
    WtsC[idx] = f2bf(v);
  }
  if (idx < 4 * 128) {
    int m = idx >> 7, c = idx & 127;
    int l = m >> 1, isT = m & 1;
    bskC[idx] = isT ? bsk[(size_t)(l * 3 + 1) * 128 + c]
                    : bsk[(size_t)(l * 3 + 0) * 128 + c] + bsk[(size_t)(l * 3 + 2) * 128 + c];
  }
  if (idx < 512) zeros[idx] = 0.f;
}

// ---------- M = Wq_h @ Wk_h^T, parallel: grid (24, 8), 16 cp-rows per block ----------
// Bit-identical to the old serial version: per-output f32 accumulate over c = 0..127.
__global__ __launch_bounds__(256) void mk_m2(const float* __restrict__ Wq_all,
                                             const float* __restrict__ bq_all,
                                             u16* __restrict__ Mwt,
                                             float* __restrict__ Uw) {
  const int rel = blockIdx.x >> 2, h = blockIdx.x & 3;
  const int cpB = blockIdx.y;                 // 16 cp rows per block
  const float* Wq = Wq_all + (size_t)(rel * 3 + 0) * 128 * 512 + h * 128;
  const float* Wk = Wq_all + (size_t)(rel * 3 + 1) * 128 * 512 + h * 128;
  const float* bq = bq_all + (size_t)(rel * 3 + 0) * 512 + h * 128;

  __shared__ float Qs[128][129];
  __shared__ float Ks[16][129];
  for (int idx = threadIdx.x; idx < 16384; idx += 256) {
    int a = idx >> 7, c = idx & 127;
    Qs[a][c] = Wq[(size_t)a * 512 + c];
  }
  for (int idx = threadIdx.x; idx < 2048; idx += 256) {
    int row = idx >> 7, c = idx & 127;
    int d = colperm(cpB * 16 + row) & 127;
    Ks[row][c] = Wk[(size_t)d * 512 + c];
  }
  __syncthreads();

  const int a = threadIdx.x & 127;
  const int rsel = threadIdx.x >> 7;          // 0 or 1 -> cp_local 0..7 or 8..15
  float acc[8] = {};
  for (int c = 0; c < 128; ++c) {
    float qa = Qs[a][c];
    #pragma unroll
    for (int j = 0; j < 8; ++j) acc[j] = fmaf(qa, Ks[rsel * 8 + j][c], acc[j]);
  }
  u16* mp = Mwt + ((size_t)rel * 512 + h * 128 + cpB * 16 + rsel * 8) * 128 + a;
  #pragma unroll
  for (int j = 0; j < 8; ++j) mp[(size_t)j * 128] = f2bf(acc[j]);

  // U = scale * (Wk_h @ bq_h): computed once, in the cpB==0 blocks
  if (cpB == 0 && threadIdx.x < 128) {
    int d = threadIdx.x;
    float s = 0.f;
    for (int c = 0; c < 128; ++c) s = fmaf(Wk[(size_t)d * 512 + c], bq[c], s);
    Uw[((size_t)rel * 4 + h) * 128 + d] = s * 0.08838834764831845f;
  }
}

// ---------- CSR build ----------
__global__ __launch_bounds__(256) void hist3(const int* e0, const int* e1, const int* e2,
                                             int* c0, int* c1, int* c2) {
  int idx = blockIdx.x * 256 + threadIdx.x;
  if (idx >= 3 * EE) return;
  int r = idx / EE, e = idx - r * EE;
  const int* edst = (r == 0 ? e0 : r == 1 ? e1 : e2) + EE;
  int* cnt = r == 0 ? c0 : r == 1 ? c1 : c2;
  atomicAdd(&cnt[edst[e]], 1);
}

__global__ __launch_bounds__(256) void bsum3(const int* c0, const int* c1, const int* c2,
                                             int* __restrict__ bsumA) {
  int b = blockIdx.x;
  int r, lb, n;
  if (b < 196)      { r = 0; lb = b;       n = NUU; }
  else if (b < 587) { r = 1; lb = b - 196; n = NTT; }
  else              { r = 2; lb = b - 587; n = NUU; }
  const int* cnt = r == 0 ? c0 : r == 1 ? c1 : c2;
  int i = lb * 256 + threadIdx.x;
  int v = (i < n) ? cnt[i] : 0;
  #pragma unroll
  for (int o = 1; o < 64; o <<= 1) v += __shfl_xor(v, o);
  __shared__ int ws4[4];
  if ((threadIdx.x & 63) == 0) ws4[threadIdx.x >> 6] = v;
  __syncthreads();
  if (threadIdx.x == 0) bsumA[r * 400 + lb] = ws4[0] + ws4[1] + ws4[2] + ws4[3];
}

__global__ __launch_bounds__(256) void bscan3(int* __restrict__ bsumA) {
  int r = blockIdx.x;
  int* bsum = bsumA + r * 400;
  const int nb = (r == 1) ? 391 : 196;
  __shared__ int sh[256];
  __shared__ int runs;
  if (threadIdx.x == 0) runs = 0;
  __syncthreads();
  for (int base = 0; base < nb; base += 256) {
    int i = base + threadIdx.x;
    int v = (i < nb) ? bsum[i] : 0;
    sh[threadIdx.x] = v;
    __syncthreads();
    for (int o = 1; o < 256; o <<= 1) {
      int t = (threadIdx.x >= o) ? sh[threadIdx.x - o] : 0;
      __syncthreads();
      sh[threadIdx.x] += t;
      __syncthreads();
    }
    int incl = sh[threadIdx.x];
    int r0 = runs;
    if (i < nb) bsum[i] = r0 + incl - v;
    __syncthreads();
    if (threadIdx.x == 0) runs = r0 + sh[255];
    __syncthreads();
  }
}

__global__ __launch_bounds__(256) void rptr3(int* c0, int* c1, int* c2,
                                             const int* __restrict__ bsumA,
                                             int* r0p, int* r1p, int* r2p) {
  int b = blockIdx.x;
  int r, lb, n;
  if (b < 196)      { r = 0; lb = b;       n = NUU; }
  else if (b < 587) { r = 1; lb = b - 196; n = NTT; }
  else              { r = 2; lb = b - 587; n = NUU; }
  int* cnt = r == 0 ? c0 : r == 1 ? c1 : c2;
  int* rptr = r == 0 ? r0p : r == 1 ? r1p : r2p;
  __shared__ int sh[256];
  int i = lb * 256 + threadIdx.x;
  int v = (i < n) ? cnt[i] : 0;
  sh[threadIdx.x] = v;
  __syncthreads();
  for (int o = 1; o < 256; o <<= 1) {
    int t = (threadIdx.x >= o) ? sh[threadIdx.x - o] : 0;
    __syncthreads();
    sh[threadIdx.x] += t;
    __syncthreads();
  }
  int excl = sh[threadIdx.x] - v + bsumA[r * 400 + lb];
  if (i < n) { rptr[i] = excl; cnt[i] = excl; }
  if (i == 0) rptr[n] = EE;
}

__global__ __launch_bounds__(256) void fill3(const int* e0, const int* e1, const int* e2,
                                             int* c0, int* c1, int* c2,
                                             int* s0, int* s1, int* s2) {
  int idx = blockIdx.x * 256 + threadIdx.x;
  if (idx >= 3 * EE) return;
  int r = idx / EE, e = idx - r * EE;
  const int* ebase = (r == 0 ? e0 : r == 1 ? e1 : e2);
  int* cursor = r == 0 ? c0 : r == 1 ? c1 : c2;
  int* csrc = r == 0 ? s0 : r == 1 ? s1 : s2;
  int pos = atomicAdd(&cursor[ebase[EE + e]], 1);
  csrc[pos] = ebase[e];
}

// ---------- c kernel: c[s][h] = scale * x_s . u_h ----------
__global__ __launch_bounds__(256) void c_kernel(const u16* __restrict__ xsb,
                                                const float* __restrict__ xsf,
                                                const float* __restrict__ u,
                                                float* __restrict__ cbuf,
                                                int ns, int XF) {
  int node = (int)(((size_t)blockIdx.x * 256 + threadIdx.x) >> 6);
  int lane = threadIdx.x & 63;
  if (node >= ns) return;
  float x0, x1;
  if (XF) {
    u32 xu = ((const u32*)xsb)[(size_t)node * 64 + lane];
    x0 = bflo(xu); x1 = bfhi(xu);
  } else {
    const float* xp = xsf + (size_t)node * 128 + 2 * lane;
    x0 = xp[0]; x1 = xp[1];
  }
  #pragma unroll
  for (int h = 0; h < 4; ++h) {
    float d = x0 * u[h * 128 + 2 * lane] + x1 * u[h * 128 + 2 * lane + 1];
    #pragma unroll
    for (int o = 1; o < 64; o <<= 1) d += __shfl_xor(d, o);
    if (lane == 0) cbuf[(size_t)node * 4 + h] = d;
  }
}

// ---------- per-relation q'/V GEMM (flat grid, ldy=512, PN=16) ----------
struct GRel2 {
  const u16* Xqb; const float* Xqf;
  const u16* Xvb; const float* Xvf;
  const u16* Wq; const u16* Wv;
  const float* bzq; const float* bzv;
  u16 *oq, *ov;
  int nq, nv, bq, bv, xbq, xbv;
};

__global__ __launch_bounds__(256) void gemm_rel2(GRel2 a) {
  const int bx = blockIdx.x;
  int lb, n, usexb; const u16* Xb; const float* Xf; const u16* Wt; const float* bias; u16* Y;
  if (bx < a.bq) { lb = bx; n = a.nq; Xb = a.Xqb; Xf = a.Xqf; Wt = a.Wq; bias = a.bzq; Y = a.oq; usexb = a.xbq; }
  else { lb = bx - a.bq; n = a.nv; Xb = a.Xvb; Xf = a.Xvf; Wt = a.Wv; bias = a.bzv; Y = a.ov; usexb = a.xbv; }
  const int bm = lb * 128;
  if (bm >= n) return;

  const int wid = threadIdx.x >> 6, lane = threadIdx.x & 63;
  const int l15 = lane & 15, l4 = lane >> 4;
  const int rbase = bm + wid * 32;
  int r0 = rbase + l15;      if (r0 >= n) r0 = n - 1;
  int r1 = rbase + 16 + l15; if (r1 >= n) r1 = n - 1;
  s8v a0[4], a1[4];
  if (usexb) {
    const u16* xb0 = Xb + (size_t)r0 * DD + l4 * 8;
    const u16* xb1 = Xb + (size_t)r1 * DD + l4 * 8;
    #pragma unroll
    for (int kk = 0; kk < 4; ++kk) {
      a0[kk] = *(const s8v*)(xb0 + kk * 32);
      a1[kk] = *(const s8v*)(xb1 + kk * 32);
    }
  } else {
    const float* xp0 = Xf + (size_t)r0 * DD + l4 * 8;
    const float* xp1 = Xf + (size_t)r1 * DD + l4 * 8;
    #pragma unroll
    for (int kk = 0; kk < 4; ++kk) {
      a0[kk] = cvt_row8(xp0 + kk * 32);
      a1[kk] = cvt_row8(xp1 + kk * 32);
    }
  }

  const u16* wp = Wt + (size_t)l15 * DD + l4 * 8;
  const bool ok0 = (rbase + l15 < n), ok1 = (rbase + 16 + l15 < n);
  u16* yp0 = Y + (size_t)(rbase + l15) * HCC + l4 * 8;
  u16* yp1 = Y + (size_t)(rbase + 16 + l15) * HCC + l4 * 8;

  s8v w0[8], w1[8];
  #pragma unroll
  for (int kk = 0; kk < 4; ++kk) {
    w0[kk]     = *(const s8v*)(wp + kk * 32);
    w0[4 + kk] = *(const s8v*)(wp + 16 * DD + kk * 32);
  }
  #pragma unroll
  for (int p = 0; p < 16; ++p) {
    const s8v* cw = (p & 1) ? w1 : w0;
    s8v* nw = (p & 1) ? w0 : w1;
    if (p + 1 < 16) {
      const u16* wq = wp + (size_t)(2 * (p + 1)) * 16 * DD;
      #pragma unroll
      for (int kk = 0; kk < 4; ++kk) {
        nw[kk]     = *(const s8v*)(wq + kk * 32);
        nw[4 + kk] = *(const s8v*)(wq + 16 * DD + kk * 32);
      }
    }
    f4v aE0 = {}, aE1 = {}, aO0 = {}, aO1 = {};
    #pragma unroll
    for (int kk = 0; kk < 4; ++kk) {
      aE0 = __builtin_amdgcn_mfma_f32_16x16x32_bf16(cw[kk], a0[kk], aE0, 0, 0, 0);
      aE1 = __builtin_amdgcn_mfma_f32_16x16x32_bf16(cw[kk], a1[kk], aE1, 0, 0, 0);
      aO0 = __builtin_amdgcn_mfma_f32_16x16x32_bf16(cw[4 + kk], a0[kk], aO0, 0, 0, 0);
      aO1 = __builtin_amdgcn_mfma_f32_16x16x32_bf16(cw[4 + kk], a1[kk], aO1, 0, 0, 0);
    }
    const float4 bbE = *(const float4*)(bias + p * 32 + l4 * 8);
    const float4 bbO = *(const float4*)(bias + p * 32 + l4 * 8 + 4);
    if (ok0) {
      u16x8 pk;
      pk[0] = f2bf(aE0[0] + bbE.x); pk[1] = f2bf(aE0[1] + bbE.y);
      pk[2] = f2bf(aE0[2] + bbE.z); pk[3] = f2bf(aE0[3] + bbE.w);
      pk[4] = f2bf(aO0[0] + bbO.x); pk[5] = f2bf(aO0[1] + bbO.y);
      pk[6] = f2bf(aO0[2] + bbO.z); pk[7] = f2bf(aO0[3] + bbO.w);
      *(u16x8*)(yp0 + p * 32) = pk;
    }
    if (ok1) {
      u16x8 pk;
      pk[0] = f2bf(aE1[0] + bbE.x); pk[1] = f2bf(aE1[1] + bbE.y);
      pk[2] = f2bf(aE1[2] + bbE.z); pk[3] = f2bf(aE1[3] + bbE.w);
      pk[4] = f2bf(aO1[0] + bbO.x); pk[5] = f2bf(aO1[1] + bbO.y);
      pk[6] = f2bf(aO1[2] + bbO.z); pk[7] = f2bf(aO1[3] + bbO.w);
      *(u16x8*)(yp1 + p * 32) = pk;
    }
  }
}

// ---------- skip GEMM (flat grid, STORE) ----------
__global__ __launch_bounds__(256) void gemm_skip3(const u16* xbu, const u16* xbt,
                                                  const float* xfu, const float* xft,
                                                  const u16* Wu, const u16* Wtw,
                                                  const float* bu, const float* btw,
                                                  float* aggu, float* aggt,
                                                  int fu, int ft) {
  const int bx = blockIdx.x;
  int job, lb;
  if (bx < BU) { job = 0; lb = bx; } else { job = 1; lb = bx - BU; }
  const int n = job ? NTT : NUU;
  const int bm = lb * 128;
  const u16* XB = job ? xbt : xbu;
  const float* XF = job ? xft : xfu;
  const u16* Wt = job ? Wtw : Wu;
  const float* bias = job ? btw : bu;
  float* out = job ? aggt : aggu;
  const int usexb = job ? ft : fu;

  const int wid = threadIdx.x >> 6, lane = threadIdx.x & 63;
  const int l15 = lane & 15, l4 = lane >> 4;
  const int rbase = bm + wid * 32;
  int r0 = rbase + l15;      if (r0 >= n) r0 = n - 1;
  int r1 = rbase + 16 + l15; if (r1 >= n) r1 = n - 1;
  s8v a0[4], a1[4];
  if (usexb) {
    const u16* xb0 = XB + (size_t)r0 * DD + l4 * 8;
    const u16* xb1 = XB + (size_t)r1 * DD + l4 * 8;
    #pragma unroll
    for (int kk = 0; kk < 4; ++kk) {
      a0[kk] = *(const s8v*)(xb0 + kk * 32);
      a1[kk] = *(const s8v*)(xb1 + kk * 32);
    }
  } else {
    const float* xp0 = XF + (size_t)r0 * DD + l4 * 8;
    const float* xp1 = XF + (size_t)r1 * DD + l4 * 8;
    #pragma unroll
    for (int kk = 0; kk < 4; ++kk) {
      a0[kk] = cvt_row8(xp0 + kk * 32);
      a1[kk] = cvt_row8(xp1 + kk * 32);
    }
  }

  const u16* wp = Wt + (size_t)l15 * DD + l4 * 8;
  const bool ok0 = (rbase + l15 < n), ok1 = (rbase + 16 + l15 < n);
  float* yp0 = out + (size_t)(rbase + l15) * DD + l4 * 8;
  float* yp1 = out + (size_t)(rbase + 16 + l15) * DD + l4 * 8;

  s8v w0[8], w1[8];
  #pragma unroll
  for (int kk = 0; kk < 4; ++kk) {
    w0[kk]     = *(const s8v*)(wp + kk * 32);
    w0[4 + kk] = *(const s8v*)(wp + 16 * DD + kk * 32);
  }
  #pragma unroll
  for (int p = 0; p < 4; ++p) {
    const s8v* cw = (p & 1) ? w1 : w0;
    s8v* nw = (p & 1) ? w0 : w1;
    if (p + 1 < 4) {
      const u16* wq = wp + (size_t)(2 * (p + 1)) * 16 * DD;
      #pragma unroll
      for (int kk = 0; kk < 4; ++kk) {
        nw[kk]     = *(const s8v*)(wq + kk * 32);
        nw[4 + kk] = *(const s8v*)(wq + 16 * DD + kk * 32);
      }
    }
    f4v aE0 = {}, aE1 = {}, aO0 = {}, aO1 = {};
    #pragma unroll
    for (int kk = 0; kk < 4; ++kk) {
      aE0 = __builtin_amdgcn_mfma_f32_16x16x32_bf16(cw[kk], a0[kk], aE0, 0, 0, 0);
      aE1 = __builtin_amdgcn_mfma_f32_16x16x32_bf16(cw[kk], a1[kk], aE1, 0, 0, 0);
      aO0 = __builtin_amdgcn_mfma_f32_16x16x32_bf16(cw[4 + kk], a0[kk], aO0, 0, 0, 0);
      aO1 = __builtin_amdgcn_mfma_f32_16x16x32_bf16(cw[4 + kk], a1[kk], aO1, 0, 0, 0);
    }
    const float4 bbE = *(const float4*)(bias + p * 32 + l4 * 8);
    const float4 bbO = *(const float4*)(bias + p * 32 + l4 * 8 + 4);
    if (ok0) {
      *(float4*)(yp0 + p * 32) = make_float4(aE0[0] + bbE.x, aE0[1] + bbE.y, aE0[2] + bbE.z, aE0[3] + bbE.w);
      *(float4*)(yp0 + p * 32 + 4) = make_float4(aO0[0] + bbO.x, aO0[1] + bbO.y, aO0[2] + bbO.z, aO0[3] + bbO.w);
    }
    if (ok1) {
      *(float4*)(yp1 + p * 32) = make_float4(aE1[0] + bbE.x, aE1[1] + bbE.y, aE1[2] + bbE.z, aE1[3] + bbE.w);
      *(float4*)(yp1 + p * 32 + 4) = make_float4(aO1[0] + bbO.x, aO1[1] + bbO.y, aO1[2] + bbO.z, aO1[3] + bbO.w);
    }
  }
}

// ---------- edge kernel: logits via q'.x_s + c(s); V gather; deg-1 fast path ----------
template<int XF>
__global__ __launch_bounds__(256) void edge_fused2(const u16* __restrict__ qp,
                                                   const u16* __restrict__ v,
                                                   const u16* __restrict__ xsb,
                                                   const float* __restrict__ xsf,
                                                   const float* __restrict__ cbuf,
                                                   const int* __restrict__ rptr,
                                                   const int* __restrict__ csrc,
                                                   float* __restrict__ agg,
                                                   int nd, int qs32) {
  int node = (int)(((size_t)blockIdx.x * 256 + threadIdx.x) >> 6);
  int lane = threadIdx.x & 63;
  if (node >= nd) return;
  int e0 = rptr[node], e1 = rptr[node + 1];
  if (e0 == e1) return;
  const int g = lane >> 4, i = lane & 15;
  float acc[8];

  if (e1 - e0 == 1) {
    int s = csrc[e0];
    const u32* vp = (const u32*)v + (size_t)s * 256 + lane * 4;
    #pragma unroll
    for (int j = 0; j < 4; ++j) { u32 u = vp[j]; acc[2 * j] = bflo(u); acc[2 * j + 1] = bfhi(u); }
  } else {
    u32 qv[4];
    {
      const u32* qq = (const u32*)qp + (size_t)node * qs32 + g * 64 + i * 4;
      #pragma unroll
      for (int j = 0; j < 4; ++j) qv[j] = qq[j];
    }
    float m = -1e30f, z = 0.f;
    #pragma unroll
    for (int j = 0; j < 8; ++j) acc[j] = 0.f;

    int s_cur = csrc[e0];
    u32 xc[4]; float xf[8];
    if (XF) {
      const u32* xp = (const u32*)xsb + (size_t)s_cur * 64 + i * 4;
      #pragma unroll
      for (int j = 0; j < 4; ++j) xc[j] = xp[j];
    } else {
      const float* xp = xsf + (size_t)s_cur * 128 + i * 8;
      #pragma unroll
      for (int j = 0; j < 8; ++j) xf[j] = xp[j];
    }

    for (int e = e0; e < e1; ++e) {
      u32 vcur[4];
      {
        const u32* vp = (const u32*)v + (size_t)s_cur * 256 + lane * 4;
        #pragma unroll
        for (int j = 0; j < 4; ++j) vcur[j] = vp[j];
      }
      float cs = cbuf[(size_t)s_cur * 4 + g];
      const bool has = (e + 1 < e1);
      int s_nxt = csrc[has ? e + 1 : e0];
      u32 xn[4]; float xnf[8];
      if (XF) {
        const u32* xp = (const u32*)xsb + (size_t)s_nxt * 64 + i * 4;
        #pragma unroll
        for (int j = 0; j < 4; ++j) xn[j] = xp[j];
      } else {
        const float* xp = xsf + (size_t)s_nxt * 128 + i * 8;
        #pragma unroll
        for (int j = 0; j < 8; ++j) xnf[j] = xp[j];
      }

      float dot = 0.f;
      if (XF) {
        #pragma unroll
        for (int j = 0; j < 4; ++j)
          dot += bflo(qv[j]) * bflo(xc[j]) + bfhi(qv[j]) * bfhi(xc[j]);
      } else {
        #pragma unroll
        for (int j = 0; j < 4; ++j)
          dot += bflo(qv[j]) * xf[2 * j] + bfhi(qv[j]) * xf[2 * j + 1];
      }
      dot += __shfl_xor(dot, 1);
      dot += __shfl_xor(dot, 2);
      dot += __shfl_xor(dot, 4);
      dot += __shfl_xor(dot, 8);
      float lg = dot * 0.08838834764831845f + cs;
      float w;
      if (lg > m) {
        float sc = __expf(m - lg);
        z *= sc;
        #pragma unroll
        for (int j = 0; j < 8; ++j) acc[j] *= sc;
        m = lg; w = 1.f;
      } else {
        w = __expf(lg - m);
      }
      z += w;
      #pragma unroll
      for (int j = 0; j < 4; ++j) {
        acc[2 * j]     += w * bflo(vcur[j]);
        acc[2 * j + 1] += w * bfhi(vcur[j]);
      }
      if (has) {
        s_cur = s_nxt;
        if (XF) {
          #pragma unroll
          for (int j = 0; j < 4; ++j) xc[j] = xn[j];
        } else {
          #pragma unroll
          for (int j = 0; j < 8; ++j) xf[j] = xnf[j];
        }
      }
    }
    float iz = 1.f / z;
    #pragma unroll
    for (int j = 0; j < 8; ++j) acc[j] *= iz;
  }

  #pragma unroll
  for (int j = 0; j < 8; ++j) acc[j] *= 0.25f;
  #pragma unroll
  for (int o = 16; o < 64; o <<= 1) {
    #pragma unroll
    for (int j = 0; j < 8; ++j) acc[j] += __shfl_xor(acc[j], o);
  }
  if (lane < 16) {
    float* op = agg + (size_t)node * DD + lane * 8;
    #pragma unroll
    for (int j = 0; j < 8; ++j) op[j] += acc[j];
  }
}

// ---------- l0-tu shortcut: uniform softmax over broadcast K/V ----------
__global__ __launch_bounds__(256) void add_bcast4(const u16* __restrict__ v,
                                                  const int* __restrict__ rptr,
                                                  float* __restrict__ agg, int nd) {
  int node = (int)(((size_t)blockIdx.x * 256 + threadIdx.x) >> 6);
  int lane = threadIdx.x & 63;
  if (node >= nd) return;
  if (rptr[node + 1] <= rptr[node]) return;
  const u32* vp = (const u32*)v;   // row 0
  float a0 = 0.f, a1 = 0.f;
  #pragma unroll
  for (int h = 0; h < 4; ++h) {
    u32 u = vp[h * 64 + lane];
    a0 += bflo(u); a1 += bfhi(u);
  }
  float* op = agg + (size_t)node * DD + 2 * lane;
  op[0] += 0.25f * a0;
  op[1] += 0.25f * a1;
}

// ---------- LayerNorm + residual (+ bf16 mirror writes) ----------
__global__ __launch_bounds__(256) void ln2(const float* __restrict__ aggu,
                                           const float* __restrict__ aggt,
                                           const float* __restrict__ g2,
                                           const float* __restrict__ b2,
                                           float* __restrict__ xu,
                                           float* __restrict__ xt,
                                           u16* __restrict__ xbu,
                                           u16* __restrict__ xbt,
                                           int wbu, int wbt) {
  int wid = (int)(((size_t)blockIdx.x * 256 + threadIdx.x) >> 6);
  int lane = threadIdx.x & 63;
  if (wid >= NUU + NTT) return;
  const float* ap; float* xp; const float* g; const float* b; u16* xbp; int wb;
  if (wid < NUU) {
    ap = aggu + (size_t)wid * DD; xp = xu + (size_t)wid * DD;
    xbp = xbu ? xbu + (size_t)wid * DD : nullptr; g = g2; b = b2; wb = wbu;
  } else {
    int t = wid - NUU;
    ap = aggt + (size_t)t * DD; xp = xt + (size_t)t * DD;
    xbp = xbt ? xbt + (size_t)t * DD : nullptr; g = g2 + DD; b = b2 + DD; wb = wbt;
  }
  float v0 = ap[lane], v1 = ap[lane + 64];
  float s = v0 + v1;
  #pragma unroll
  for (int o = 1; o < 64; o <<= 1) s += __shfl_xor(s, o);
  float mean = s * (1.0f / DD);
  float d0 = v0 - mean, d1 = v1 - mean;
  float sq = d0 * d0 + d1 * d1;
  #pragma unroll
  for (int o = 1; o < 64; o <<= 1) sq += __shfl_xor(sq, o);
  float rstd = rsqrtf(sq * (1.0f / DD) + 1e-5f);
  float n0 = g[lane]      * d0 * rstd + b[lane]      + xp[lane];
  float n1 = g[lane + 64] * d1 * rstd + b[lane + 64] + xp[lane + 64];
  xp[lane] = n0;
  xp[lane + 64] = n1;
  if (wb) {
    xbp[lane] = f2bf(n0);
    xbp[lane + 64] = f2bf(n1);
  }
}

extern "C" void kernel_launch(void* const* d_in, const int* in_sizes, int n_in,
                              void* d_out, int out_size, void* d_ws, size_t ws_size,
                              hipStream_t stream) {
  const float* emb_user = (const float*)d_in[0];
  const float* tv_tweet = (const float*)d_in[1];
  const float* W_qkv  = (const float*)d_in[2];
  const float* b_qkv  = (const float*)d_in[3];
  const float* W_skip = (const float*)d_in[4];
  const float* b_skip = (const float*)d_in[5];
  const float* ln_g   = (const float*)d_in[6];
  const float* ln_b   = (const float*)d_in[7];
  const int* edges[3] = { (const int*)d_in[8], (const int*)d_in[9], (const int*)d_in[10] };

  float* x_user  = (float*)d_out;
  float* x_tweet = x_user + (size_t)NUU * DD;

  // ---- workspace layout ----
  const size_t fixed = 786432 + 131072 + 2048 + 786432 + 12288 + 2048 + 1600000
                     + 76800000 + (size_t)3 * 400032 + (size_t)3 * 400000 + 4800
                     + 153600000 + 4096;
  int XBU = 0, XBT = 0;
  if      (ws_size >= fixed + 38400000) { XBU = 1; XBT = 1; }
  else if (ws_size >= fixed + 25600000) { XBT = 1; }

  char* w = (char*)d_ws;
  u16* Wtv = (u16*)w;        w += 786432;
  u16* WtsC = (u16*)w;       w += 131072;
  float* bskC = (float*)w;   w += 2048;
  u16* Mwt = (u16*)w;        w += 786432;
  float* Uw = (float*)w;     w += 12288;
  float* zeros = (float*)w;  w += 2048;
  float* cbuf = (float*)w;   w += 1600000;
  float* agg_u = (float*)w;  w += (size_t)NUU * DD * 4;
  float* agg_t = (float*)w;  w += (size_t)NTT * DD * 4;
  int* rptrA[3]; int* csrcA[3];
  for (int r = 0; r < 3; ++r) { rptrA[r] = (int*)w; w += 400032; }
  for (int r = 0; r < 3; ++r) { csrcA[r] = (int*)w; w += 400000; }
  int* bsumA = (int*)w;      w += 4800;
  u16* xb_user = nullptr; u16* xb_tweet = nullptr;
  if (XBT) { xb_tweet = (u16*)w; w += (size_t)NTT * DD * 2; }
  if (XBU) { xb_user = (u16*)w;  w += (size_t)NUU * DD * 2; }
  u16* arena = (u16*)w;      // 153.6 MB; CSR cnt/cursor aliases its start
  int* cntA[3];
  cntA[0] = (int*)arena; cntA[1] = cntA[0] + 100000; cntA[2] = cntA[0] + 200000;

  init_x2<<<(19500000 + 255) / 256, 256, 0, stream>>>(emb_user, tv_tweet, x_user, x_tweet,
                                                      cntA[0], xb_user, xb_tweet, XBU, XBT);
  conv_w<<<(6 * 512 * 128 + 255) / 256, 256, 0, stream>>>(W_qkv, W_skip, b_skip,
                                                          Wtv, WtsC, bskC, zeros);
  mk_m2<<<dim3(24, 8), 256, 0, stream>>>(W_qkv, b_qkv, Mwt, Uw);

  hist3<<<(3 * EE + 255) / 256, 256, 0, stream>>>(edges[0], edges[1], edges[2],
                                                  cntA[0], cntA[1], cntA[2]);
  bsum3<<<783, 256, 0, stream>>>(cntA[0], cntA[1], cntA[2], bsumA);
  bscan3<<<3, 256, 0, stream>>>(bsumA);
  rptr3<<<783, 256, 0, stream>>>(cntA[0], cntA[1], cntA[2], bsumA, rptrA[0], rptrA[1], rptrA[2]);
  fill3<<<(3 * EE + 255) / 256, 256, 0, stream>>>(edges[0], edges[1], edges[2],
                                                  cntA[0], cntA[1], cntA[2],
                                                  csrcA[0], csrcA[1], csrcA[2]);

  const int stt[3] = {0, 0, 1}, dtt[3] = {0, 1, 0};
  const int cnt2[2] = {NUU, NTT};
  float* xs[2]   = {x_user, x_tweet};
  u16* xbs[2]    = {xb_user, xb_tweet};
  const int xbf[2] = {XBU, XBT};
  float* aggs[2] = {agg_u, agg_t};

  for (int l = 0; l < 2; ++l) {
    gemm_skip3<<<BU + BT, 256, 0, stream>>>(
        xb_user, xb_tweet, x_user, x_tweet,
        WtsC + (size_t)(2 * l) * 128 * 128, WtsC + (size_t)(2 * l + 1) * 128 * 128,
        bskC + (size_t)(2 * l) * 128, bskC + (size_t)(2 * l + 1) * 128,
        agg_u, agg_t, XBU, XBT);

    for (int r = 0; r < 3; ++r) {
      const int st = stt[r], dt = dtt[r];
      const int ns = cnt2[st], nd = cnt2[dt];
      const int rel = l * 3 + r;
      const bool qDeg = (l == 0 && dt == 1);   // ut-l0: broadcast dst
      const bool uniSM = (l == 0 && st == 1);  // tu-l0: broadcast src -> uniform softmax

      const int nq_eff = uniSM ? 0 : (qDeg ? 1 : nd);
      const int nv_eff = uniSM ? 1 : ns;
      u16* qb_r = arena;
      u16* vb_r = arena + (size_t)nq_eff * HCC;

      GRel2 ga;
      ga.Xqb = xbs[dt]; ga.Xqf = xs[dt]; ga.xbq = xbf[dt];
      ga.Xvb = xbs[st]; ga.Xvf = xs[st]; ga.xbv = xbf[st];
      ga.Wq = Mwt + (size_t)rel * 512 * 128;
      ga.Wv = Wtv + (size_t)rel * 512 * 128;
      ga.bzq = zeros;
      ga.bzv = b_qkv + (size_t)(rel * 3 + 2) * HCC;
      ga.oq = qb_r; ga.ov = vb_r;
      ga.nq = nq_eff; ga.nv = nv_eff;
      ga.bq = (nq_eff + 127) / 128; ga.bv = (nv_eff + 127) / 128;
      gemm_rel2<<<ga.bq + ga.bv, 256, 0, stream>>>(ga);

      const int eblk = (nd + 3) / 4;
      if (uniSM) {
        add_bcast4<<<eblk, 256, 0, stream>>>(vb_r, rptrA[r], aggs[dt], nd);
      } else {
        c_kernel<<<(ns + 3) / 4, 256, 0, stream>>>(xbs[st], xs[st], Uw + (size_t)rel * 512,
                                                   cbuf, ns, xbf[st]);
        const int qs32 = qDeg ? 0 : 256;
        if (xbf[st])
          edge_fused2<1><<<eblk, 256, 0, stream>>>(qb_r, vb_r, xbs[st], xs[st], cbuf,
                                                   rptrA[r], csrcA[r], aggs[dt], nd, qs32);
        else
          edge_fused2<0><<<eblk, 256, 0, stream>>>(qb_r, vb_r, xbs[st], xs[st], cbuf,
                                                   rptrA[r], csrcA[r], aggs[dt], nd, qs32);
      }
    }
    ln2<<<(NUU + NTT + 3) / 4, 256, 0, stream>>>(agg_u, agg_t,
                                                 ln_g + (size_t)l * 2 * DD,
                                                 ln_b + (size_t)l * 2 * DD,
                                                 x_user, x_tweet,
                                                 xb_user, xb_tweet,
                                                 XBU && l == 0, XBT && l == 0);
  }
}

// Round 12
// 749.722 us; speedup vs baseline: 5.5267x; 1.3286x over previous
//
#include <hip/hip_runtime.h>
#include <hip/hip_bf16.h>
#include <math.h>

typedef unsigned short u16;
typedef unsigned int   u32;
typedef __attribute__((ext_vector_type(8))) short s8v;    // 8 x bf16
typedef __attribute__((ext_vector_type(8))) unsigned short u16x8;
typedef __attribute__((ext_vector_type(4))) float f4v;    // MFMA accumulator

#define NUU 50000
#define NTT 100000
#define EE  100000
#define DD  128
#define HH  4
#define HCC 512
#define BU  391
#define BT  782

// ---------- helpers ----------
__device__ __forceinline__ float bflo(u32 u) { return __uint_as_float(u << 16); }
__device__ __forceinline__ float bfhi(u32 u) { return __uint_as_float(u & 0xFFFF0000u); }
__device__ __forceinline__ u16 f2bf(float f) {
  u32 u = __float_as_uint(f);
  u32 r = (u + 0x7FFFu + ((u >> 16) & 1u)) >> 16;
  return (u16)r;
}
__device__ __forceinline__ s8v cvt_row8(const float* __restrict__ p) {
  float4 u = *(const float4*)p;
  float4 v = *(const float4*)(p + 4);
  s8v r;
  r[0] = (short)f2bf(u.x); r[1] = (short)f2bf(u.y);
  r[2] = (short)f2bf(u.z); r[3] = (short)f2bf(u.w);
  r[4] = (short)f2bf(v.x); r[5] = (short)f2bf(v.y);
  r[6] = (short)f2bf(v.z); r[7] = (short)f2bf(v.w);
  return r;
}
__device__ __forceinline__ int colperm(int c) {   // still used by skip GEMM
  return (c & ~31) | (((c >> 2) & 3) << 3) | (((c >> 4) & 1) << 2) | (c & 3);
}

// ---------- init: x + bf16 mirrors + zero cnt ----------
__global__ __launch_bounds__(256) void init_x2(const float* __restrict__ emb,
                                               const float* __restrict__ tv,
                                               float* __restrict__ xu,
                                               float* __restrict__ xt,
                                               int* __restrict__ cz,
                                               u16* __restrict__ xbu,
                                               u16* __restrict__ xbt,
                                               int fu, int ft) {
  size_t idx = (size_t)blockIdx.x * 256 + threadIdx.x;
  const size_t nu = (size_t)NUU * DD;
  const size_t nt = (size_t)NTT * DD;
  if (idx < nu) {
    float v = emb[idx];
    xu[idx] = v;
    if (fu) xbu[idx] = f2bf(v);
  } else if (idx < nu + nt) {
    size_t j = idx - nu;
    float v = tv[j & (DD - 1)];
    xt[j] = v;
    if (ft) xbt[j] = f2bf(v);
  } else {
    size_t j = idx - (nu + nt);
    if (j < 300000) cz[j] = 0;
  }
}

// ---------- weights ----------
// Wtv: fragment-swizzled layout per mat (65536 u16):
//   Wsw[((ct*4 + kk)*64 + lane)*8 + e] = W[k][col], col = ct*16 + (lane&15),
//   k = kk*32 + (lane>>4)*8 + e.   (W = V weight, [128][512] row-major-by-k)
__global__ __launch_bounds__(256) void conv_w(const float* __restrict__ Wq,
                                              const float* __restrict__ Wsk,
                                              const float* __restrict__ bsk,
                                              u16* __restrict__ Wtv,
                                              u16* __restrict__ WtsC,
                                              float* __restrict__ bskC,
                                              float* __restrict__ zeros) {
  int idx = blockIdx.x * 256 + threadIdx.x;
  if (idx < 6 * 65536) {
    int mat = idx >> 16, pos = idx & 65535;
    int e = pos & 7, lane = (pos >> 3) & 63, kk = (pos >> 9) & 3, ct = pos >> 11;
    int col = ct * 16 + (lane & 15);
    int k = kk * 32 + (lane >> 4) * 8 + e;
    Wtv[idx] = f2bf(Wq[((size_t)(mat * 3 + 2) * 128 + k) * 512 + col]);
  }
  if (idx < 4 * 128 * 128) {
    int k = idx & 127, cp = (idx >> 7) & 127, m = idx >> 14;
    int l = m >> 1, isT = m & 1, col = colperm(cp);
    float v;
    if (isT) v = Wsk[((size_t)(l * 3 + 1) * 128 + k) * 128 + col];
    else     v = Wsk[((size_t)(l * 3 + 0) * 128 + k) * 128 + col]
               + Wsk[((size_t)(l * 3 + 2) * 128 + k) * 128 + col];
    WtsC[idx] = f2bf(v);
  }
  if (idx < 4 * 128) {
    int m = idx >> 7, c = idx & 127;
    int l = m >> 1, isT = m & 1;
    bskC[idx] = isT ? bsk[(size_t)(l * 3 + 1) * 128 + c]
                    : bsk[(size_t)(l * 3 + 0) * 128 + c] + bsk[(size_t)(l * 3 + 2) * 128 + c];
  }
  if (idx < 512) zeros[idx] = 0.f;
}

// ---------- M = Wq_h @ Wk_h^T (swizzled output) + U = Wk_h @ bq_h ----------
__global__ __launch_bounds__(256) void mk_m2(const float* __restrict__ Wq_all,
                                             const float* __restrict__ bq_all,
                                             u16* __restrict__ Mwt,
                                             float* __restrict__ Uw) {
  const int rel = blockIdx.x >> 2, h = blockIdx.x & 3;
  const int cpB = blockIdx.y;                 // 16 d-rows per block
  const float* Wq = Wq_all + (size_t)(rel * 3 + 0) * 128 * 512 + h * 128;
  const float* Wk = Wq_all + (size_t)(rel * 3 + 1) * 128 * 512 + h * 128;
  const float* bq = bq_all + (size_t)(rel * 3 + 0) * 512 + h * 128;

  __shared__ float Qs[128][129];
  __shared__ float Ks[16][129];
  for (int idx = threadIdx.x; idx < 16384; idx += 256) {
    int a = idx >> 7, c = idx & 127;
    Qs[a][c] = Wq[(size_t)a * 512 + c];
  }
  for (int idx = threadIdx.x; idx < 2048; idx += 256) {
    int row = idx >> 7, c = idx & 127;
    int d = cpB * 16 + row;
    Ks[row][c] = Wk[(size_t)d * 512 + c];
  }
  __syncthreads();

  const int a = threadIdx.x & 127;
  const int rsel = threadIdx.x >> 7;
  float acc[8] = {};
  for (int c = 0; c < 128; ++c) {
    float qa = Qs[a][c];
    #pragma unroll
    for (int j = 0; j < 8; ++j) acc[j] = fmaf(qa, Ks[rsel * 8 + j][c], acc[j]);
  }
  const int kk = a >> 5, l4a = (a >> 3) & 3, e = a & 7;
  #pragma unroll
  for (int j = 0; j < 8; ++j) {
    int d = cpB * 16 + rsel * 8 + j;
    int col = h * 128 + d;
    int ct = col >> 4, l15c = col & 15;
    int lane = l4a * 16 + l15c;
    Mwt[(size_t)rel * 65536 + ((size_t)(ct * 4 + kk) * 64 + lane) * 8 + e] = f2bf(acc[j]);
  }

  if (cpB == 0 && threadIdx.x < 128) {
    int d = threadIdx.x;
    float s = 0.f;
    for (int c = 0; c < 128; ++c) s = fmaf(Wk[(size_t)d * 512 + c], bq[c], s);
    Uw[((size_t)rel * 4 + h) * 128 + d] = s * 0.08838834764831845f;
  }
}

// ---------- CSR build ----------
__global__ __launch_bounds__(256) void hist3(const int* e0, const int* e1, const int* e2,
                                             int* c0, int* c1, int* c2) {
  int idx = blockIdx.x * 256 + threadIdx.x;
  if (idx >= 3 * EE) return;
  int r = idx / EE, e = idx - r * EE;
  const int* edst = (r == 0 ? e0 : r == 1 ? e1 : e2) + EE;
  int* cnt = r == 0 ? c0 : r == 1 ? c1 : c2;
  atomicAdd(&cnt[edst[e]], 1);
}

__global__ __launch_bounds__(256) void bsum3(const int* c0, const int* c1, const int* c2,
                                             int* __restrict__ bsumA) {
  int b = blockIdx.x;
  int r, lb, n;
  if (b < 196)      { r = 0; lb = b;       n = NUU; }
  else if (b < 587) { r = 1; lb = b - 196; n = NTT; }
  else              { r = 2; lb = b - 587; n = NUU; }
  const int* cnt = r == 0 ? c0 : r == 1 ? c1 : c2;
  int i = lb * 256 + threadIdx.x;
  int v = (i < n) ? cnt[i] : 0;
  #pragma unroll
  for (int o = 1; o < 64; o <<= 1) v += __shfl_xor(v, o);
  __shared__ int ws4[4];
  if ((threadIdx.x & 63) == 0) ws4[threadIdx.x >> 6] = v;
  __syncthreads();
  if (threadIdx.x == 0) bsumA[r * 400 + lb] = ws4[0] + ws4[1] + ws4[2] + ws4[3];
}

__global__ __launch_bounds__(256) void bscan3(int* __restrict__ bsumA) {
  int r = blockIdx.x;
  int* bsum = bsumA + r * 400;
  const int nb = (r == 1) ? 391 : 196;
  __shared__ int sh[256];
  __shared__ int runs;
  if (threadIdx.x == 0) runs = 0;
  __syncthreads();
  for (int base = 0; base < nb; base += 256) {
    int i = base + threadIdx.x;
    int v = (i < nb) ? bsum[i] : 0;
    sh[threadIdx.x] = v;
    __syncthreads();
    for (int o = 1; o < 256; o <<= 1) {
      int t = (threadIdx.x >= o) ? sh[threadIdx.x - o] : 0;
      __syncthreads();
      sh[threadIdx.x] += t;
      __syncthreads();
    }
    int incl = sh[threadIdx.x];
    int r0 = runs;
    if (i < nb) bsum[i] = r0 + incl - v;
    __syncthreads();
    if (threadIdx.x == 0) runs = r0 + sh[255];
    __syncthreads();
  }
}

__global__ __launch_bounds__(256) void rptr3(int* c0, int* c1, int* c2,
                                             const int* __restrict__ bsumA,
                                             int* r0p, int* r1p, int* r2p) {
  int b = blockIdx.x;
  int r, lb, n;
  if (b < 196)      { r = 0; lb = b;       n = NUU; }
  else if (b < 587) { r = 1; lb = b - 196; n = NTT; }
  else              { r = 2; lb = b - 587; n = NUU; }
  int* cnt = r == 0 ? c0 : r == 1 ? c1 : c2;
  int* rptr = r == 0 ? r0p : r == 1 ? r1p : r2p;
  __shared__ int sh[256];
  int i = lb * 256 + threadIdx.x;
  int v = (i < n) ? cnt[i] : 0;
  sh[threadIdx.x] = v;
  __syncthreads();
  for (int o = 1; o < 256; o <<= 1) {
    int t = (threadIdx.x >= o) ? sh[threadIdx.x - o] : 0;
    __syncthreads();
    sh[threadIdx.x] += t;
    __syncthreads();
  }
  int excl = sh[threadIdx.x] - v + bsumA[r * 400 + lb];
  if (i < n) { rptr[i] = excl; cnt[i] = excl; }
  if (i == 0) rptr[n] = EE;
}

__global__ __launch_bounds__(256) void fill3(const int* e0, const int* e1, const int* e2,
                                             int* c0, int* c1, int* c2,
                                             int* s0, int* s1, int* s2) {
  int idx = blockIdx.x * 256 + threadIdx.x;
  if (idx >= 3 * EE) return;
  int r = idx / EE, e = idx - r * EE;
  const int* ebase = (r == 0 ? e0 : r == 1 ? e1 : e2);
  int* cursor = r == 0 ? c0 : r == 1 ? c1 : c2;
  int* csrc = r == 0 ? s0 : r == 1 ? s1 : s2;
  int pos = atomicAdd(&cursor[ebase[EE + e]], 1);
  csrc[pos] = ebase[e];
}

// ---------- c kernel: c[s][h] = scale * x_s . u_h ----------
__global__ __launch_bounds__(256) void c_kernel(const u16* __restrict__ xsb,
                                                const float* __restrict__ xsf,
                                                const float* __restrict__ u,
                                                float* __restrict__ cbuf,
                                                int ns, int XF) {
  int node = (int)(((size_t)blockIdx.x * 256 + threadIdx.x) >> 6);
  int lane = threadIdx.x & 63;
  if (node >= ns) return;
  float x0, x1;
  if (XF) {
    u32 xu = ((const u32*)xsb)[(size_t)node * 64 + lane];
    x0 = bflo(xu); x1 = bfhi(xu);
  } else {
    const float* xp = xsf + (size_t)node * 128 + 2 * lane;
    x0 = xp[0]; x1 = xp[1];
  }
  #pragma unroll
  for (int h = 0; h < 4; ++h) {
    float d = x0 * u[h * 128 + 2 * lane] + x1 * u[h * 128 + 2 * lane + 1];
    #pragma unroll
    for (int o = 1; o < 64; o <<= 1) d += __shfl_xor(d, o);
    if (lane == 0) cbuf[(size_t)node * 4 + h] = d;
  }
}

// ---------- LDS-staged q'/V GEMM: 32 rows x 512 cols per block ----------
struct GRel3 {
  const u16* Xqb; const float* Xqf;
  const u16* Xvb; const float* Xvf;
  const u16* Wq; const u16* Wv;       // fragment-swizzled layouts
  const float* bzq; const float* bzv;
  u16 *oq, *ov;
  int nq, nv, bq, bv, xbq, xbv;
};

__global__ __launch_bounds__(256) void gemm_rel3(GRel3 a) {
  __shared__ u16 Xs[32 * 128];   // 8 KB,  swizzled: byte ^= (row&7)<<4
  __shared__ u16 Os[32 * 512];   // 32 KB, swizzled: byte ^= (row&7)<<4
  const int bx = blockIdx.x;
  int lb, n, usexb; const u16* Xb; const float* Xf; const u16* Wsw; const float* bias; u16* Y;
  if (bx < a.bq) { lb = bx; n = a.nq; Xb = a.Xqb; Xf = a.Xqf; Wsw = a.Wq; bias = a.bzq; Y = a.oq; usexb = a.xbq; }
  else { lb = bx - a.bq; n = a.nv; Xb = a.Xvb; Xf = a.Xvf; Wsw = a.Wv; bias = a.bzv; Y = a.ov; usexb = a.xbv; }
  const int row0 = lb * 32;
  if (row0 >= n) return;
  const int tid = threadIdx.x;

  // ---- stage X (coalesced global -> swizzled LDS) ----
  if (usexb) {
    #pragma unroll
    for (int q = 0; q < 2; ++q) {
      int c = tid + q * 256;             // 512 chunks of 16B
      int row = c >> 4, off = (c & 15) * 16;
      int gr = row0 + row; if (gr >= n) gr = n - 1;
      uint4 val = *(const uint4*)((const char*)Xb + (size_t)gr * 256 + off);
      *(uint4*)((char*)Xs + row * 256 + (off ^ ((row & 7) << 4))) = val;
    }
  } else {
    #pragma unroll
    for (int q = 0; q < 4; ++q) {
      int c = tid + q * 256;             // 1024 chunks: f32x4 -> bf16x4 (8B)
      int row = c >> 5, sub = c & 31;
      int gr = row0 + row; if (gr >= n) gr = n - 1;
      float4 f = *(const float4*)(Xf + (size_t)gr * 128 + sub * 4);
      ushort4 pk;
      pk.x = f2bf(f.x); pk.y = f2bf(f.y); pk.z = f2bf(f.z); pk.w = f2bf(f.w);
      *(ushort4*)((char*)Xs + row * 256 + ((sub * 8) ^ ((row & 7) << 4))) = pk;
    }
  }
  __syncthreads();

  const int wid = tid >> 6, lane = tid & 63;
  const int l15 = lane & 15, l4 = lane >> 4;

  // A fragments: 2 row-tiles of 16
  s8v afr[2][4];
  #pragma unroll
  for (int rt = 0; rt < 2; ++rt) {
    int row = rt * 16 + l15;
    #pragma unroll
    for (int kk = 0; kk < 4; ++kk)
      afr[rt][kk] = *(const s8v*)((const char*)Xs + row * 256 + ((kk * 64 + l4 * 16) ^ ((row & 7) << 4)));
  }

  // wave wid covers cols wid*128 .. +127  (8 coltiles)
  const u16* wbase = Wsw + ((size_t)wid * 16384) + (size_t)lane * 8;
  s8v w0[4], w1[4];
  #pragma unroll
  for (int kk = 0; kk < 4; ++kk) w0[kk] = *(const s8v*)(wbase + kk * 512);

  #pragma unroll
  for (int ctl = 0; ctl < 8; ++ctl) {
    const s8v* cw = (ctl & 1) ? w1 : w0;
    s8v* nw = (ctl & 1) ? w0 : w1;
    if (ctl + 1 < 8) {
      #pragma unroll
      for (int kk = 0; kk < 4; ++kk)
        nw[kk] = *(const s8v*)(wbase + (ctl + 1) * 2048 + kk * 512);
    }
    f4v acc0 = {}, acc1 = {};
    #pragma unroll
    for (int kk = 0; kk < 4; ++kk) {
      acc0 = __builtin_amdgcn_mfma_f32_16x16x32_bf16(cw[kk], afr[0][kk], acc0, 0, 0, 0);
      acc1 = __builtin_amdgcn_mfma_f32_16x16x32_bf16(cw[kk], afr[1][kk], acc1, 0, 0, 0);
    }
    const int colb = wid * 128 + ctl * 16 + l4 * 4;
    const float4 bb = *(const float4*)(bias + colb);
    {
      int row = l15;
      ushort4 pk;
      pk.x = f2bf(acc0[0] + bb.x); pk.y = f2bf(acc0[1] + bb.y);
      pk.z = f2bf(acc0[2] + bb.z); pk.w = f2bf(acc0[3] + bb.w);
      *(ushort4*)((char*)Os + row * 1024 + ((colb * 2) ^ ((row & 7) << 4))) = pk;
    }
    {
      int row = 16 + l15;
      ushort4 pk;
      pk.x = f2bf(acc1[0] + bb.x); pk.y = f2bf(acc1[1] + bb.y);
      pk.z = f2bf(acc1[2] + bb.z); pk.w = f2bf(acc1[3] + bb.w);
      *(ushort4*)((char*)Os + row * 1024 + ((colb * 2) ^ ((row & 7) << 4))) = pk;
    }
  }
  __syncthreads();

  // ---- store: full 1KB rows, coalesced ----
  #pragma unroll
  for (int r = 0; r < 8; ++r) {
    int row = wid * 8 + r;
    int gr = row0 + row;
    if (gr < n) {
      uint4 val = *(const uint4*)((const char*)Os + row * 1024 + ((lane * 16) ^ ((row & 7) << 4)));
      *(uint4*)(Y + (size_t)gr * 512 + lane * 8) = val;
    }
  }
}

// ---------- skip GEMM (flat grid, STORE) — unchanged ----------
__global__ __launch_bounds__(256) void gemm_skip3(const u16* xbu, const u16* xbt,
                                                  const float* xfu, const float* xft,
                                                  const u16* Wu, const u16* Wtw,
                                                  const float* bu, const float* btw,
                                                  float* aggu, float* aggt,
                                                  int fu, int ft) {
  const int bx = blockIdx.x;
  int job, lb;
  if (bx < BU) { job = 0; lb = bx; } else { job = 1; lb = bx - BU; }
  const int n = job ? NTT : NUU;
  const int bm = lb * 128;
  const u16* XB = job ? xbt : xbu;
  const float* XF = job ? xft : xfu;
  const u16* Wt = job ? Wtw : Wu;
  const float* bias = job ? btw : bu;
  float* out = job ? aggt : aggu;
  const int usexb = job ? ft : fu;

  const int wid = threadIdx.x >> 6, lane = threadIdx.x & 63;
  const int l15 = lane & 15, l4 = lane >> 4;
  const int rbase = bm + wid * 32;
  int r0 = rbase + l15;      if (r0 >= n) r0 = n - 1;
  int r1 = rbase + 16 + l15; if (r1 >= n) r1 = n - 1;
  s8v a0[4], a1[4];
  if (usexb) {
    const u16* xb0 = XB + (size_t)r0 * DD + l4 * 8;
    const u16* xb1 = XB + (size_t)r1 * DD + l4 * 8;
    #pragma unroll
    for (int kk = 0; kk < 4; ++kk) {
      a0[kk] = *(const s8v*)(xb0 + kk * 32);
      a1[kk] = *(const s8v*)(xb1 + kk * 32);
    }
  } else {
    const float* xp0 = XF + (size_t)r0 * DD + l4 * 8;
    const float* xp1 = XF + (size_t)r1 * DD + l4 * 8;
    #pragma unroll
    for (int kk = 0; kk < 4; ++kk) {
      a0[kk] = cvt_row8(xp0 + kk * 32);
      a1[kk] = cvt_row8(xp1 + kk * 32);
    }
  }

  const u16* wp = Wt + (size_t)l15 * DD + l4 * 8;
  const bool ok0 = (rbase + l15 < n), ok1 = (rbase + 16 + l15 < n);
  float* yp0 = out + (size_t)(rbase + l15) * DD + l4 * 8;
  float* yp1 = out + (size_t)(rbase + 16 + l15) * DD + l4 * 8;

  s8v w0[8], w1[8];
  #pragma unroll
  for (int kk = 0; kk < 4; ++kk) {
    w0[kk]     = *(const s8v*)(wp + kk * 32);
    w0[4 + kk] = *(const s8v*)(wp + 16 * DD + kk * 32);
  }
  #pragma unroll
  for (int p = 0; p < 4; ++p) {
    const s8v* cw = (p & 1) ? w1 : w0;
    s8v* nw = (p & 1) ? w0 : w1;
    if (p + 1 < 4) {
      const u16* wq = wp + (size_t)(2 * (p + 1)) * 16 * DD;
      #pragma unroll
      for (int kk = 0; kk < 4; ++kk) {
        nw[kk]     = *(const s8v*)(wq + kk * 32);
        nw[4 + kk] = *(const s8v*)(wq + 16 * DD + kk * 32);
      }
    }
    f4v aE0 = {}, aE1 = {}, aO0 = {}, aO1 = {};
    #pragma unroll
    for (int kk = 0; kk < 4; ++kk) {
      aE0 = __builtin_amdgcn_mfma_f32_16x16x32_bf16(cw[kk], a0[kk], aE0, 0, 0, 0);
      aE1 = __builtin_amdgcn_mfma_f32_16x16x32_bf16(cw[kk], a1[kk], aE1, 0, 0, 0);
      aO0 = __builtin_amdgcn_mfma_f32_16x16x32_bf16(cw[4 + kk], a0[kk], aO0, 0, 0, 0);
      aO1 = __builtin_amdgcn_mfma_f32_16x16x32_bf16(cw[4 + kk], a1[kk], aO1, 0, 0, 0);
    }
    const float4 bbE = *(const float4*)(bias + p * 32 + l4 * 8);
    const float4 bbO = *(const float4*)(bias + p * 32 + l4 * 8 + 4);
    if (ok0) {
      *(float4*)(yp0 + p * 32) = make_float4(aE0[0] + bbE.x, aE0[1] + bbE.y, aE0[2] + bbE.z, aE0[3] + bbE.w);
      *(float4*)(yp0 + p * 32 + 4) = make_float4(aO0[0] + bbO.x, aO0[1] + bbO.y, aO0[2] + bbO.z, aO0[3] + bbO.w);
    }
    if (ok1) {
      *(float4*)(yp1 + p * 32) = make_float4(aE1[0] + bbE.x, aE1[1] + bbE.y, aE1[2] + bbE.z, aE1[3] + bbE.w);
      *(float4*)(yp1 + p * 32 + 4) = make_float4(aO1[0] + bbO.x, aO1[1] + bbO.y, aO1[2] + bbO.z, aO1[3] + bbO.w);
    }
  }
}

// ---------- edge kernel: logits via q'.x_s + c(s); V gather; deg-1 fast path ----------
template<int XF>
__global__ __launch_bounds__(256) void edge_fused2(const u16* __restrict__ qp,
                                                   const u16* __restrict__ v,
                                                   const u16* __restrict__ xsb,
                                                   const float* __restrict__ xsf,
                                                   const float* __restrict__ cbuf,
                                                   const int* __restrict__ rptr,
                                                   const int* __restrict__ csrc,
                                                   float* __restrict__ agg,
                                                   int nd, int qs32) {
  int node = (int)(((size_t)blockIdx.x * 256 + threadIdx.x) >> 6);
  int lane = threadIdx.x & 63;
  if (node >= nd) return;
  int e0 = rptr[node], e1 = rptr[node + 1];
  if (e0 == e1) return;
  const int g = lane >> 4, i = lane & 15;
  float acc[8];

  if (e1 - e0 == 1) {
    int s = csrc[e0];
    const u32* vp = (const u32*)v + (size_t)s * 256 + lane * 4;
    #pragma unroll
    for (int j = 0; j < 4; ++j) { u32 u = vp[j]; acc[2 * j] = bflo(u); acc[2 * j + 1] = bfhi(u); }
  } else {
    u32 qv[4];
    {
      const u32* qq = (const u32*)qp + (size_t)node * qs32 + g * 64 + i * 4;
      #pragma unroll
      for (int j = 0; j < 4; ++j) qv[j] = qq[j];
    }
    float m = -1e30f, z = 0.f;
    #pragma unroll
    for (int j = 0; j < 8; ++j) acc[j] = 0.f;

    int s_cur = csrc[e0];
    u32 xc[4]; float xf[8];
    if (XF) {
      const u32* xp = (const u32*)xsb + (size_t)s_cur * 64 + i * 4;
      #pragma unroll
      for (int j = 0; j < 4; ++j) xc[j] = xp[j];
    } else {
      const float* xp = xsf + (size_t)s_cur * 128 + i * 8;
      #pragma unroll
      for (int j = 0; j < 8; ++j) xf[j] = xp[j];
    }

    for (int e = e0; e < e1; ++e) {
      u32 vcur[4];
      {
        const u32* vp = (const u32*)v + (size_t)s_cur * 256 + lane * 4;
        #pragma unroll
        for (int j = 0; j < 4; ++j) vcur[j] = vp[j];
      }
      float cs = cbuf[(size_t)s_cur * 4 + g];
      const bool has = (e + 1 < e1);
      int s_nxt = csrc[has ? e + 1 : e0];
      u32 xn[4]; float xnf[8];
      if (XF) {
        const u32* xp = (const u32*)xsb + (size_t)s_nxt * 64 + i * 4;
        #pragma unroll
        for (int j = 0; j < 4; ++j) xn[j] = xp[j];
      } else {
        const float* xp = xsf + (size_t)s_nxt * 128 + i * 8;
        #pragma unroll
        for (int j = 0; j < 8; ++j) xnf[j] = xp[j];
      }

      float dot = 0.f;
      if (XF) {
        #pragma unroll
        for (int j = 0; j < 4; ++j)
          dot += bflo(qv[j]) * bflo(xc[j]) + bfhi(qv[j]) * bfhi(xc[j]);
      } else {
        #pragma unroll
        for (int j = 0; j < 4; ++j)
          dot += bflo(qv[j]) * xf[2 * j] + bfhi(qv[j]) * xf[2 * j + 1];
      }
      dot += __shfl_xor(dot, 1);
      dot += __shfl_xor(dot, 2);
      dot += __shfl_xor(dot, 4);
      dot += __shfl_xor(dot, 8);
      float lg = dot * 0.08838834764831845f + cs;
      float w;
      if (lg > m) {
        float sc = __expf(m - lg);
        z *= sc;
        #pragma unroll
        for (int j = 0; j < 8; ++j) acc[j] *= sc;
        m = lg; w = 1.f;
      } else {
        w = __expf(lg - m);
      }
      z += w;
      #pragma unroll
      for (int j = 0; j < 4; ++j) {
        acc[2 * j]     += w * bflo(vcur[j]);
        acc[2 * j + 1] += w * bfhi(vcur[j]);
      }
      if (has) {
        s_cur = s_nxt;
        if (XF) {
          #pragma unroll
          for (int j = 0; j < 4; ++j) xc[j] = xn[j];
        } else {
          #pragma unroll
          for (int j = 0; j < 8; ++j) xf[j] = xnf[j];
        }
      }
    }
    float iz = 1.f / z;
    #pragma unroll
    for (int j = 0; j < 8; ++j) acc[j] *= iz;
  }

  #pragma unroll
  for (int j = 0; j < 8; ++j) acc[j] *= 0.25f;
  #pragma unroll
  for (int o = 16; o < 64; o <<= 1) {
    #pragma unroll
    for (int j = 0; j < 8; ++j) acc[j] += __shfl_xor(acc[j], o);
  }
  if (lane < 16) {
    float* op = agg + (size_t)node * DD + lane * 8;
    #pragma unroll
    for (int j = 0; j < 8; ++j) op[j] += acc[j];
  }
}

// ---------- l0-tu shortcut: uniform softmax over broadcast K/V ----------
__global__ __launch_bounds__(256) void add_bcast4(const u16* __restrict__ v,
                                                  const int* __restrict__ rptr,
                                                  float* __restrict__ agg, int nd) {
  int node = (int)(((size_t)blockIdx.x * 256 + threadIdx.x) >> 6);
  int lane = threadIdx.x & 63;
  if (node >= nd) return;
  if (rptr[node + 1] <= rptr[node]) return;
  const u32* vp = (const u32*)v;   // row 0
  float a0 = 0.f, a1 = 0.f;
  #pragma unroll
  for (int h = 0; h < 4; ++h) {
    u32 u = vp[h * 64 + lane];
    a0 += bflo(u); a1 += bfhi(u);
  }
  float* op = agg + (size_t)node * DD + 2 * lane;
  op[0] += 0.25f * a0;
  op[1] += 0.25f * a1;
}

// ---------- LayerNorm + residual (+ bf16 mirror writes) ----------
__global__ __launch_bounds__(256) void ln2(const float* __restrict__ aggu,
                                           const float* __restrict__ aggt,
                                           const float* __restrict__ g2,
                                           const float* __restrict__ b2,
                                           float* __restrict__ xu,
                                           float* __restrict__ xt,
                                           u16* __restrict__ xbu,
                                           u16* __restrict__ xbt,
                                           int wbu, int wbt) {
  int wid = (int)(((size_t)blockIdx.x * 256 + threadIdx.x) >> 6);
  int lane = threadIdx.x & 63;
  if (wid >= NUU + NTT) return;
  const float* ap; float* xp; const float* g; const float* b; u16* xbp; int wb;
  if (wid < NUU) {
    ap = aggu + (size_t)wid * DD; xp = xu + (size_t)wid * DD;
    xbp = xbu ? xbu + (size_t)wid * DD : nullptr; g = g2; b = b2; wb = wbu;
  } else {
    int t = wid - NUU;
    ap = aggt + (size_t)t * DD; xp = xt + (size_t)t * DD;
    xbp = xbt ? xbt + (size_t)t * DD : nullptr; g = g2 + DD; b = b2 + DD; wb = wbt;
  }
  float v0 = ap[lane], v1 = ap[lane + 64];
  float s = v0 + v1;
  #pragma unroll
  for (int o = 1; o < 64; o <<= 1) s += __shfl_xor(s, o);
  float mean = s * (1.0f / DD);
  float d0 = v0 - mean, d1 = v1 - mean;
  float sq = d0 * d0 + d1 * d1;
  #pragma unroll
  for (int o = 1; o < 64; o <<= 1) sq += __shfl_xor(sq, o);
  float rstd = rsqrtf(sq * (1.0f / DD) + 1e-5f);
  float n0 = g[lane]      * d0 * rstd + b[lane]      + xp[lane];
  float n1 = g[lane + 64] * d1 * rstd + b[lane + 64] + xp[lane + 64];
  xp[lane] = n0;
  xp[lane + 64] = n1;
  if (wb) {
    xbp[lane] = f2bf(n0);
    xbp[lane + 64] = f2bf(n1);
  }
}

extern "C" void kernel_launch(void* const* d_in, const int* in_sizes, int n_in,
                              void* d_out, int out_size, void* d_ws, size_t ws_size,
                              hipStream_t stream) {
  const float* emb_user = (const float*)d_in[0];
  const float* tv_tweet = (const float*)d_in[1];
  const float* W_qkv  = (const float*)d_in[2];
  const float* b_qkv  = (const float*)d_in[3];
  const float* W_skip = (const float*)d_in[4];
  const float* b_skip = (const float*)d_in[5];
  const float* ln_g   = (const float*)d_in[6];
  const float* ln_b   = (const float*)d_in[7];
  const int* edges[3] = { (const int*)d_in[8], (const int*)d_in[9], (const int*)d_in[10] };

  float* x_user  = (float*)d_out;
  float* x_tweet = x_user + (size_t)NUU * DD;

  // ---- workspace layout ----
  const size_t fixed = 786432 + 131072 + 2048 + 786432 + 12288 + 2048 + 1600000
                     + 76800000 + (size_t)3 * 400032 + (size_t)3 * 400000 + 4800
                     + 153600000 + 4096;
  int XBU = 0, XBT = 0;
  if      (ws_size >= fixed + 38400000) { XBU = 1; XBT = 1; }
  else if (ws_size >= fixed + 25600000) { XBT = 1; }

  char* w = (char*)d_ws;
  u16* Wtv = (u16*)w;        w += 786432;
  u16* WtsC = (u16*)w;       w += 131072;
  float* bskC = (float*)w;   w += 2048;
  u16* Mwt = (u16*)w;        w += 786432;
  float* Uw = (float*)w;     w += 12288;
  float* zeros = (float*)w;  w += 2048;
  float* cbuf = (float*)w;   w += 1600000;
  float* agg_u = (float*)w;  w += (size_t)NUU * DD * 4;
  float* agg_t = (float*)w;  w += (size_t)NTT * DD * 4;
  int* rptrA[3]; int* csrcA[3];
  for (int r = 0; r < 3; ++r) { rptrA[r] = (int*)w; w += 400032; }
  for (int r = 0; r < 3; ++r) { csrcA[r] = (int*)w; w += 400000; }
  int* bsumA = (int*)w;      w += 4800;
  u16* xb_user = nullptr; u16* xb_tweet = nullptr;
  if (XBT) { xb_tweet = (u16*)w; w += (size_t)NTT * DD * 2; }
  if (XBU) { xb_user = (u16*)w;  w += (size_t)NUU * DD * 2; }
  u16* arena = (u16*)w;      // 153.6 MB; CSR cnt/cursor aliases its start
  int* cntA[3];
  cntA[0] = (int*)arena; cntA[1] = cntA[0] + 100000; cntA[2] = cntA[0] + 200000;

  init_x2<<<(19500000 + 255) / 256, 256, 0, stream>>>(emb_user, tv_tweet, x_user, x_tweet,
                                                      cntA[0], xb_user, xb_tweet, XBU, XBT);
  conv_w<<<(6 * 65536 + 255) / 256, 256, 0, stream>>>(W_qkv, W_skip, b_skip,
                                                      Wtv, WtsC, bskC, zeros);
  mk_m2<<<dim3(24, 8), 256, 0, stream>>>(W_qkv, b_qkv, Mwt, Uw);

  hist3<<<(3 * EE + 255) / 256, 256, 0, stream>>>(edges[0], edges[1], edges[2],
                                                  cntA[0], cntA[1], cntA[2]);
  bsum3<<<783, 256, 0, stream>>>(cntA[0], cntA[1], cntA[2], bsumA);
  bscan3<<<3, 256, 0, stream>>>(bsumA);
  rptr3<<<783, 256, 0, stream>>>(cntA[0], cntA[1], cntA[2], bsumA, rptrA[0], rptrA[1], rptrA[2]);
  fill3<<<(3 * EE + 255) / 256, 256, 0, stream>>>(edges[0], edges[1], edges[2],
                                                  cntA[0], cntA[1], cntA[2],
                                                  csrcA[0], csrcA[1], csrcA[2]);

  const int stt[3] = {0, 0, 1}, dtt[3] = {0, 1, 0};
  const int cnt2[2] = {NUU, NTT};
  float* xs[2]   = {x_user, x_tweet};
  u16* xbs[2]    = {xb_user, xb_tweet};
  const int xbf[2] = {XBU, XBT};
  float* aggs[2] = {agg_u, agg_t};

  for (int l = 0; l < 2; ++l) {
    gemm_skip3<<<BU + BT, 256, 0, stream>>>(
        xb_user, xb_tweet, x_user, x_tweet,
        WtsC + (size_t)(2 * l) * 128 * 128, WtsC + (size_t)(2 * l + 1) * 128 * 128,
        bskC + (size_t)(2 * l) * 128, bskC + (size_t)(2 * l + 1) * 128,
        agg_u, agg_t, XBU, XBT);

    for (int r = 0; r < 3; ++r) {
      const int st = stt[r], dt = dtt[r];
      const int ns = cnt2[st], nd = cnt2[dt];
      const int rel = l * 3 + r;
      const bool qDeg = (l == 0 && dt == 1);   // ut-l0: broadcast dst
      const bool uniSM = (l == 0 && st == 1);  // tu-l0: broadcast src -> uniform softmax

      const int nq_eff = uniSM ? 0 : (qDeg ? 1 : nd);
      const int nv_eff = uniSM ? 1 : ns;
      u16* qb_r = arena;
      u16* vb_r = arena + (size_t)nq_eff * HCC;

      GRel3 ga;
      ga.Xqb = xbs[dt]; ga.Xqf = xs[dt]; ga.xbq = xbf[dt];
      ga.Xvb = xbs[st]; ga.Xvf = xs[st]; ga.xbv = xbf[st];
      ga.Wq = Mwt + (size_t)rel * 65536;
      ga.Wv = Wtv + (size_t)rel * 65536;
      ga.bzq = zeros;
      ga.bzv = b_qkv + (size_t)(rel * 3 + 2) * HCC;
      ga.oq = qb_r; ga.ov = vb_r;
      ga.nq = nq_eff; ga.nv = nv_eff;
      ga.bq = (nq_eff + 31) / 32; ga.bv = (nv_eff + 31) / 32;
      gemm_rel3<<<ga.bq + ga.bv, 256, 0, stream>>>(ga);

      const int eblk = (nd + 3) / 4;
      if (uniSM) {
        add_bcast4<<<eblk, 256, 0, stream>>>(vb_r, rptrA[r], aggs[dt], nd);
      } else {
        c_kernel<<<(ns + 3) / 4, 256, 0, stream>>>(xbs[st], xs[st], Uw + (size_t)rel * 512,
                                                   cbuf, ns, xbf[st]);
        const int qs32 = qDeg ? 0 : 256;
        if (xbf[st])
          edge_fused2<1><<<eblk, 256, 0, stream>>>(qb_r, vb_r, xbs[st], xs[st], cbuf,
                                                   rptrA[r], csrcA[r], aggs[dt], nd, qs32);
        else
          edge_fused2<0><<<eblk, 256, 0, stream>>>(qb_r, vb_r, xbs[st], xs[st], cbuf,
                                                   rptrA[r], csrcA[r], aggs[dt], nd, qs32);
      }
    }
    ln2<<<(NUU + NTT + 3) / 4, 256, 0, stream>>>(agg_u, agg_t,
                                                 ln_g + (size_t)l * 2 * DD,
                                                 ln_b + (size_t)l * 2 * DD,
                                                 x_user, x_tweet,
                                                 xb_user, xb_tweet,
                                                 XBU && l == 0, XBT && l == 0);
  }
}

// Round 14
// 663.022 us; speedup vs baseline: 6.2494x; 1.1308x over previous
//
#include <hip/hip_runtime.h>
#include <hip/hip_bf16.h>
#include <math.h>

typedef unsigned short u16;
typedef unsigned int   u32;
typedef __attribute__((ext_vector_type(8))) short s8v;    // 8 x bf16
typedef __attribute__((ext_vector_type(8))) unsigned short u16x8;
typedef __attribute__((ext_vector_type(4))) float f4v;    // MFMA accumulator

#define NUU 50000
#define NTT 100000
#define EE  100000
#define DD  128
#define HH  4
#define HCC 512
#define BU  391
#define BT  782

// ---------- helpers ----------
__device__ __forceinline__ float bflo(u32 u) { return __uint_as_float(u << 16); }
__device__ __forceinline__ float bfhi(u32 u) { return __uint_as_float(u & 0xFFFF0000u); }
__device__ __forceinline__ u16 f2bf(float f) {
  u32 u = __float_as_uint(f);
  u32 r = (u + 0x7FFFu + ((u >> 16) & 1u)) >> 16;
  return (u16)r;
}
__device__ __forceinline__ s8v cvt_row8(const float* __restrict__ p) {
  float4 u = *(const float4*)p;
  float4 v = *(const float4*)(p + 4);
  s8v r;
  r[0] = (short)f2bf(u.x); r[1] = (short)f2bf(u.y);
  r[2] = (short)f2bf(u.z); r[3] = (short)f2bf(u.w);
  r[4] = (short)f2bf(v.x); r[5] = (short)f2bf(v.y);
  r[6] = (short)f2bf(v.z); r[7] = (short)f2bf(v.w);
  return r;
}
__device__ __forceinline__ int colperm(int c) {   // used by skip GEMM
  return (c & ~31) | (((c >> 2) & 3) << 3) | (((c >> 4) & 1) << 2) | (c & 3);
}

// ---------- init: x + bf16 mirrors + zero cnt ----------
__global__ __launch_bounds__(256) void init_x2(const float* __restrict__ emb,
                                               const float* __restrict__ tv,
                                               float* __restrict__ xu,
                                               float* __restrict__ xt,
                                               int* __restrict__ cz,
                                               u16* __restrict__ xbu,
                                               u16* __restrict__ xbt,
                                               int fu, int ft) {
  size_t idx = (size_t)blockIdx.x * 256 + threadIdx.x;
  const size_t nu = (size_t)NUU * DD;
  const size_t nt = (size_t)NTT * DD;
  if (idx < nu) {
    float v = emb[idx];
    xu[idx] = v;
    if (fu) xbu[idx] = f2bf(v);
  } else if (idx < nu + nt) {
    size_t j = idx - nu;
    float v = tv[j & (DD - 1)];
    xt[j] = v;
    if (ft) xbt[j] = f2bf(v);
  } else {
    size_t j = idx - (nu + nt);
    if (j < 300000) cz[j] = 0;
  }
}

// ---------- weights: Wtv fragment-swizzled; combined skip W; zeros ----------
__global__ __launch_bounds__(256) void conv_w(const float* __restrict__ Wq,
                                              const float* __restrict__ Wsk,
                                              const float* __restrict__ bsk,
                                              u16* __restrict__ Wtv,
                                              u16* __restrict__ WtsC,
                                              float* __restrict__ bskC,
                                              float* __restrict__ zeros) {
  int idx = blockIdx.x * 256 + threadIdx.x;
  if (idx < 6 * 65536) {
    int mat = idx >> 16, pos = idx & 65535;
    int e = pos & 7, lane = (pos >> 3) & 63, kk = (pos >> 9) & 3, ct = pos >> 11;
    int col = ct * 16 + (lane & 15);
    int k = kk * 32 + (lane >> 4) * 8 + e;
    Wtv[idx] = f2bf(Wq[((size_t)(mat * 3 + 2) * 128 + k) * 512 + col]);
  }
  if (idx < 4 * 128 * 128) {
    int k = idx & 127, cp = (idx >> 7) & 127, m = idx >> 14;
    int l = m >> 1, isT = m & 1, col = colperm(cp);
    float v;
    if (isT) v = Wsk[((size_t)(l * 3 + 1) * 128 + k) * 128 + col];
    else     v = Wsk[((size_t)(l * 3 + 0) * 128 + k) * 128 + col]
               + Wsk[((size_t)(l * 3 + 2) * 128 + k) * 128 + col];
    WtsC[idx] = f2bf(v);
  }
  if (idx < 4 * 128) {
    int m = idx >> 7, c = idx & 127;
    int l = m >> 1, isT = m & 1;
    bskC[idx] = isT ? bsk[(size_t)(l * 3 + 1) * 128 + c]
                    : bsk[(size_t)(l * 3 + 0) * 128 + c] + bsk[(size_t)(l * 3 + 2) * 128 + c];
  }
  if (idx < 512) zeros[idx] = 0.f;
}

// ---------- M = Wq_h @ Wk_h^T (swizzled output) + U = Wk_h @ bq_h ----------
__global__ __launch_bounds__(256) void mk_m2(const float* __restrict__ Wq_all,
                                             const float* __restrict__ bq_all,
                                             u16* __restrict__ Mwt,
                                             float* __restrict__ Uw) {
  const int rel = blockIdx.x >> 2, h = blockIdx.x & 3;
  const int cpB = blockIdx.y;
  const float* Wq = Wq_all + (size_t)(rel * 3 + 0) * 128 * 512 + h * 128;
  const float* Wk = Wq_all + (size_t)(rel * 3 + 1) * 128 * 512 + h * 128;
  const float* bq = bq_all + (size_t)(rel * 3 + 0) * 512 + h * 128;

  __shared__ float Qs[128][129];
  __shared__ float Ks[16][129];
  for (int idx = threadIdx.x; idx < 16384; idx += 256) {
    int a = idx >> 7, c = idx & 127;
    Qs[a][c] = Wq[(size_t)a * 512 + c];
  }
  for (int idx = threadIdx.x; idx < 2048; idx += 256) {
    int row = idx >> 7, c = idx & 127;
    int d = cpB * 16 + row;
    Ks[row][c] = Wk[(size_t)d * 512 + c];
  }
  __syncthreads();

  const int a = threadIdx.x & 127;
  const int rsel = threadIdx.x >> 7;
  float acc[8] = {};
  for (int c = 0; c < 128; ++c) {
    float qa = Qs[a][c];
    #pragma unroll
    for (int j = 0; j < 8; ++j) acc[j] = fmaf(qa, Ks[rsel * 8 + j][c], acc[j]);
  }
  const int kk = a >> 5, l4a = (a >> 3) & 3, e = a & 7;
  #pragma unroll
  for (int j = 0; j < 8; ++j) {
    int d = cpB * 16 + rsel * 8 + j;
    int col = h * 128 + d;
    int ct = col >> 4, l15c = col & 15;
    int lane = l4a * 16 + l15c;
    Mwt[(size_t)rel * 65536 + ((size_t)(ct * 4 + kk) * 64 + lane) * 8 + e] = f2bf(acc[j]);
  }

  if (cpB == 0 && threadIdx.x < 128) {
    int d = threadIdx.x;
    float s = 0.f;
    for (int c = 0; c < 128; ++c) s = fmaf(Wk[(size_t)d * 512 + c], bq[c], s);
    Uw[((size_t)rel * 4 + h) * 128 + d] = s * 0.08838834764831845f;
  }
}

// ---------- CSR build ----------
__global__ __launch_bounds__(256) void hist3(const int* e0, const int* e1, const int* e2,
                                             int* c0, int* c1, int* c2) {
  int idx = blockIdx.x * 256 + threadIdx.x;
  if (idx >= 3 * EE) return;
  int r = idx / EE, e = idx - r * EE;
  const int* edst = (r == 0 ? e0 : r == 1 ? e1 : e2) + EE;
  int* cnt = r == 0 ? c0 : r == 1 ? c1 : c2;
  atomicAdd(&cnt[edst[e]], 1);
}

__global__ __launch_bounds__(256) void bsum3(const int* c0, const int* c1, const int* c2,
                                             int* __restrict__ bsumA) {
  int b = blockIdx.x;
  int r, lb, n;
  if (b < 196)      { r = 0; lb = b;       n = NUU; }
  else if (b < 587) { r = 1; lb = b - 196; n = NTT; }
  else              { r = 2; lb = b - 587; n = NUU; }
  const int* cnt = r == 0 ? c0 : r == 1 ? c1 : c2;
  int i = lb * 256 + threadIdx.x;
  int v = (i < n) ? cnt[i] : 0;
  #pragma unroll
  for (int o = 1; o < 64; o <<= 1) v += __shfl_xor(v, o);
  __shared__ int ws4[4];
  if ((threadIdx.x & 63) == 0) ws4[threadIdx.x >> 6] = v;
  __syncthreads();
  if (threadIdx.x == 0) bsumA[r * 400 + lb] = ws4[0] + ws4[1] + ws4[2] + ws4[3];
}

__global__ __launch_bounds__(256) void bscan3(int* __restrict__ bsumA) {
  int r = blockIdx.x;
  int* bsum = bsumA + r * 400;
  const int nb = (r == 1) ? 391 : 196;
  __shared__ int sh[256];
  __shared__ int runs;
  if (threadIdx.x == 0) runs = 0;
  __syncthreads();
  for (int base = 0; base < nb; base += 256) {
    int i = base + threadIdx.x;
    int v = (i < nb) ? bsum[i] : 0;
    sh[threadIdx.x] = v;
    __syncthreads();
    for (int o = 1; o < 256; o <<= 1) {
      int t = (threadIdx.x >= o) ? sh[threadIdx.x - o] : 0;
      __syncthreads();
      sh[threadIdx.x] += t;
      __syncthreads();
    }
    int incl = sh[threadIdx.x];
    int r0 = runs;
    if (i < nb) bsum[i] = r0 + incl - v;
    __syncthreads();
    if (threadIdx.x == 0) runs = r0 + sh[255];
    __syncthreads();
  }
}

__global__ __launch_bounds__(256) void rptr3(int* c0, int* c1, int* c2,
                                             const int* __restrict__ bsumA,
                                             int* r0p, int* r1p, int* r2p) {
  int b = blockIdx.x;
  int r, lb, n;
  if (b < 196)      { r = 0; lb = b;       n = NUU; }
  else if (b < 587) { r = 1; lb = b - 196; n = NTT; }
  else              { r = 2; lb = b - 587; n = NUU; }
  int* cnt = r == 0 ? c0 : r == 1 ? c1 : c2;
  int* rptr = r == 0 ? r0p : r == 1 ? r1p : r2p;
  __shared__ int sh[256];
  int i = lb * 256 + threadIdx.x;
  int v = (i < n) ? cnt[i] : 0;
  sh[threadIdx.x] = v;
  __syncthreads();
  for (int o = 1; o < 256; o <<= 1) {
    int t = (threadIdx.x >= o) ? sh[threadIdx.x - o] : 0;
    __syncthreads();
    sh[threadIdx.x] += t;
    __syncthreads();
  }
  int excl = sh[threadIdx.x] - v + bsumA[r * 400 + lb];
  if (i < n) { rptr[i] = excl; cnt[i] = excl; }
  if (i == 0) rptr[n] = EE;
}

__global__ __launch_bounds__(256) void fill3(const int* e0, const int* e1, const int* e2,
                                             int* c0, int* c1, int* c2,
                                             int* s0, int* s1, int* s2) {
  int idx = blockIdx.x * 256 + threadIdx.x;
  if (idx >= 3 * EE) return;
  int r = idx / EE, e = idx - r * EE;
  const int* ebase = (r == 0 ? e0 : r == 1 ? e1 : e2);
  int* cursor = r == 0 ? c0 : r == 1 ? c1 : c2;
  int* csrc = r == 0 ? s0 : r == 1 ? s1 : s2;
  int pos = atomicAdd(&cursor[ebase[EE + e]], 1);
  csrc[pos] = ebase[e];
}

// ---------- LDS-staged q'/V GEMM: 32 rows x 512 cols per block ----------
// V branch optionally fuses c[s][h] = sum_d x_s[d] * cU[h*128+d]  (cOut != null)
struct GRel3 {
  const u16* Xqb; const float* Xqf;
  const u16* Xvb; const float* Xvf;
  const u16* Wq; const u16* Wv;
  const float* bzq; const float* bzv;
  const float* cU; float* cOut;
  u16 *oq, *ov;
  int nq, nv, bq, bv, xbq, xbv;
};

__global__ __launch_bounds__(256) void gemm_rel3(GRel3 a) {
  __shared__ u16 Xs[32 * 128];
  __shared__ u16 Os[32 * 512];
  const int bx = blockIdx.x;
  int lb, n, usexb, isV;
  const u16* Xb; const float* Xf; const u16* Wsw; const float* bias; u16* Y;
  if (bx < a.bq) {
    lb = bx; n = a.nq; Xb = a.Xqb; Xf = a.Xqf; Wsw = a.Wq; bias = a.bzq; Y = a.oq;
    usexb = a.xbq; isV = 0;
  } else {
    lb = bx - a.bq; n = a.nv; Xb = a.Xvb; Xf = a.Xvf; Wsw = a.Wv; bias = a.bzv; Y = a.ov;
    usexb = a.xbv; isV = 1;
  }
  const int row0 = lb * 32;
  if (row0 >= n) return;
  const int tid = threadIdx.x;

  if (usexb) {
    #pragma unroll
    for (int q = 0; q < 2; ++q) {
      int c = tid + q * 256;
      int row = c >> 4, off = (c & 15) * 16;
      int gr = row0 + row; if (gr >= n) gr = n - 1;
      uint4 val = *(const uint4*)((const char*)Xb + (size_t)gr * 256 + off);
      *(uint4*)((char*)Xs + row * 256 + (off ^ ((row & 7) << 4))) = val;
    }
  } else {
    #pragma unroll
    for (int q = 0; q < 4; ++q) {
      int c = tid + q * 256;
      int row = c >> 5, sub = c & 31;
      int gr = row0 + row; if (gr >= n) gr = n - 1;
      float4 f = *(const float4*)(Xf + (size_t)gr * 128 + sub * 4);
      ushort4 pk;
      pk.x = f2bf(f.x); pk.y = f2bf(f.y); pk.z = f2bf(f.z); pk.w = f2bf(f.w);
      *(ushort4*)((char*)Xs + row * 256 + ((sub * 8) ^ ((row & 7) << 4))) = pk;
    }
  }
  __syncthreads();

  // ---- fused c for V blocks: 8 threads per row, 16 dims each ----
  if (isV && a.cOut != nullptr) {
    const int row = tid >> 3, k = tid & 7;
    const int gr = row0 + row;
    float part[4] = {};
    #pragma unroll
    for (int dd2 = 0; dd2 < 16; ++dd2) {
      int d = k * 16 + dd2;
      u16 xv = *(const u16*)((const char*)Xs + row * 256 + ((2 * d) ^ ((row & 7) << 4)));
      float xf = bflo((u32)xv);
      #pragma unroll
      for (int h = 0; h < 4; ++h) part[h] = fmaf(xf, a.cU[h * 128 + d], part[h]);
    }
    #pragma unroll
    for (int h = 0; h < 4; ++h) {
      #pragma unroll
      for (int o = 1; o < 8; o <<= 1) part[h] += __shfl_xor(part[h], o);
    }
    if (k == 0 && gr < n) {
      *(float4*)(a.cOut + (size_t)gr * 4) = make_float4(part[0], part[1], part[2], part[3]);
    }
  }

  const int wid = tid >> 6, lane = tid & 63;
  const int l15 = lane & 15, l4 = lane >> 4;

  s8v afr[2][4];
  #pragma unroll
  for (int rt = 0; rt < 2; ++rt) {
    int row = rt * 16 + l15;
    #pragma unroll
    for (int kk = 0; kk < 4; ++kk)
      afr[rt][kk] = *(const s8v*)((const char*)Xs + row * 256 + ((kk * 64 + l4 * 16) ^ ((row & 7) << 4)));
  }

  const u16* wbase = Wsw + ((size_t)wid * 16384) + (size_t)lane * 8;
  s8v w0[4], w1[4];
  #pragma unroll
  for (int kk = 0; kk < 4; ++kk) w0[kk] = *(const s8v*)(wbase + kk * 512);

  #pragma unroll
  for (int ctl = 0; ctl < 8; ++ctl) {
    const s8v* cw = (ctl & 1) ? w1 : w0;
    s8v* nw = (ctl & 1) ? w0 : w1;
    if (ctl + 1 < 8) {
      #pragma unroll
      for (int kk = 0; kk < 4; ++kk)
        nw[kk] = *(const s8v*)(wbase + (ctl + 1) * 2048 + kk * 512);
    }
    f4v acc0 = {}, acc1 = {};
    #pragma unroll
    for (int kk = 0; kk < 4; ++kk) {
      acc0 = __builtin_amdgcn_mfma_f32_16x16x32_bf16(cw[kk], afr[0][kk], acc0, 0, 0, 0);
      acc1 = __builtin_amdgcn_mfma_f32_16x16x32_bf16(cw[kk], afr[1][kk], acc1, 0, 0, 0);
    }
    const int colb = wid * 128 + ctl * 16 + l4 * 4;
    const float4 bb = *(const float4*)(bias + colb);
    {
      int row = l15;
      ushort4 pk;
      pk.x = f2bf(acc0[0] + bb.x); pk.y = f2bf(acc0[1] + bb.y);
      pk.z = f2bf(acc0[2] + bb.z); pk.w = f2bf(acc0[3] + bb.w);
      *(ushort4*)((char*)Os + row * 1024 + ((colb * 2) ^ ((row & 7) << 4))) = pk;
    }
    {
      int row = 16 + l15;
      ushort4 pk;
      pk.x = f2bf(acc1[0] + bb.x); pk.y = f2bf(acc1[1] + bb.y);
      pk.z = f2bf(acc1[2] + bb.z); pk.w = f2bf(acc1[3] + bb.w);
      *(ushort4*)((char*)Os + row * 1024 + ((colb * 2) ^ ((row & 7) << 4))) = pk;
    }
  }
  __syncthreads();

  #pragma unroll
  for (int r = 0; r < 8; ++r) {
    int row = wid * 8 + r;
    int gr = row0 + row;
    if (gr < n) {
      uint4 val = *(const uint4*)((const char*)Os + row * 1024 + ((lane * 16) ^ ((row & 7) << 4)));
      *(uint4*)(Y + (size_t)gr * 512 + lane * 8) = val;
    }
  }
}

// ---------- skip GEMM (flat grid, STORE) ----------
__global__ __launch_bounds__(256) void gemm_skip3(const u16* xbu, const u16* xbt,
                                                  const float* xfu, const float* xft,
                                                  const u16* Wu, const u16* Wtw,
                                                  const float* bu, const float* btw,
                                                  float* aggu, float* aggt,
                                                  int fu, int ft) {
  const int bx = blockIdx.x;
  int job, lb;
  if (bx < BU) { job = 0; lb = bx; } else { job = 1; lb = bx - BU; }
  const int n = job ? NTT : NUU;
  const int bm = lb * 128;
  const u16* XB = job ? xbt : xbu;
  const float* XF = job ? xft : xfu;
  const u16* Wt = job ? Wtw : Wu;
  const float* bias = job ? btw : bu;
  float* out = job ? aggt : aggu;
  const int usexb = job ? ft : fu;

  const int wid = threadIdx.x >> 6, lane = threadIdx.x & 63;
  const int l15 = lane & 15, l4 = lane >> 4;
  const int rbase = bm + wid * 32;
  int r0 = rbase + l15;      if (r0 >= n) r0 = n - 1;
  int r1 = rbase + 16 + l15; if (r1 >= n) r1 = n - 1;
  s8v a0[4], a1[4];
  if (usexb) {
    const u16* xb0 = XB + (size_t)r0 * DD + l4 * 8;
    const u16* xb1 = XB + (size_t)r1 * DD + l4 * 8;
    #pragma unroll
    for (int kk = 0; kk < 4; ++kk) {
      a0[kk] = *(const s8v*)(xb0 + kk * 32);
      a1[kk] = *(const s8v*)(xb1 + kk * 32);
    }
  } else {
    const float* xp0 = XF + (size_t)r0 * DD + l4 * 8;
    const float* xp1 = XF + (size_t)r1 * DD + l4 * 8;
    #pragma unroll
    for (int kk = 0; kk < 4; ++kk) {
      a0[kk] = cvt_row8(xp0 + kk * 32);
      a1[kk] = cvt_row8(xp1 + kk * 32);
    }
  }

  const u16* wp = Wt + (size_t)l15 * DD + l4 * 8;
  const bool ok0 = (rbase + l15 < n), ok1 = (rbase + 16 + l15 < n);
  float* yp0 = out + (size_t)(rbase + l15) * DD + l4 * 8;
  float* yp1 = out + (size_t)(rbase + 16 + l15) * DD + l4 * 8;

  s8v w0[8], w1[8];
  #pragma unroll
  for (int kk = 0; kk < 4; ++kk) {
    w0[kk]     = *(const s8v*)(wp + kk * 32);
    w0[4 + kk] = *(const s8v*)(wp + 16 * DD + kk * 32);
  }
  #pragma unroll
  for (int p = 0; p < 4; ++p) {
    const s8v* cw = (p & 1) ? w1 : w0;
    s8v* nw = (p & 1) ? w0 : w1;
    if (p + 1 < 4) {
      const u16* wq = wp + (size_t)(2 * (p + 1)) * 16 * DD;
      #pragma unroll
      for (int kk = 0; kk < 4; ++kk) {
        nw[kk]     = *(const s8v*)(wq + kk * 32);
        nw[4 + kk] = *(const s8v*)(wq + 16 * DD + kk * 32);
      }
    }
    f4v aE0 = {}, aE1 = {}, aO0 = {}, aO1 = {};
    #pragma unroll
    for (int kk = 0; kk < 4; ++kk) {
      aE0 = __builtin_amdgcn_mfma_f32_16x16x32_bf16(cw[kk], a0[kk], aE0, 0, 0, 0);
      aE1 = __builtin_amdgcn_mfma_f32_16x16x32_bf16(cw[kk], a1[kk], aE1, 0, 0, 0);
      aO0 = __builtin_amdgcn_mfma_f32_16x16x32_bf16(cw[4 + kk], a0[kk], aO0, 0, 0, 0);
      aO1 = __builtin_amdgcn_mfma_f32_16x16x32_bf16(cw[4 + kk], a1[kk], aO1, 0, 0, 0);
    }
    const float4 bbE = *(const float4*)(bias + p * 32 + l4 * 8);
    const float4 bbO = *(const float4*)(bias + p * 32 + l4 * 8 + 4);
    if (ok0) {
      *(float4*)(yp0 + p * 32) = make_float4(aE0[0] + bbE.x, aE0[1] + bbE.y, aE0[2] + bbE.z, aE0[3] + bbE.w);
      *(float4*)(yp0 + p * 32 + 4) = make_float4(aO0[0] + bbO.x, aO0[1] + bbO.y, aO0[2] + bbO.z, aO0[3] + bbO.w);
    }
    if (ok1) {
      *(float4*)(yp1 + p * 32) = make_float4(aE1[0] + bbE.x, aE1[1] + bbE.y, aE1[2] + bbE.z, aE1[3] + bbE.w);
      *(float4*)(yp1 + p * 32 + 4) = make_float4(aO1[0] + bbO.x, aO1[1] + bbO.y, aO1[2] + bbO.z, aO1[3] + bbO.w);
    }
  }
}

// ---------- edge kernel: logits via q'.x_s + c(s); V gather; deg-1 fast path ----------
template<int XF>
__global__ __launch_bounds__(256) void edge_fused2(const u16* __restrict__ qp,
                                                   const u16* __restrict__ v,
                                                   const u16* __restrict__ xsb,
                                                   const float* __restrict__ xsf,
                                                   const float* __restrict__ cbuf,
                                                   const int* __restrict__ rptr,
                                                   const int* __restrict__ csrc,
                                                   float* __restrict__ agg,
                                                   int nd, int qs32) {
  int node = (int)(((size_t)blockIdx.x * 256 + threadIdx.x) >> 6);
  int lane = threadIdx.x & 63;
  if (node >= nd) return;
  int e0 = rptr[node], e1 = rptr[node + 1];
  if (e0 == e1) return;
  const int g = lane >> 4, i = lane & 15;
  float acc[8];

  if (e1 - e0 == 1) {
    int s = csrc[e0];
    const u32* vp = (const u32*)v + (size_t)s * 256 + lane * 4;
    #pragma unroll
    for (int j = 0; j < 4; ++j) { u32 u = vp[j]; acc[2 * j] = bflo(u); acc[2 * j + 1] = bfhi(u); }
  } else {
    u32 qv[4];
    {
      const u32* qq = (const u32*)qp + (size_t)node * qs32 + g * 64 + i * 4;
      #pragma unroll
      for (int j = 0; j < 4; ++j) qv[j] = qq[j];
    }
    float m = -1e30f, z = 0.f;
    #pragma unroll
    for (int j = 0; j < 8; ++j) acc[j] = 0.f;

    int s_cur = csrc[e0];
    u32 xc[4]; float xf[8];
    if (XF) {
      const u32* xp = (const u32*)xsb + (size_t)s_cur * 64 + i * 4;
      #pragma unroll
      for (int j = 0; j < 4; ++j) xc[j] = xp[j];
    } else {
      const float* xp = xsf + (size_t)s_cur * 128 + i * 8;
      #pragma unroll
      for (int j = 0; j < 8; ++j) xf[j] = xp[j];
    }

    for (int e = e0; e < e1; ++e) {
      u32 vcur[4];
      {
        const u32* vp = (const u32*)v + (size_t)s_cur * 256 + lane * 4;
        #pragma unroll
        for (int j = 0; j < 4; ++j) vcur[j] = vp[j];
      }
      float cs = cbuf[(size_t)s_cur * 4 + g];
      const bool has = (e + 1 < e1);
      int s_nxt = csrc[has ? e + 1 : e0];
      u32 xn[4]; float xnf[8];
      if (XF) {
        const u32* xp = (const u32*)xsb + (size_t)s_nxt * 64 + i * 4;
        #pragma unroll
        for (int j = 0; j < 4; ++j) xn[j] = xp[j];
      } else {
        const float* xp = xsf + (size_t)s_nxt * 128 + i * 8;
        #pragma unroll
        for (int j = 0; j < 8; ++j) xnf[j] = xp[j];
      }

      float dot = 0.f;
      if (XF) {
        #pragma unroll
        for (int j = 0; j < 4; ++j)
          dot += bflo(qv[j]) * bflo(xc[j]) + bfhi(qv[j]) * bfhi(xc[j]);
      } else {
        #pragma unroll
        for (int j = 0; j < 4; ++j)
          dot += bflo(qv[j]) * xf[2 * j] + bfhi(qv[j]) * xf[2 * j + 1];
      }
      dot += __shfl_xor(dot, 1);
      dot += __shfl_xor(dot, 2);
      dot += __shfl_xor(dot, 4);
      dot += __shfl_xor(dot, 8);
      float lg = dot * 0.08838834764831845f + cs;
      float w;
      if (lg > m) {
        float sc = __expf(m - lg);
        z *= sc;
        #pragma unroll
        for (int j = 0; j < 8; ++j) acc[j] *= sc;
        m = lg; w = 1.f;
      } else {
        w = __expf(lg - m);
      }
      z += w;
      #pragma unroll
      for (int j = 0; j < 4; ++j) {
        acc[2 * j]     += w * bflo(vcur[j]);
        acc[2 * j + 1] += w * bfhi(vcur[j]);
      }
      if (has) {
        s_cur = s_nxt;
        if (XF) {
          #pragma unroll
          for (int j = 0; j < 4; ++j) xc[j] = xn[j];
        } else {
          #pragma unroll
          for (int j = 0; j < 8; ++j) xf[j] = xnf[j];
        }
      }
    }
    float iz = 1.f / z;
    #pragma unroll
    for (int j = 0; j < 8; ++j) acc[j] *= iz;
  }

  #pragma unroll
  for (int j = 0; j < 8; ++j) acc[j] *= 0.25f;
  #pragma unroll
  for (int o = 16; o < 64; o <<= 1) {
    #pragma unroll
    for (int j = 0; j < 8; ++j) acc[j] += __shfl_xor(acc[j], o);
  }
  if (lane < 16) {
    float* op = agg + (size_t)node * DD + lane * 8;
    #pragma unroll
    for (int j = 0; j < 8; ++j) op[j] += acc[j];
  }
}

// ---------- l0-tu shortcut: uniform softmax over broadcast K/V ----------
__global__ __launch_bounds__(256) void add_bcast4(const u16* __restrict__ v,
                                                  const int* __restrict__ rptr,
                                                  float* __restrict__ agg, int nd) {
  int node = (int)(((size_t)blockIdx.x * 256 + threadIdx.x) >> 6);
  int lane = threadIdx.x & 63;
  if (node >= nd) return;
  if (rptr[node + 1] <= rptr[node]) return;
  const u32* vp = (const u32*)v;   // row 0
  float a0 = 0.f, a1 = 0.f;
  #pragma unroll
  for (int h = 0; h < 4; ++h) {
    u32 u = vp[h * 64 + lane];
    a0 += bflo(u); a1 += bfhi(u);
  }
  float* op = agg + (size_t)node * DD + 2 * lane;
  op[0] += 0.25f * a0;
  op[1] += 0.25f * a1;
}

// ---------- LayerNorm + residual (+ bf16 mirror writes) ----------
__global__ __launch_bounds__(256) void ln2(const float* __restrict__ aggu,
                                           const float* __restrict__ aggt,
                                           const float* __restrict__ g2,
                                           const float* __restrict__ b2,
                                           float* __restrict__ xu,
                                           float* __restrict__ xt,
                                           u16* __restrict__ xbu,
                                           u16* __restrict__ xbt,
                                           int wbu, int wbt) {
  int wid = (int)(((size_t)blockIdx.x * 256 + threadIdx.x) >> 6);
  int lane = threadIdx.x & 63;
  if (wid >= NUU + NTT) return;
  const float* ap; float* xp; const float* g; const float* b; u16* xbp; int wb;
  if (wid < NUU) {
    ap = aggu + (size_t)wid * DD; xp = xu + (size_t)wid * DD;
    xbp = xbu ? xbu + (size_t)wid * DD : nullptr; g = g2; b = b2; wb = wbu;
  } else {
    int t = wid - NUU;
    ap = aggt + (size_t)t * DD; xp = xt + (size_t)t * DD;
    xbp = xbt ? xbt + (size_t)t * DD : nullptr; g = g2 + DD; b = b2 + DD; wb = wbt;
  }
  float v0 = ap[lane], v1 = ap[lane + 64];
  float s = v0 + v1;
  #pragma unroll
  for (int o = 1; o < 64; o <<= 1) s += __shfl_xor(s, o);
  float mean = s * (1.0f / DD);
  float d0 = v0 - mean, d1 = v1 - mean;
  float sq = d0 * d0 + d1 * d1;
  #pragma unroll
  for (int o = 1; o < 64; o <<= 1) sq += __shfl_xor(sq, o);
  float rstd = rsqrtf(sq * (1.0f / DD) + 1e-5f);
  float n0 = g[lane]      * d0 * rstd + b[lane]      + xp[lane];
  float n1 = g[lane + 64] * d1 * rstd + b[lane + 64] + xp[lane + 64];
  xp[lane] = n0;
  xp[lane + 64] = n1;
  if (wb) {
    xbp[lane] = f2bf(n0);
    xbp[lane + 64] = f2bf(n1);
  }
}

extern "C" void kernel_launch(void* const* d_in, const int* in_sizes, int n_in,
                              void* d_out, int out_size, void* d_ws, size_t ws_size,
                              hipStream_t stream) {
  const float* emb_user = (const float*)d_in[0];
  const float* tv_tweet = (const float*)d_in[1];
  const float* W_qkv  = (const float*)d_in[2];
  const float* b_qkv  = (const float*)d_in[3];
  const float* W_skip = (const float*)d_in[4];
  const float* b_skip = (const float*)d_in[5];
  const float* ln_g   = (const float*)d_in[6];
  const float* ln_b   = (const float*)d_in[7];
  const int* edges[3] = { (const int*)d_in[8], (const int*)d_in[9], (const int*)d_in[10] };

  float* x_user  = (float*)d_out;
  float* x_tweet = x_user + (size_t)NUU * DD;

  // ---- workspace layout (identical to R12) ----
  const size_t fixed = 786432 + 131072 + 2048 + 786432 + 12288 + 2048 + 1600000
                     + 76800000 + (size_t)3 * 400032 + (size_t)3 * 400000 + 4800
                     + 153600000 + 4096;
  int XBU = 0, XBT = 0;
  if      (ws_size >= fixed + 38400000) { XBU = 1; XBT = 1; }
  else if (ws_size >= fixed + 25600000) { XBT = 1; }

  char* w = (char*)d_ws;
  u16* Wtv = (u16*)w;        w += 786432;
  u16* WtsC = (u16*)w;       w += 131072;
  float* bskC = (float*)w;   w += 2048;
  u16* Mwt = (u16*)w;        w += 786432;
  float* Uw = (float*)w;     w += 12288;
  float* zeros = (float*)w;  w += 2048;
  float* cbuf = (float*)w;   w += 1600000;
  float* agg_u = (float*)w;  w += (size_t)NUU * DD * 4;
  float* agg_t = (float*)w;  w += (size_t)NTT * DD * 4;
  int* rptrA[3]; int* csrcA[3];
  for (int r = 0; r < 3; ++r) { rptrA[r] = (int*)w; w += 400032; }
  for (int r = 0; r < 3; ++r) { csrcA[r] = (int*)w; w += 400000; }
  int* bsumA = (int*)w;      w += 4800;
  u16* xb_user = nullptr; u16* xb_tweet = nullptr;
  if (XBT) { xb_tweet = (u16*)w; w += (size_t)NTT * DD * 2; }
  if (XBU) { xb_user = (u16*)w;  w += (size_t)NUU * DD * 2; }
  u16* arena = (u16*)w;
  int* cntA[3];
  cntA[0] = (int*)arena; cntA[1] = cntA[0] + 100000; cntA[2] = cntA[0] + 200000;

  init_x2<<<(19500000 + 255) / 256, 256, 0, stream>>>(emb_user, tv_tweet, x_user, x_tweet,
                                                      cntA[0], xb_user, xb_tweet, XBU, XBT);
  conv_w<<<(6 * 65536 + 255) / 256, 256, 0, stream>>>(W_qkv, W_skip, b_skip,
                                                      Wtv, WtsC, bskC, zeros);
  mk_m2<<<dim3(24, 8), 256, 0, stream>>>(W_qkv, b_qkv, Mwt, Uw);

  hist3<<<(3 * EE + 255) / 256, 256, 0, stream>>>(edges[0], edges[1], edges[2],
                                                  cntA[0], cntA[1], cntA[2]);
  bsum3<<<783, 256, 0, stream>>>(cntA[0], cntA[1], cntA[2], bsumA);
  bscan3<<<3, 256, 0, stream>>>(bsumA);
  rptr3<<<783, 256, 0, stream>>>(cntA[0], cntA[1], cntA[2], bsumA, rptrA[0], rptrA[1], rptrA[2]);
  fill3<<<(3 * EE + 255) / 256, 256, 0, stream>>>(edges[0], edges[1], edges[2],
                                                  cntA[0], cntA[1], cntA[2],
                                                  csrcA[0], csrcA[1], csrcA[2]);

  const int stt[3] = {0, 0, 1}, dtt[3] = {0, 1, 0};
  const int cnt2[2] = {NUU, NTT};
  float* xs[2]   = {x_user, x_tweet};
  u16* xbs[2]    = {xb_user, xb_tweet};
  const int xbf[2] = {XBU, XBT};
  float* aggs[2] = {agg_u, agg_t};

  for (int l = 0; l < 2; ++l) {
    gemm_skip3<<<BU + BT, 256, 0, stream>>>(
        xb_user, xb_tweet, x_user, x_tweet,
        WtsC + (size_t)(2 * l) * 128 * 128, WtsC + (size_t)(2 * l + 1) * 128 * 128,
        bskC + (size_t)(2 * l) * 128, bskC + (size_t)(2 * l + 1) * 128,
        agg_u, agg_t, XBU, XBT);

    for (int r = 0; r < 3; ++r) {
      const int st = stt[r], dt = dtt[r];
      const int ns = cnt2[st], nd = cnt2[dt];
      const int rel = l * 3 + r;
      const bool qDeg = (l == 0 && dt == 1);   // ut-l0: broadcast dst
      const bool uniSM = (l == 0 && st == 1);  // tu-l0: broadcast src -> uniform softmax

      const int nq_eff = uniSM ? 0 : (qDeg ? 1 : nd);
      const int nv_eff = uniSM ? 1 : ns;
      u16* qb_r = arena;
      u16* vb_r = arena + (size_t)nq_eff * HCC;

      GRel3 ga;
      ga.Xqb = xbs[dt]; ga.Xqf = xs[dt]; ga.xbq = xbf[dt];
      ga.Xvb = xbs[st]; ga.Xvf = xs[st]; ga.xbv = xbf[st];
      ga.Wq = Mwt + (size_t)rel * 65536;
      ga.Wv = Wtv + (size_t)rel * 65536;
      ga.bzq = zeros;
      ga.bzv = b_qkv + (size_t)(rel * 3 + 2) * HCC;
      ga.cU = Uw + (size_t)rel * 512;
      ga.cOut = uniSM ? nullptr : cbuf;
      ga.oq = qb_r; ga.ov = vb_r;
      ga.nq = nq_eff; ga.nv = nv_eff;
      ga.bq = (nq_eff + 31) / 32; ga.bv = (nv_eff + 31) / 32;
      gemm_rel3<<<ga.bq + ga.bv, 256, 0, stream>>>(ga);

      const int eblk = (nd + 3) / 4;
      if (uniSM) {
        add_bcast4<<<eblk, 256, 0, stream>>>(vb_r, rptrA[r], aggs[dt], nd);
      } else {
        const int qs32 = qDeg ? 0 : 256;
        if (xbf[st])
          edge_fused2<1><<<eblk, 256, 0, stream>>>(qb_r, vb_r, xbs[st], xs[st], cbuf,
                                                   rptrA[r], csrcA[r], aggs[dt], nd, qs32);
        else
          edge_fused2<0><<<eblk, 256, 0, stream>>>(qb_r, vb_r, xbs[st], xs[st], cbuf,
                                                   rptrA[r], csrcA[r], aggs[dt], nd, qs32);
      }
    }
    ln2<<<(NUU + NTT + 3) / 4, 256, 0, stream>>>(agg_u, agg_t,
                                                 ln_g + (size_t)l * 2 * DD,
                                                 ln_b + (size_t)l * 2 * DD,
                                                 x_user, x_tweet,
                                                 xb_user, xb_tweet,
                                                 XBU && l == 0, XBT && l == 0);
  }
}